// Round 1
// baseline (2980.789 us; speedup 1.0000x reference)
//
#include <hip/hip_runtime.h>
#include <math.h>

// Problem constants (n=1, t=3, c=64, h=w=32)
#define HW 1024
#define W_IMG 32
#define H_IMG 32

// ---------------------------------------------------------------------------
// Bilinear sample with zero padding, absolute pixel coords (matches reference
// _bilinear: validity tested on unclipped floor coords, then clamped gather).
// ---------------------------------------------------------------------------
__device__ __forceinline__ float bilin32(const float* __restrict__ img, float px, float py) {
    float x0f = floorf(px), y0f = floorf(py);
    float wx = px - x0f, wy = py - y0f;
    bool vx0 = (x0f >= 0.f) && (x0f <= 31.f);
    bool vx1 = (x0f >= -1.f) && (x0f <= 30.f);
    bool vy0 = (y0f >= 0.f) && (y0f <= 31.f);
    bool vy1 = (y0f >= -1.f) && (y0f <= 30.f);
    int ix0 = (int)fminf(fmaxf(x0f, 0.f), 31.f);
    int iy0 = (int)fminf(fmaxf(y0f, 0.f), 31.f);
    int ix1 = (int)fminf(fmaxf(x0f + 1.f, 0.f), 31.f);
    int iy1 = (int)fminf(fmaxf(y0f + 1.f, 0.f), 31.f);
    float w00 = (1.f - wx) * (1.f - wy) * ((vx0 && vy0) ? 1.f : 0.f);
    float w01 = wx * (1.f - wy) * ((vx1 && vy0) ? 1.f : 0.f);
    float w10 = (1.f - wx) * wy * ((vx0 && vy1) ? 1.f : 0.f);
    float w11 = wx * wy * ((vx1 && vy1) ? 1.f : 0.f);
    return w00 * img[iy0 * 32 + ix0] + w01 * img[iy0 * 32 + ix1] +
           w10 * img[iy1 * 32 + ix0] + w11 * img[iy1 * 32 + ix1];
}

// ---------------------------------------------------------------------------
// K1: flow composition.
// flow_cn2 = flow_1 + warp(flow_2, flow_1)
// flow_n2c = flip_flow_2 + warp(flip_flow_1, flip_flow_2)
// ---------------------------------------------------------------------------
__global__ __launch_bounds__(256) void compose_flows_k(
    const float* __restrict__ flow_1, const float* __restrict__ flow_2,
    const float* __restrict__ flip_flow_1, const float* __restrict__ flip_flow_2,
    float* __restrict__ flow_cn2, float* __restrict__ flow_n2c)
{
    int pix = blockIdx.x * blockDim.x + threadIdx.x;
    if (pix >= HW) return;
    int y = pix >> 5, x = pix & 31;
    {
        float fx = flow_1[pix], fy = flow_1[HW + pix];
        float px = (float)x + fx, py = (float)y + fy;
        flow_cn2[pix]      = fx + bilin32(flow_2, px, py);
        flow_cn2[HW + pix] = fy + bilin32(flow_2 + HW, px, py);
    }
    {
        float fx = flip_flow_2[pix], fy = flip_flow_2[HW + pix];
        float px = (float)x + fx, py = (float)y + fy;
        flow_n2c[pix]      = fx + bilin32(flip_flow_1, px, py);
        flow_n2c[HW + pix] = fy + bilin32(flip_flow_1 + HW, px, py);
    }
}

// ---------------------------------------------------------------------------
// K2: build 'extra' tensor [460, 1024]:
// [x0(64) | warp_cn1 | warp_cn2 | warp_n1c | warp_n1n2 | warp_n2n1 | warp_n2c |
//  flow_1(2) | flow_cn2 | flip_flow_1 | flow_2 | flip_flow_2 | flow_n2c]
// ---------------------------------------------------------------------------
__global__ __launch_bounds__(256) void build_extra_k(
    const float* __restrict__ x, const float* __restrict__ flow_1,
    const float* __restrict__ flow_2, const float* __restrict__ flip_flow_1,
    const float* __restrict__ flip_flow_2, const float* __restrict__ flow_cn2,
    const float* __restrict__ flow_n2c, float* __restrict__ extra)
{
    int idx = blockIdx.x * blockDim.x + threadIdx.x;
    if (idx >= 460 * HW) return;
    int ch = idx >> 10;
    int pix = idx & 1023;
    int y = pix >> 5, xx = pix & 31;
    float v;
    if (ch < 64) {
        v = x[ch * HW + pix];
    } else if (ch < 448) {
        int grp = (ch - 64) >> 6;
        int c = (ch - 64) & 63;
        const float* src; const float* fl;
        if (grp == 0)      { src = x + 64 * HW;  fl = flow_1; }      // warp_cn1
        else if (grp == 1) { src = x + 128 * HW; fl = flow_cn2; }    // warp_cn2
        else if (grp == 2) { src = x;            fl = flip_flow_1; } // warp_n1c
        else if (grp == 3) { src = x + 128 * HW; fl = flow_2; }      // warp_n1n2
        else if (grp == 4) { src = x + 64 * HW;  fl = flip_flow_2; } // warp_n2n1
        else               { src = x;            fl = flow_n2c; }    // warp_n2c
        float px = (float)xx + fl[pix];
        float py = (float)y + fl[HW + pix];
        v = bilin32(src + c * HW, px, py);
    } else {
        int fc = ch - 448;
        int which = fc >> 1, comp = fc & 1;
        const float* fl;
        if (which == 0)      fl = flow_1;
        else if (which == 1) fl = flow_cn2;
        else if (which == 2) fl = flip_flow_1;
        else if (which == 3) fl = flow_2;
        else if (which == 4) fl = flip_flow_2;
        else                 fl = flow_n2c;
        v = fl[comp * HW + pix];
    }
    extra[idx] = v;
}

// ---------------------------------------------------------------------------
// K3: generic 3x3 SAME conv (cross-correlation), NCHW flat [C,1024].
// Block: 256 threads = 256 pixels; each block does 8 output channels.
// Grid: (Cout/8, 4). Weights read via wave-uniform indices -> scalar loads.
// relu_out: apply leaky-relu(0.1) to output. residual: optional add.
// ---------------------------------------------------------------------------
__global__ __launch_bounds__(256) void conv3x3_k(
    const float* __restrict__ in, const float* __restrict__ wgt,
    const float* __restrict__ bias, float* __restrict__ out,
    int Cin, int relu_out, const float* __restrict__ residual)
{
    const int co0 = blockIdx.x * 8;
    const int pix = blockIdx.y * 256 + threadIdx.x;
    const int y = pix >> 5, x = pix & 31;
    float acc[8];
#pragma unroll
    for (int c = 0; c < 8; ++c) acc[c] = bias[co0 + c];
    const bool ym1 = (y > 0), yp1 = (y < 31), xm1 = (x > 0), xp1 = (x < 31);
    for (int ci = 0; ci < Cin; ++ci) {
        const float* ip = in + ci * HW + pix;
        float v[9];
        v[0] = (ym1 && xm1) ? ip[-33] : 0.f;
        v[1] = ym1 ? ip[-32] : 0.f;
        v[2] = (ym1 && xp1) ? ip[-31] : 0.f;
        v[3] = xm1 ? ip[-1] : 0.f;
        v[4] = ip[0];
        v[5] = xp1 ? ip[1] : 0.f;
        v[6] = (yp1 && xm1) ? ip[31] : 0.f;
        v[7] = yp1 ? ip[32] : 0.f;
        v[8] = (yp1 && xp1) ? ip[33] : 0.f;
        const float* wp = wgt + (size_t)co0 * Cin * 9 + ci * 9;
#pragma unroll
        for (int c = 0; c < 8; ++c) {
            const float* w = wp + (size_t)c * Cin * 9;
#pragma unroll
            for (int t = 0; t < 9; ++t) acc[c] = fmaf(w[t], v[t], acc[c]);
        }
    }
#pragma unroll
    for (int c = 0; c < 8; ++c) {
        float r = acc[c];
        if (relu_out) r = (r >= 0.f) ? r : 0.1f * r;
        if (residual) r += residual[(co0 + c) * HW + pix];
        out[(co0 + c) * HW + pix] = r;
    }
}

// ---------------------------------------------------------------------------
// K4: deformable attention. One wave (64 lanes) per (q, m) pair.
// q = f*1024 + pix (f in 0..2), m in 0..7. 24576 waves total.
// value   [192,1024]  (t*c image layout)
// so_out  [1728,1024] channel = f*576 + ((m*3+l)*12+p)*2 + comp
// aw_out  [7776,1024] channel = f*2592 + m*324 + j, j = l*108 + p*9 + k
// attn_out[192,1024]  channel = f*64 + m*8 + d
// Sampling coords simplify to px = x + off_x (+flow +patch), py = y + off_y.
// ---------------------------------------------------------------------------
__global__ __launch_bounds__(256) void deform_attn_k(
    const float* __restrict__ value, const float* __restrict__ so_out,
    const float* __restrict__ aw_out,
    const float* __restrict__ flow_1, const float* __restrict__ flow_2,
    const float* __restrict__ flip_flow_1, const float* __restrict__ flip_flow_2,
    const float* __restrict__ flow_cn2, const float* __restrict__ flow_n2c,
    float* __restrict__ attn_out)
{
    const int wav = threadIdx.x >> 6;
    const int lane = threadIdx.x & 63;
    const int wid = blockIdx.x * 4 + wav;      // 0..24575
    const int q = wid >> 3, m = wid & 7;
    const int f = q >> 10, pix = q & 1023;
    const int y = pix >> 5, x = pix & 31;

    // ---- softmax over 324 attention logits ----
    const int awbase = (f * 2592 + m * 324) * HW + pix;
    float av[6];
    float vmax = -1e30f;
#pragma unroll
    for (int it = 0; it < 6; ++it) {
        int j = lane + it * 64;
        float a = (j < 324) ? aw_out[awbase + j * HW] : -1e30f;
        av[it] = a;
        vmax = fmaxf(vmax, a);
    }
#pragma unroll
    for (int off = 32; off; off >>= 1) vmax = fmaxf(vmax, __shfl_xor(vmax, off));
    float ssum = 0.f;
#pragma unroll
    for (int it = 0; it < 6; ++it) {
        int j = lane + it * 64;
        float e = (j < 324) ? __expf(av[it] - vmax) : 0.f;
        av[it] = e;
        ssum += e;
    }
#pragma unroll
    for (int off = 32; off; off >>= 1) ssum += __shfl_xor(ssum, off);
    const float inv = 1.f / ssum;

    // ---- sample + accumulate ----
    float acc[8];
#pragma unroll
    for (int d = 0; d < 8; ++d) acc[d] = 0.f;

#pragma unroll
    for (int it = 0; it < 6; ++it) {
        int j = lane + it * 64;
        if (j < 324) {
            float wj = av[it] * inv;
            int l = j / 108;
            int r = j - l * 108;
            int p = r / 9;
            int k = r - p * 9;
            int sobase = (f * 576 + ((m * 3 + l) * 12 + p) * 2) * HW + pix;
            float ox = so_out[sobase];
            float oy = so_out[sobase + HW];
            // flow-guided addition per (f, l)
            const float* fl = nullptr;
            if (f == 0)      { if (l == 1) fl = flow_1;      else if (l == 2) fl = flow_cn2; }
            else if (f == 1) { if (l == 0) fl = flip_flow_1; else if (l == 2) fl = flow_2; }
            else             { if (l == 0) fl = flow_n2c;    else if (l == 1) fl = flip_flow_2; }
            float fx = fl ? fl[pix] : 0.f;
            float fy = fl ? fl[HW + pix] : 0.f;
            float pxf = (float)x + ox + fx + (float)(k / 3 - 1);
            float pyf = (float)y + oy + fy + (float)(k % 3 - 1);
            // bilinear taps (shared across the 8 head dims)
            float x0f = floorf(pxf), y0f = floorf(pyf);
            float wx = pxf - x0f, wy = pyf - y0f;
            bool vx0 = (x0f >= 0.f) && (x0f <= 31.f);
            bool vx1 = (x0f >= -1.f) && (x0f <= 30.f);
            bool vy0 = (y0f >= 0.f) && (y0f <= 31.f);
            bool vy1 = (y0f >= -1.f) && (y0f <= 30.f);
            int ix0 = (int)fminf(fmaxf(x0f, 0.f), 31.f);
            int iy0 = (int)fminf(fmaxf(y0f, 0.f), 31.f);
            int ix1 = (int)fminf(fmaxf(x0f + 1.f, 0.f), 31.f);
            int iy1 = (int)fminf(fmaxf(y0f + 1.f, 0.f), 31.f);
            float w00 = (1.f - wx) * (1.f - wy) * ((vx0 && vy0) ? 1.f : 0.f);
            float w01 = wx * (1.f - wy) * ((vx1 && vy0) ? 1.f : 0.f);
            float w10 = (1.f - wx) * wy * ((vx0 && vy1) ? 1.f : 0.f);
            float w11 = wx * wy * ((vx1 && vy1) ? 1.f : 0.f);
            int p00 = iy0 * 32 + ix0, p01 = iy0 * 32 + ix1;
            int p10 = iy1 * 32 + ix0, p11 = iy1 * 32 + ix1;
            const float* vb = value + (l * 64 + m * 8) * HW;
#pragma unroll
            for (int d = 0; d < 8; ++d) {
                const float* vd = vb + d * HW;
                float s = w00 * vd[p00] + w01 * vd[p01] + w10 * vd[p10] + w11 * vd[p11];
                acc[d] = fmaf(wj, s, acc[d]);
            }
        }
    }
    // wave reduction
#pragma unroll
    for (int d = 0; d < 8; ++d) {
#pragma unroll
        for (int off = 32; off; off >>= 1) acc[d] += __shfl_xor(acc[d], off);
    }
    if (lane == 0) {
        int ob = (f * 64 + m * 8) * HW + pix;
#pragma unroll
        for (int d = 0; d < 8; ++d) attn_out[ob + d * HW] = acc[d];
    }
}

// ---------------------------------------------------------------------------
extern "C" void kernel_launch(void* const* d_in, const int* in_sizes, int n_in,
                              void* d_out, int out_size, void* d_ws, size_t ws_size,
                              hipStream_t stream) {
    const float* x      = (const float*)d_in[0];
    const float* flow_1 = (const float*)d_in[1];
    const float* flow_2 = (const float*)d_in[2];
    const float* flip_1 = (const float*)d_in[3];
    const float* flip_2 = (const float*)d_in[4];
    const float* vp0_w = (const float*)d_in[5];  const float* vp0_b = (const float*)d_in[6];
    const float* vp1_w = (const float*)d_in[7];  const float* vp1_b = (const float*)d_in[8];
    const float* so0_w = (const float*)d_in[9];  const float* so0_b = (const float*)d_in[10];
    const float* so1_w = (const float*)d_in[11]; const float* so1_b = (const float*)d_in[12];
    const float* so2_w = (const float*)d_in[13]; const float* so2_b = (const float*)d_in[14];
    const float* so3_w = (const float*)d_in[15]; const float* so3_b = (const float*)d_in[16];
    const float* aw0_w = (const float*)d_in[17]; const float* aw0_b = (const float*)d_in[18];
    const float* aw1_w = (const float*)d_in[19]; const float* aw1_b = (const float*)d_in[20];
    const float* aw2_w = (const float*)d_in[21]; const float* aw2_b = (const float*)d_in[22];
    const float* aw3_w = (const float*)d_in[23]; const float* aw3_b = (const float*)d_in[24];
    const float* op0_w = (const float*)d_in[25]; const float* op0_b = (const float*)d_in[26];
    const float* op1_w = (const float*)d_in[27]; const float* op1_b = (const float*)d_in[28];
    float* out = (float*)d_out;

    float* ws = (float*)d_ws;
    float* flow_cn2 = ws;                    // 2048
    float* flow_n2c = flow_cn2 + 2048;       // 2048
    float* extra    = flow_n2c + 2048;       // 460*1024 = 471040
    float* value    = extra + 460 * HW;      // 192*1024 = 196608
    float* bufA     = value + 192 * HW;      // 192*1024
    float* bufB     = bufA + 192 * HW;       // 64*1024
    float* so_out   = bufB + 64 * HW;        // 1728*1024
    float* aw_out   = so_out + 1728 * HW;    // 7776*1024
    float* attn_out = aw_out + 7776 * HW;    // 192*1024
    (void)ws_size; (void)in_sizes; (void)n_in; (void)out_size;

    // 1. flow composition
    compose_flows_k<<<4, 256, 0, stream>>>(flow_1, flow_2, flip_1, flip_2,
                                           flow_cn2, flow_n2c);
    // 2. extra tensor (warps + flows)
    build_extra_k<<<(460 * HW + 255) / 256, 256, 0, stream>>>(
        x, flow_1, flow_2, flip_1, flip_2, flow_cn2, flow_n2c, extra);

    // 3. value projection: vp0 (lrelu) -> vp1
    conv3x3_k<<<dim3(192 / 8, 4), 256, 0, stream>>>(x, vp0_w, vp0_b, bufA, 192, 1, nullptr);
    conv3x3_k<<<dim3(192 / 8, 4), 256, 0, stream>>>(bufA, vp1_w, vp1_b, value, 192, 0, nullptr);

    // 4. sampling-offset head
    conv3x3_k<<<dim3(64 / 8, 4), 256, 0, stream>>>(extra, so0_w, so0_b, bufA, 460, 1, nullptr);
    conv3x3_k<<<dim3(64 / 8, 4), 256, 0, stream>>>(bufA, so1_w, so1_b, bufB, 64, 1, nullptr);
    conv3x3_k<<<dim3(64 / 8, 4), 256, 0, stream>>>(bufB, so2_w, so2_b, bufA, 64, 1, nullptr);
    conv3x3_k<<<dim3(1728 / 8, 4), 256, 0, stream>>>(bufA, so3_w, so3_b, so_out, 64, 0, nullptr);

    // 5. attention-weight head
    conv3x3_k<<<dim3(64 / 8, 4), 256, 0, stream>>>(extra, aw0_w, aw0_b, bufA, 460, 1, nullptr);
    conv3x3_k<<<dim3(64 / 8, 4), 256, 0, stream>>>(bufA, aw1_w, aw1_b, bufB, 64, 1, nullptr);
    conv3x3_k<<<dim3(64 / 8, 4), 256, 0, stream>>>(bufB, aw2_w, aw2_b, bufA, 64, 1, nullptr);
    conv3x3_k<<<dim3(7776 / 8, 4), 256, 0, stream>>>(bufA, aw3_w, aw3_b, aw_out, 64, 0, nullptr);

    // 6. deformable attention (softmax fused)
    deform_attn_k<<<24576 / 4, 256, 0, stream>>>(value, so_out, aw_out,
                                                 flow_1, flow_2, flip_1, flip_2,
                                                 flow_cn2, flow_n2c, attn_out);

    // 7. output projection + residual
    conv3x3_k<<<dim3(192 / 8, 4), 256, 0, stream>>>(attn_out, op0_w, op0_b, bufA, 192, 1, nullptr);
    conv3x3_k<<<dim3(192 / 8, 4), 256, 0, stream>>>(bufA, op1_w, op1_b, out, 192, 0, x);
}

// Round 2
// 1687.189 us; speedup vs baseline: 1.7667x; 1.7667x over previous
//
#include <hip/hip_runtime.h>
#include <math.h>

// Problem constants (n=1, t=3, c=64, h=w=32)
#define HW 1024

// ---------------------------------------------------------------------------
// Bilinear sample with zero padding, absolute pixel coords.
// ---------------------------------------------------------------------------
__device__ __forceinline__ float bilin32(const float* __restrict__ img, float px, float py) {
    float x0f = floorf(px), y0f = floorf(py);
    float wx = px - x0f, wy = py - y0f;
    bool vx0 = (x0f >= 0.f) && (x0f <= 31.f);
    bool vx1 = (x0f >= -1.f) && (x0f <= 30.f);
    bool vy0 = (y0f >= 0.f) && (y0f <= 31.f);
    bool vy1 = (y0f >= -1.f) && (y0f <= 30.f);
    int ix0 = (int)fminf(fmaxf(x0f, 0.f), 31.f);
    int iy0 = (int)fminf(fmaxf(y0f, 0.f), 31.f);
    int ix1 = (int)fminf(fmaxf(x0f + 1.f, 0.f), 31.f);
    int iy1 = (int)fminf(fmaxf(y0f + 1.f, 0.f), 31.f);
    float w00 = (1.f - wx) * (1.f - wy) * ((vx0 && vy0) ? 1.f : 0.f);
    float w01 = wx * (1.f - wy) * ((vx1 && vy0) ? 1.f : 0.f);
    float w10 = (1.f - wx) * wy * ((vx0 && vy1) ? 1.f : 0.f);
    float w11 = wx * wy * ((vx1 && vy1) ? 1.f : 0.f);
    return w00 * img[iy0 * 32 + ix0] + w01 * img[iy0 * 32 + ix1] +
           w10 * img[iy1 * 32 + ix0] + w11 * img[iy1 * 32 + ix1];
}

// ---------------------------------------------------------------------------
// K1: flow composition.
// ---------------------------------------------------------------------------
__global__ __launch_bounds__(256) void compose_flows_k(
    const float* __restrict__ flow_1, const float* __restrict__ flow_2,
    const float* __restrict__ flip_flow_1, const float* __restrict__ flip_flow_2,
    float* __restrict__ flow_cn2, float* __restrict__ flow_n2c)
{
    int pix = blockIdx.x * blockDim.x + threadIdx.x;
    if (pix >= HW) return;
    int y = pix >> 5, x = pix & 31;
    {
        float fx = flow_1[pix], fy = flow_1[HW + pix];
        float px = (float)x + fx, py = (float)y + fy;
        flow_cn2[pix]      = fx + bilin32(flow_2, px, py);
        flow_cn2[HW + pix] = fy + bilin32(flow_2 + HW, px, py);
    }
    {
        float fx = flip_flow_2[pix], fy = flip_flow_2[HW + pix];
        float px = (float)x + fx, py = (float)y + fy;
        flow_n2c[pix]      = fx + bilin32(flip_flow_1, px, py);
        flow_n2c[HW + pix] = fy + bilin32(flip_flow_1 + HW, px, py);
    }
}

// ---------------------------------------------------------------------------
// K2: build 'extra' tensor [460, 1024] channel-major.
// ---------------------------------------------------------------------------
__global__ __launch_bounds__(256) void build_extra_k(
    const float* __restrict__ x, const float* __restrict__ flow_1,
    const float* __restrict__ flow_2, const float* __restrict__ flip_flow_1,
    const float* __restrict__ flip_flow_2, const float* __restrict__ flow_cn2,
    const float* __restrict__ flow_n2c, float* __restrict__ extra)
{
    int idx = blockIdx.x * blockDim.x + threadIdx.x;
    if (idx >= 460 * HW) return;
    int ch = idx >> 10;
    int pix = idx & 1023;
    int y = pix >> 5, xx = pix & 31;
    float v;
    if (ch < 64) {
        v = x[ch * HW + pix];
    } else if (ch < 448) {
        int grp = (ch - 64) >> 6;
        int c = (ch - 64) & 63;
        const float* src; const float* fl;
        if (grp == 0)      { src = x + 64 * HW;  fl = flow_1; }
        else if (grp == 1) { src = x + 128 * HW; fl = flow_cn2; }
        else if (grp == 2) { src = x;            fl = flip_flow_1; }
        else if (grp == 3) { src = x + 128 * HW; fl = flow_2; }
        else if (grp == 4) { src = x + 64 * HW;  fl = flip_flow_2; }
        else               { src = x;            fl = flow_n2c; }
        float px = (float)xx + fl[pix];
        float py = (float)y + fl[HW + pix];
        v = bilin32(src + c * HW, px, py);
    } else {
        int fc = ch - 448;
        int which = fc >> 1, comp = fc & 1;
        const float* fl;
        if (which == 0)      fl = flow_1;
        else if (which == 1) fl = flow_cn2;
        else if (which == 2) fl = flip_flow_1;
        else if (which == 3) fl = flow_2;
        else if (which == 4) fl = flip_flow_2;
        else                 fl = flow_n2c;
        v = fl[comp * HW + pix];
    }
    extra[idx] = v;
}

// ---------------------------------------------------------------------------
// K3: 3x3 SAME conv, dual-tensor capable (set A for blockIdx.x < ngA, else B).
// Block = 256 threads = 4 waves; each wave: 2 output channels x 64 pixels.
// Grid: ((CoutA+CoutB)/8, 16).
// cmod == 0: channel-major out [Cout,1024].
// cmod  > 0: transposed out [(co/cmod)*1024 + pix][cmod] (query-major).
// relu: leaky-relu 0.1 on output. residual (set A only, channel-major).
// ---------------------------------------------------------------------------
__global__ __launch_bounds__(256) void conv3x3_k(
    const float* __restrict__ inA, const float* __restrict__ wA,
    const float* __restrict__ bA, float* __restrict__ outA, int ngA, int cmodA,
    const float* __restrict__ inB, const float* __restrict__ wB,
    const float* __restrict__ bB, float* __restrict__ outB, int cmodB,
    int Cin, int relu, const float* __restrict__ residual)
{
    int bx = blockIdx.x;
    const float *in, *wgt, *bias; float* out; int cmod;
    const float* res = nullptr;
    if (bx < ngA) { in = inA; wgt = wA; bias = bA; out = outA; cmod = cmodA; res = residual; }
    else { bx -= ngA; in = inB; wgt = wB; bias = bB; out = outB; cmod = cmodB; }

    const int wav = threadIdx.x >> 6, lane = threadIdx.x & 63;
    const int co0 = bx * 8 + wav * 2;
    const int pix = blockIdx.y * 64 + lane;
    const int y = pix >> 5, x = pix & 31;
    const bool ym1 = (y > 0), yp1 = (y < 31), xm1 = (x > 0), xp1 = (x < 31);

    float a0 = bias[co0], a1 = bias[co0 + 1];
    const size_t wstride = (size_t)Cin * 9;
    const float* wrow = wgt + (size_t)co0 * wstride;

#pragma unroll 2
    for (int ci = 0; ci < Cin; ++ci) {
        const float* ip = in + ci * HW + pix;
        float v[9];
        v[0] = (ym1 && xm1) ? ip[-33] : 0.f;
        v[1] = ym1 ? ip[-32] : 0.f;
        v[2] = (ym1 && xp1) ? ip[-31] : 0.f;
        v[3] = xm1 ? ip[-1] : 0.f;
        v[4] = ip[0];
        v[5] = xp1 ? ip[1] : 0.f;
        v[6] = (yp1 && xm1) ? ip[31] : 0.f;
        v[7] = yp1 ? ip[32] : 0.f;
        v[8] = (yp1 && xp1) ? ip[33] : 0.f;
        const float* w0 = wrow + ci * 9;
        const float* w1 = w0 + wstride;
#pragma unroll
        for (int t = 0; t < 9; ++t) {
            a0 = fmaf(w0[t], v[t], a0);
            a1 = fmaf(w1[t], v[t], a1);
        }
    }
    if (relu) {
        a0 = (a0 >= 0.f) ? a0 : 0.1f * a0;
        a1 = (a1 >= 0.f) ? a1 : 0.1f * a1;
    }
    if (cmod == 0) {
        if (res) {
            a0 += res[co0 * HW + pix];
            a1 += res[(co0 + 1) * HW + pix];
        }
        out[co0 * HW + pix] = a0;
        out[(co0 + 1) * HW + pix] = a1;
    } else {
        int fq = co0 / cmod;
        int cc = co0 - fq * cmod;
        float2 st; st.x = a0; st.y = a1;
        *(float2*)(out + (size_t)(fq * HW + pix) * cmod + cc) = st;
    }
}

// ---------------------------------------------------------------------------
// K4: deformable attention with query-major inputs. One wave per (q, m).
// aw_t   [q][2592]  cc = m*324 + j           (coalesced: lane j)
// so_t   [q][576]   cc = (m*36 + l*12 + p)*2 (+comp)
// value_t[(l*8+m)*1024 + pix][8]             (float4 x2 per tap)
// attn   [192,1024] channel-major, channel = f*64 + m*8 + d
// ---------------------------------------------------------------------------
__global__ __launch_bounds__(256) void deform_attn_k(
    const float* __restrict__ value_t, const float* __restrict__ so_t,
    const float* __restrict__ aw_t,
    const float* __restrict__ flow_1, const float* __restrict__ flow_2,
    const float* __restrict__ flip_flow_1, const float* __restrict__ flip_flow_2,
    const float* __restrict__ flow_cn2, const float* __restrict__ flow_n2c,
    float* __restrict__ attn_out)
{
    const int wav = threadIdx.x >> 6;
    const int lane = threadIdx.x & 63;
    const int wid = blockIdx.x * 4 + wav;      // 0..24575
    const int q = wid >> 3, m = wid & 7;
    const int f = q >> 10, pix = q & 1023;
    const int y = pix >> 5, x = pix & 31;

    // per-level flow for this (f, pix) — wave-uniform loads (broadcast)
    float flx0 = 0.f, fly0 = 0.f, flx1 = 0.f, fly1 = 0.f, flx2 = 0.f, fly2 = 0.f;
    if (f == 0) {
        flx1 = flow_1[pix];      fly1 = flow_1[HW + pix];
        flx2 = flow_cn2[pix];    fly2 = flow_cn2[HW + pix];
    } else if (f == 1) {
        flx0 = flip_flow_1[pix]; fly0 = flip_flow_1[HW + pix];
        flx2 = flow_2[pix];      fly2 = flow_2[HW + pix];
    } else {
        flx0 = flow_n2c[pix];    fly0 = flow_n2c[HW + pix];
        flx1 = flip_flow_2[pix]; fly1 = flip_flow_2[HW + pix];
    }

    // ---- softmax over 324 logits (coalesced reads) ----
    const float* awp = aw_t + (size_t)q * 2592 + m * 324;
    float av[6];
    float vmax = -1e30f;
#pragma unroll
    for (int it = 0; it < 6; ++it) {
        int j = lane + it * 64;
        float a = (j < 324) ? awp[j] : -1e30f;
        av[it] = a;
        vmax = fmaxf(vmax, a);
    }
#pragma unroll
    for (int off = 32; off; off >>= 1) vmax = fmaxf(vmax, __shfl_xor(vmax, off));
    float ssum = 0.f;
#pragma unroll
    for (int it = 0; it < 6; ++it) {
        int j = lane + it * 64;
        float e = (j < 324) ? __expf(av[it] - vmax) : 0.f;
        av[it] = e;
        ssum += e;
    }
#pragma unroll
    for (int off = 32; off; off >>= 1) ssum += __shfl_xor(ssum, off);
    const float inv = 1.f / ssum;

    // ---- sample + accumulate ----
    float acc[8];
#pragma unroll
    for (int d = 0; d < 8; ++d) acc[d] = 0.f;
    const float* sop = so_t + (size_t)q * 576 + m * 72;

#pragma unroll
    for (int it = 0; it < 6; ++it) {
        int j = lane + it * 64;
        if (j < 324) {
            float wj = av[it] * inv;
            int l = j / 108;
            int r = j - l * 108;
            int p = r / 9;
            int k = r - p * 9;
            float2 so2 = *(const float2*)(sop + (l * 12 + p) * 2);
            float fx = (l == 0) ? flx0 : (l == 1) ? flx1 : flx2;
            float fy = (l == 0) ? fly0 : (l == 1) ? fly1 : fly2;
            float pxf = (float)x + so2.x + fx + (float)(k / 3 - 1);
            float pyf = (float)y + so2.y + fy + (float)(k % 3 - 1);
            float x0f = floorf(pxf), y0f = floorf(pyf);
            float wx = pxf - x0f, wy = pyf - y0f;
            bool vx0 = (x0f >= 0.f) && (x0f <= 31.f);
            bool vx1 = (x0f >= -1.f) && (x0f <= 30.f);
            bool vy0 = (y0f >= 0.f) && (y0f <= 31.f);
            bool vy1 = (y0f >= -1.f) && (y0f <= 30.f);
            int ix0 = (int)fminf(fmaxf(x0f, 0.f), 31.f);
            int iy0 = (int)fminf(fmaxf(y0f, 0.f), 31.f);
            int ix1 = (int)fminf(fmaxf(x0f + 1.f, 0.f), 31.f);
            int iy1 = (int)fminf(fmaxf(y0f + 1.f, 0.f), 31.f);
            float w00 = (1.f - wx) * (1.f - wy) * ((vx0 && vy0) ? 1.f : 0.f);
            float w01 = wx * (1.f - wy) * ((vx1 && vy0) ? 1.f : 0.f);
            float w10 = (1.f - wx) * wy * ((vx0 && vy1) ? 1.f : 0.f);
            float w11 = wx * wy * ((vx1 && vy1) ? 1.f : 0.f);
            int t00 = iy0 * 32 + ix0, t01 = iy0 * 32 + ix1;
            int t10 = iy1 * 32 + ix0, t11 = iy1 * 32 + ix1;
            const float4* vb = (const float4*)(value_t) + (size_t)(l * 8 + m) * 2048;
            float4 a00 = vb[t00 * 2], b00 = vb[t00 * 2 + 1];
            float4 a01 = vb[t01 * 2], b01 = vb[t01 * 2 + 1];
            float4 a10 = vb[t10 * 2], b10 = vb[t10 * 2 + 1];
            float4 a11 = vb[t11 * 2], b11 = vb[t11 * 2 + 1];
            float s0 = w00 * a00.x + w01 * a01.x + w10 * a10.x + w11 * a11.x;
            float s1 = w00 * a00.y + w01 * a01.y + w10 * a10.y + w11 * a11.y;
            float s2 = w00 * a00.z + w01 * a01.z + w10 * a10.z + w11 * a11.z;
            float s3 = w00 * a00.w + w01 * a01.w + w10 * a10.w + w11 * a11.w;
            float s4 = w00 * b00.x + w01 * b01.x + w10 * b10.x + w11 * b11.x;
            float s5 = w00 * b00.y + w01 * b01.y + w10 * b10.y + w11 * b11.y;
            float s6 = w00 * b00.z + w01 * b01.z + w10 * b10.z + w11 * b11.z;
            float s7 = w00 * b00.w + w01 * b01.w + w10 * b10.w + w11 * b11.w;
            acc[0] = fmaf(wj, s0, acc[0]);
            acc[1] = fmaf(wj, s1, acc[1]);
            acc[2] = fmaf(wj, s2, acc[2]);
            acc[3] = fmaf(wj, s3, acc[3]);
            acc[4] = fmaf(wj, s4, acc[4]);
            acc[5] = fmaf(wj, s5, acc[5]);
            acc[6] = fmaf(wj, s6, acc[6]);
            acc[7] = fmaf(wj, s7, acc[7]);
        }
    }
#pragma unroll
    for (int d = 0; d < 8; ++d) {
#pragma unroll
        for (int off = 32; off; off >>= 1) acc[d] += __shfl_xor(acc[d], off);
    }
    if (lane == 0) {
        int ob = (f * 64 + m * 8) * HW + pix;
#pragma unroll
        for (int d = 0; d < 8; ++d) attn_out[ob + d * HW] = acc[d];
    }
}

// ---------------------------------------------------------------------------
static inline void conv_single(hipStream_t s, const float* in, const float* w,
                               const float* b, float* out, int Cout, int Cin,
                               int relu, int cmod, const float* residual) {
    int ng = Cout / 8;
    conv3x3_k<<<dim3(ng, 16), 256, 0, s>>>(in, w, b, out, ng, cmod,
                                           nullptr, nullptr, nullptr, nullptr, 0,
                                           Cin, relu, residual);
}
static inline void conv_dual(hipStream_t s,
                             const float* inA, const float* wA, const float* bA,
                             float* outA, int CoutA, int cmodA,
                             const float* inB, const float* wB, const float* bB,
                             float* outB, int CoutB, int cmodB,
                             int Cin, int relu) {
    int ngA = CoutA / 8, ngB = CoutB / 8;
    conv3x3_k<<<dim3(ngA + ngB, 16), 256, 0, s>>>(inA, wA, bA, outA, ngA, cmodA,
                                                  inB, wB, bB, outB, cmodB,
                                                  Cin, relu, nullptr);
}

extern "C" void kernel_launch(void* const* d_in, const int* in_sizes, int n_in,
                              void* d_out, int out_size, void* d_ws, size_t ws_size,
                              hipStream_t stream) {
    const float* x      = (const float*)d_in[0];
    const float* flow_1 = (const float*)d_in[1];
    const float* flow_2 = (const float*)d_in[2];
    const float* flip_1 = (const float*)d_in[3];
    const float* flip_2 = (const float*)d_in[4];
    const float* vp0_w = (const float*)d_in[5];  const float* vp0_b = (const float*)d_in[6];
    const float* vp1_w = (const float*)d_in[7];  const float* vp1_b = (const float*)d_in[8];
    const float* so0_w = (const float*)d_in[9];  const float* so0_b = (const float*)d_in[10];
    const float* so1_w = (const float*)d_in[11]; const float* so1_b = (const float*)d_in[12];
    const float* so2_w = (const float*)d_in[13]; const float* so2_b = (const float*)d_in[14];
    const float* so3_w = (const float*)d_in[15]; const float* so3_b = (const float*)d_in[16];
    const float* aw0_w = (const float*)d_in[17]; const float* aw0_b = (const float*)d_in[18];
    const float* aw1_w = (const float*)d_in[19]; const float* aw1_b = (const float*)d_in[20];
    const float* aw2_w = (const float*)d_in[21]; const float* aw2_b = (const float*)d_in[22];
    const float* aw3_w = (const float*)d_in[23]; const float* aw3_b = (const float*)d_in[24];
    const float* op0_w = (const float*)d_in[25]; const float* op0_b = (const float*)d_in[26];
    const float* op1_w = (const float*)d_in[27]; const float* op1_b = (const float*)d_in[28];
    float* out = (float*)d_out;
    (void)ws_size; (void)in_sizes; (void)n_in; (void)out_size;

    float* ws = (float*)d_ws;
    float* flow_cn2 = ws;                        // 2048
    float* flow_n2c = flow_cn2 + 2048;           // 2048
    float* extra    = flow_n2c + 2048;           // 460*1024
    float* value_t  = extra + 460 * HW;          // 192*1024 (query-major, 8/d)
    float* vbuf     = value_t + 192 * HW;        // 192*1024 (vp0 out; reused for op0 out)
    float* so_bufA  = vbuf + 192 * HW;           // 64*1024
    float* so_bufB  = so_bufA + 64 * HW;         // 64*1024
    float* aw_bufA  = so_bufB + 64 * HW;         // 64*1024
    float* aw_bufB  = aw_bufA + 64 * HW;         // 64*1024
    float* so_t     = aw_bufB + 64 * HW;         // 1728*1024
    float* aw_t     = so_t + 1728 * HW;          // 7776*1024
    float* attn     = aw_t + 7776 * HW;          // 192*1024

    // 1. flow composition
    compose_flows_k<<<4, 256, 0, stream>>>(flow_1, flow_2, flip_1, flip_2,
                                           flow_cn2, flow_n2c);
    // 2. extra tensor
    build_extra_k<<<(460 * HW + 255) / 256, 256, 0, stream>>>(
        x, flow_1, flow_2, flip_1, flip_2, flow_cn2, flow_n2c, extra);

    // 3. value projection (vp1 writes query-major value_t via cmod=8)
    conv_single(stream, x, vp0_w, vp0_b, vbuf, 192, 192, 1, 0, nullptr);
    conv_single(stream, vbuf, vp1_w, vp1_b, value_t, 192, 192, 0, 8, nullptr);

    // 4-5. offset + attention-weight heads (dual launches, shared shapes)
    conv_dual(stream, extra, so0_w, so0_b, so_bufA, 64, 0,
                      extra, aw0_w, aw0_b, aw_bufA, 64, 0, 460, 1);
    conv_dual(stream, so_bufA, so1_w, so1_b, so_bufB, 64, 0,
                      aw_bufA, aw1_w, aw1_b, aw_bufB, 64, 0, 64, 1);
    conv_dual(stream, so_bufB, so2_w, so2_b, so_bufA, 64, 0,
                      aw_bufB, aw2_w, aw2_b, aw_bufA, 64, 0, 64, 1);
    conv_dual(stream, so_bufA, so3_w, so3_b, so_t, 1728, 576,
                      aw_bufA, aw3_w, aw3_b, aw_t, 7776, 2592, 64, 0);

    // 6. deformable attention (softmax fused), query-major inputs
    deform_attn_k<<<24576 / 4, 256, 0, stream>>>(value_t, so_t, aw_t,
                                                 flow_1, flow_2, flip_1, flip_2,
                                                 flow_cn2, flow_n2c, attn);

    // 7. output projection + residual
    conv_single(stream, attn, op0_w, op0_b, vbuf, 192, 192, 1, 0, nullptr);
    conv_single(stream, vbuf, op1_w, op1_b, out, 192, 192, 0, 0, x);
}

// Round 3
// 815.024 us; speedup vs baseline: 3.6573x; 2.0701x over previous
//
#include <hip/hip_runtime.h>
#include <math.h>

#define HW 1024

typedef __attribute__((ext_vector_type(8))) short bf16x8;
typedef __attribute__((ext_vector_type(4))) float floatx4;

__device__ __forceinline__ unsigned short f2bf(float f) {
    unsigned u = __float_as_uint(f);
    u += 0x7FFF + ((u >> 16) & 1);
    return (unsigned short)(u >> 16);
}
__device__ __forceinline__ float bf2f(unsigned short u) {
    return __uint_as_float(((unsigned)u) << 16);
}

// ---------------------------------------------------------------------------
// Bilinear sample, zero padding, absolute pixel coords (matches reference).
// ---------------------------------------------------------------------------
__device__ __forceinline__ float bilin32(const float* __restrict__ img, float px, float py) {
    float x0f = floorf(px), y0f = floorf(py);
    float wx = px - x0f, wy = py - y0f;
    bool vx0 = (x0f >= 0.f) && (x0f <= 31.f);
    bool vx1 = (x0f >= -1.f) && (x0f <= 30.f);
    bool vy0 = (y0f >= 0.f) && (y0f <= 31.f);
    bool vy1 = (y0f >= -1.f) && (y0f <= 30.f);
    int ix0 = (int)fminf(fmaxf(x0f, 0.f), 31.f);
    int iy0 = (int)fminf(fmaxf(y0f, 0.f), 31.f);
    int ix1 = (int)fminf(fmaxf(x0f + 1.f, 0.f), 31.f);
    int iy1 = (int)fminf(fmaxf(y0f + 1.f, 0.f), 31.f);
    float w00 = (1.f - wx) * (1.f - wy) * ((vx0 && vy0) ? 1.f : 0.f);
    float w01 = wx * (1.f - wy) * ((vx1 && vy0) ? 1.f : 0.f);
    float w10 = (1.f - wx) * wy * ((vx0 && vy1) ? 1.f : 0.f);
    float w11 = wx * wy * ((vx1 && vy1) ? 1.f : 0.f);
    return w00 * img[iy0 * 32 + ix0] + w01 * img[iy0 * 32 + ix1] +
           w10 * img[iy1 * 32 + ix0] + w11 * img[iy1 * 32 + ix1];
}

// ---------------------------------------------------------------------------
// K1: flow composition (fp32).
// ---------------------------------------------------------------------------
__global__ __launch_bounds__(256) void compose_flows_k(
    const float* __restrict__ flow_1, const float* __restrict__ flow_2,
    const float* __restrict__ flip_flow_1, const float* __restrict__ flip_flow_2,
    float* __restrict__ flow_cn2, float* __restrict__ flow_n2c)
{
    int pix = blockIdx.x * blockDim.x + threadIdx.x;
    if (pix >= HW) return;
    int y = pix >> 5, x = pix & 31;
    {
        float fx = flow_1[pix], fy = flow_1[HW + pix];
        float px = (float)x + fx, py = (float)y + fy;
        flow_cn2[pix]      = fx + bilin32(flow_2, px, py);
        flow_cn2[HW + pix] = fy + bilin32(flow_2 + HW, px, py);
    }
    {
        float fx = flip_flow_2[pix], fy = flip_flow_2[HW + pix];
        float px = (float)x + fx, py = (float)y + fy;
        flow_n2c[pix]      = fx + bilin32(flip_flow_1, px, py);
        flow_n2c[HW + pix] = fy + bilin32(flip_flow_1 + HW, px, py);
    }
}

// ---------------------------------------------------------------------------
// K2: build 'extra' as padded query-major bf16 [34*34][480] (interior only;
// channels 460..479 are zero padding for the K dimension).
// ---------------------------------------------------------------------------
__global__ __launch_bounds__(256) void build_extra_k(
    const float* __restrict__ x, const float* __restrict__ flow_1,
    const float* __restrict__ flow_2, const float* __restrict__ flip_flow_1,
    const float* __restrict__ flip_flow_2, const float* __restrict__ flow_cn2,
    const float* __restrict__ flow_n2c, unsigned short* __restrict__ extra_pad)
{
    int idx = blockIdx.x * blockDim.x + threadIdx.x;
    if (idx >= 480 * HW) return;
    int ch = idx >> 10;
    int pix = idx & 1023;
    int y = pix >> 5, xx = pix & 31;
    float v = 0.f;
    if (ch < 64) {
        v = x[ch * HW + pix];
    } else if (ch < 448) {
        int grp = (ch - 64) >> 6;
        int c = (ch - 64) & 63;
        const float* src; const float* fl;
        if (grp == 0)      { src = x + 64 * HW;  fl = flow_1; }
        else if (grp == 1) { src = x + 128 * HW; fl = flow_cn2; }
        else if (grp == 2) { src = x;            fl = flip_flow_1; }
        else if (grp == 3) { src = x + 128 * HW; fl = flow_2; }
        else if (grp == 4) { src = x + 64 * HW;  fl = flip_flow_2; }
        else               { src = x;            fl = flow_n2c; }
        float px = (float)xx + fl[pix];
        float py = (float)y + fl[HW + pix];
        v = bilin32(src + c * HW, px, py);
    } else if (ch < 460) {
        int fc = ch - 448;
        int which = fc >> 1, comp = fc & 1;
        const float* fl;
        if (which == 0)      fl = flow_1;
        else if (which == 1) fl = flow_cn2;
        else if (which == 2) fl = flip_flow_1;
        else if (which == 3) fl = flow_2;
        else if (which == 4) fl = flip_flow_2;
        else                 fl = flow_n2c;
        v = fl[comp * HW + pix];
    }
    extra_pad[(size_t)((y + 1) * 34 + xx + 1) * 480 + ch] = f2bf(v);
}

// ---------------------------------------------------------------------------
// K3: x -> padded query-major bf16 [34*34][192].
// ---------------------------------------------------------------------------
__global__ __launch_bounds__(256) void xpad_k(const float* __restrict__ x,
                                              unsigned short* __restrict__ xp)
{
    int idx = blockIdx.x * 256 + threadIdx.x;
    if (idx >= 1024 * 48) return;
    int pix = idx / 48, c4 = idx - pix * 48;
    int y = pix >> 5, xx = pix & 31;
    int c0 = c4 * 4;
    ushort4 s;
    s.x = f2bf(x[(size_t)(c0 + 0) * HW + pix]);
    s.y = f2bf(x[(size_t)(c0 + 1) * HW + pix]);
    s.z = f2bf(x[(size_t)(c0 + 2) * HW + pix]);
    s.w = f2bf(x[(size_t)(c0 + 3) * HW + pix]);
    *(ushort4*)(&xp[(size_t)((y + 1) * 34 + xx + 1) * 192 + c0]) = s;
}

// ---------------------------------------------------------------------------
// K4: zero the 1-pixel border of all padded bf16 buffers (ws is re-poisoned
// to 0xAA before every launch, so this must run every call).
// ---------------------------------------------------------------------------
struct BorderP { unsigned short* p[9]; int C[9]; };
__global__ __launch_bounds__(256) void border_k(BorderP P) {
    int i = blockIdx.x;       // 0..131 border pixels
    int b = blockIdx.y;       // buffer id
    int py, px;
    if (i < 34) { py = 0; px = i; }
    else if (i < 68) { py = 33; px = i - 34; }
    else { int j = i - 68; py = 1 + (j >> 1); px = (j & 1) ? 33 : 0; }
    unsigned short* buf = P.p[b];
    int C = P.C[b];
    for (int c = threadIdx.x; c < C; c += 256)
        buf[(size_t)(py * 34 + px) * C + c] = 0;
}

// ---------------------------------------------------------------------------
// K5: weight transform -> bf16 MFMA fragment order.
// dst block index blk = (co16*9 + t)*nCb + cb; element e = (q*16+m)*8 + j
// where co = co16*16+m, ci = cb*32 + q*8 + j. Lane q*16+m then loads 8
// consecutive ci as one dwordx4 (perfectly coalesced 1 KiB/wave).
// ---------------------------------------------------------------------------
struct WX { const float* sA; const float* sB; int split, coutA, coutB, Cin, nCb, beg; };
struct WXP { WX d[10]; };
__global__ __launch_bounds__(256) void wxform_k(WXP P, unsigned short* __restrict__ wgt) {
    int b = blockIdx.x;
    int di = 0;
#pragma unroll
    for (int i = 1; i < 10; ++i) if (b >= P.d[i].beg) di = i;
    WX w = P.d[di];
    int blk = b - w.beg;
    int cb = blk % w.nCb;
    int rest = blk / w.nCb;
    int t = rest % 9;
    int co16 = rest / 9;
    for (int e = threadIdx.x; e < 512; e += 256) {
        int j = e & 7, lane = e >> 3, q = lane >> 4, mm = lane & 15;
        int co = co16 * 16 + mm;
        int ci = cb * 32 + q * 8 + j;
        const float* src; int cr, cout;
        if (co < w.split) { src = w.sA; cr = co; cout = w.coutA; }
        else { src = w.sB; cr = co - w.split; cout = w.coutB; }
        float v = (cr < cout && ci < w.Cin) ? src[((size_t)cr * w.Cin + ci) * 9 + t] : 0.f;
        wgt[(size_t)b * 512 + e] = f2bf(v);
    }
}

// ---------------------------------------------------------------------------
// K6: MFMA 3x3 conv. Input: padded bf16 [34*34][Cpad]. Block = 64co x 256pix
// (4 waves, each 64co x 64pix = 4x4 accumulators of 16x16x32 bf16 MFMA).
// Grid (Mblocks, 4); blocks with co0 >= thresh use descriptor B.
// Output modes: 0 fp32 ch-major (+residual), 1 fp32 cmod, 2 bf16 cmod,
// 3 bf16 padded query-major (cmod = CpadOut).
// ---------------------------------------------------------------------------
struct ConvDesc {
    const unsigned short* in;
    const float* bias;
    void* out;
    const float* residual;
    int mode, cmod, Cout, relu;
};

__global__ __launch_bounds__(256) void conv_mfma_k(
    const unsigned short* __restrict__ wgt, int Cpad, int thresh,
    ConvDesc dA, ConvDesc dB)
{
    __shared__ unsigned short lds[340 * 40];   // 10 rows x 34 cols x stride 40
    const int tid = threadIdx.x;
    const int w = tid >> 6, lane = tid & 63;
    const int lq = lane >> 4, ln = lane & 15;
    const int co0 = blockIdx.x * 64;
    const int by = blockIdx.y;
    const int y0 = by * 8;                     // first padded row of the stage
    const bool useB = (co0 >= thresh);
    const ConvDesc d = useB ? dB : dA;
    const int nCb = Cpad >> 5;
    const unsigned short* __restrict__ in = d.in;

    floatx4 acc[4][4];
#pragma unroll
    for (int mt = 0; mt < 4; ++mt)
#pragma unroll
        for (int nt = 0; nt < 4; ++nt)
            acc[mt][nt] = (floatx4){0.f, 0.f, 0.f, 0.f};

    for (int cb = 0; cb < nCb; ++cb) {
        __syncthreads();
        const int ci0 = cb << 5;
        for (int i = tid; i < 1360; i += 256) {      // 10*34*4 chunks of 8 bf16
            int r = i / 136;
            int rem = i - r * 136;
            int c = rem >> 2, g = rem & 3;
            const bf16x8* src = (const bf16x8*)(in + (size_t)((y0 + r) * 34 + c) * Cpad + ci0 + g * 8);
            *(bf16x8*)(&lds[(r * 34 + c) * 40 + g * 8]) = *src;
        }
        __syncthreads();
        for (int t = 0; t < 9; ++t) {
            const int dy = t / 3, dx = t - dy * 3;
            bf16x8 bfr[4];
#pragma unroll
            for (int nt = 0; nt < 4; ++nt) {
                int yy = w * 2 + (nt >> 1) + dy;
                int xx = (nt & 1) * 16 + ln + dx;
                bfr[nt] = *(const bf16x8*)(&lds[(yy * 34 + xx) * 40 + lq * 8]);
            }
#pragma unroll
            for (int mt = 0; mt < 4; ++mt) {
                const bf16x8 afr = *(const bf16x8*)(wgt +
                    ((size_t)(((co0 >> 4) + mt) * 9 + t) * nCb + cb) * 512 + lane * 8);
#pragma unroll
                for (int nt = 0; nt < 4; ++nt)
                    acc[mt][nt] = __builtin_amdgcn_mfma_f32_16x16x32_bf16(afr, bfr[nt], acc[mt][nt], 0, 0, 0);
            }
        }
    }

    const int cobase = co0 - (useB ? thresh : 0);
#pragma unroll
    for (int mt = 0; mt < 4; ++mt) {
        const int co = cobase + mt * 16 + lq * 4;
        if (co >= d.Cout) continue;
        float bv[4];
#pragma unroll
        for (int r = 0; r < 4; ++r) bv[r] = d.bias[co + r];
#pragma unroll
        for (int nt = 0; nt < 4; ++nt) {
            const int pix = by * 256 + w * 64 + nt * 16 + ln;
            float v[4];
#pragma unroll
            for (int r = 0; r < 4; ++r) {
                float vv = acc[mt][nt][r] + bv[r];
                if (d.relu) vv = (vv >= 0.f) ? vv : 0.1f * vv;
                v[r] = vv;
            }
            if (d.mode == 0) {
                float* o = (float*)d.out;
#pragma unroll
                for (int r = 0; r < 4; ++r) {
                    float vv = v[r];
                    if (d.residual) vv += d.residual[(size_t)(co + r) * HW + pix];
                    o[(size_t)(co + r) * HW + pix] = vv;
                }
            } else if (d.mode == 1) {
                int fq = co / d.cmod, cc = co - fq * d.cmod;
                *(float4*)((float*)d.out + ((size_t)fq * HW + pix) * d.cmod + cc) =
                    make_float4(v[0], v[1], v[2], v[3]);
            } else if (d.mode == 2) {
                int fq = co / d.cmod, cc = co - fq * d.cmod;
                ushort4 s4;
                s4.x = f2bf(v[0]); s4.y = f2bf(v[1]); s4.z = f2bf(v[2]); s4.w = f2bf(v[3]);
                *(ushort4*)((unsigned short*)d.out + ((size_t)fq * HW + pix) * d.cmod + cc) = s4;
            } else {
                int yy = (pix >> 5) + 1, xx = (pix & 31) + 1;
                ushort4 s4;
                s4.x = f2bf(v[0]); s4.y = f2bf(v[1]); s4.z = f2bf(v[2]); s4.w = f2bf(v[3]);
                *(ushort4*)((unsigned short*)d.out + (size_t)(yy * 34 + xx) * d.cmod + co) = s4;
            }
        }
    }
}

// ---------------------------------------------------------------------------
// K7: deformable attention. One wave per (q, m). aw_t bf16 [q][2592],
// so_t fp32 [q][576], value_t fp32 [(l*8+m)*1024+pix][8].
// Writes attn_pad bf16 [34*34][192] interior (op0's input format).
// ---------------------------------------------------------------------------
__global__ __launch_bounds__(256) void deform_attn_k(
    const float* __restrict__ value_t, const float* __restrict__ so_t,
    const unsigned short* __restrict__ aw_t,
    const float* __restrict__ flow_1, const float* __restrict__ flow_2,
    const float* __restrict__ flip_flow_1, const float* __restrict__ flip_flow_2,
    const float* __restrict__ flow_cn2, const float* __restrict__ flow_n2c,
    unsigned short* __restrict__ attn_pad)
{
    const int wav = threadIdx.x >> 6;
    const int lane = threadIdx.x & 63;
    const int wid = blockIdx.x * 4 + wav;      // 0..24575
    const int q = wid >> 3, m = wid & 7;
    const int f = q >> 10, pix = q & 1023;
    const int y = pix >> 5, x = pix & 31;

    float flx0 = 0.f, fly0 = 0.f, flx1 = 0.f, fly1 = 0.f, flx2 = 0.f, fly2 = 0.f;
    if (f == 0) {
        flx1 = flow_1[pix];      fly1 = flow_1[HW + pix];
        flx2 = flow_cn2[pix];    fly2 = flow_cn2[HW + pix];
    } else if (f == 1) {
        flx0 = flip_flow_1[pix]; fly0 = flip_flow_1[HW + pix];
        flx2 = flow_2[pix];      fly2 = flow_2[HW + pix];
    } else {
        flx0 = flow_n2c[pix];    fly0 = flow_n2c[HW + pix];
        flx1 = flip_flow_2[pix]; fly1 = flip_flow_2[HW + pix];
    }

    const unsigned short* awp = aw_t + (size_t)q * 2592 + m * 324;
    float av[6];
    float vmax = -1e30f;
#pragma unroll
    for (int it = 0; it < 6; ++it) {
        int j = lane + it * 64;
        float a = (j < 324) ? bf2f(awp[j]) : -1e30f;
        av[it] = a;
        vmax = fmaxf(vmax, a);
    }
#pragma unroll
    for (int off = 32; off; off >>= 1) vmax = fmaxf(vmax, __shfl_xor(vmax, off));
    float ssum = 0.f;
#pragma unroll
    for (int it = 0; it < 6; ++it) {
        int j = lane + it * 64;
        float e = (j < 324) ? __expf(av[it] - vmax) : 0.f;
        av[it] = e;
        ssum += e;
    }
#pragma unroll
    for (int off = 32; off; off >>= 1) ssum += __shfl_xor(ssum, off);
    const float inv = 1.f / ssum;

    float acc[8];
#pragma unroll
    for (int dd = 0; dd < 8; ++dd) acc[dd] = 0.f;
    const float* sop = so_t + (size_t)q * 576 + m * 72;

#pragma unroll
    for (int it = 0; it < 6; ++it) {
        int j = lane + it * 64;
        if (j < 324) {
            float wj = av[it] * inv;
            int l = j / 108;
            int r = j - l * 108;
            int p = r / 9;
            int k = r - p * 9;
            float2 so2 = *(const float2*)(sop + (l * 12 + p) * 2);
            float fx = (l == 0) ? flx0 : (l == 1) ? flx1 : flx2;
            float fy = (l == 0) ? fly0 : (l == 1) ? fly1 : fly2;
            float pxf = (float)x + so2.x + fx + (float)(k / 3 - 1);
            float pyf = (float)y + so2.y + fy + (float)(k % 3 - 1);
            float x0f = floorf(pxf), y0f = floorf(pyf);
            float wx = pxf - x0f, wy = pyf - y0f;
            bool vx0 = (x0f >= 0.f) && (x0f <= 31.f);
            bool vx1 = (x0f >= -1.f) && (x0f <= 30.f);
            bool vy0 = (y0f >= 0.f) && (y0f <= 31.f);
            bool vy1 = (y0f >= -1.f) && (y0f <= 30.f);
            int ix0 = (int)fminf(fmaxf(x0f, 0.f), 31.f);
            int iy0 = (int)fminf(fmaxf(y0f, 0.f), 31.f);
            int ix1 = (int)fminf(fmaxf(x0f + 1.f, 0.f), 31.f);
            int iy1 = (int)fminf(fmaxf(y0f + 1.f, 0.f), 31.f);
            float w00 = (1.f - wx) * (1.f - wy) * ((vx0 && vy0) ? 1.f : 0.f);
            float w01 = wx * (1.f - wy) * ((vx1 && vy0) ? 1.f : 0.f);
            float w10 = (1.f - wx) * wy * ((vx0 && vy1) ? 1.f : 0.f);
            float w11 = wx * wy * ((vx1 && vy1) ? 1.f : 0.f);
            int t00 = iy0 * 32 + ix0, t01 = iy0 * 32 + ix1;
            int t10 = iy1 * 32 + ix0, t11 = iy1 * 32 + ix1;
            const float4* vb = (const float4*)(value_t) + (size_t)(l * 8 + m) * 2048;
            float4 a00 = vb[t00 * 2], b00 = vb[t00 * 2 + 1];
            float4 a01 = vb[t01 * 2], b01 = vb[t01 * 2 + 1];
            float4 a10 = vb[t10 * 2], b10 = vb[t10 * 2 + 1];
            float4 a11 = vb[t11 * 2], b11 = vb[t11 * 2 + 1];
            acc[0] = fmaf(wj, w00 * a00.x + w01 * a01.x + w10 * a10.x + w11 * a11.x, acc[0]);
            acc[1] = fmaf(wj, w00 * a00.y + w01 * a01.y + w10 * a10.y + w11 * a11.y, acc[1]);
            acc[2] = fmaf(wj, w00 * a00.z + w01 * a01.z + w10 * a10.z + w11 * a11.z, acc[2]);
            acc[3] = fmaf(wj, w00 * a00.w + w01 * a01.w + w10 * a10.w + w11 * a11.w, acc[3]);
            acc[4] = fmaf(wj, w00 * b00.x + w01 * b01.x + w10 * b10.x + w11 * b11.x, acc[4]);
            acc[5] = fmaf(wj, w00 * b00.y + w01 * b01.y + w10 * b10.y + w11 * b11.y, acc[5]);
            acc[6] = fmaf(wj, w00 * b00.z + w01 * b01.z + w10 * b10.z + w11 * b11.z, acc[6]);
            acc[7] = fmaf(wj, w00 * b00.w + w01 * b01.w + w10 * b10.w + w11 * b11.w, acc[7]);
        }
    }
#pragma unroll
    for (int dd = 0; dd < 8; ++dd) {
#pragma unroll
        for (int off = 32; off; off >>= 1) acc[dd] += __shfl_xor(acc[dd], off);
    }
    if (lane == 0) {
        unsigned short* op = attn_pad + (size_t)((y + 1) * 34 + x + 1) * 192 + f * 64 + m * 8;
        ushort4 s0, s1;
        s0.x = f2bf(acc[0]); s0.y = f2bf(acc[1]); s0.z = f2bf(acc[2]); s0.w = f2bf(acc[3]);
        s1.x = f2bf(acc[4]); s1.y = f2bf(acc[5]); s1.z = f2bf(acc[6]); s1.w = f2bf(acc[7]);
        *(ushort4*)(op) = s0;
        *(ushort4*)(op + 4) = s1;
    }
}

// ---------------------------------------------------------------------------
extern "C" void kernel_launch(void* const* d_in, const int* in_sizes, int n_in,
                              void* d_out, int out_size, void* d_ws, size_t ws_size,
                              hipStream_t stream) {
    const float* x      = (const float*)d_in[0];
    const float* flow_1 = (const float*)d_in[1];
    const float* flow_2 = (const float*)d_in[2];
    const float* flip_1 = (const float*)d_in[3];
    const float* flip_2 = (const float*)d_in[4];
    const float* vp0_w = (const float*)d_in[5];  const float* vp0_b = (const float*)d_in[6];
    const float* vp1_w = (const float*)d_in[7];  const float* vp1_b = (const float*)d_in[8];
    const float* so0_w = (const float*)d_in[9];  const float* so0_b = (const float*)d_in[10];
    const float* so1_w = (const float*)d_in[11]; const float* so1_b = (const float*)d_in[12];
    const float* so2_w = (const float*)d_in[13]; const float* so2_b = (const float*)d_in[14];
    const float* so3_w = (const float*)d_in[15]; const float* so3_b = (const float*)d_in[16];
    const float* aw0_w = (const float*)d_in[17]; const float* aw0_b = (const float*)d_in[18];
    const float* aw1_w = (const float*)d_in[19]; const float* aw1_b = (const float*)d_in[20];
    const float* aw2_w = (const float*)d_in[21]; const float* aw2_b = (const float*)d_in[22];
    const float* aw3_w = (const float*)d_in[23]; const float* aw3_b = (const float*)d_in[24];
    const float* op0_w = (const float*)d_in[25]; const float* op0_b = (const float*)d_in[26];
    const float* op1_w = (const float*)d_in[27]; const float* op1_b = (const float*)d_in[28];
    float* out = (float*)d_out;
    (void)ws_size; (void)in_sizes; (void)n_in; (void)out_size;

    // ---- workspace layout ----
    float* fws = (float*)d_ws;
    float* flow_cn2 = fws;                       // 2048
    float* flow_n2c = flow_cn2 + 2048;           // 2048
    float* value_t  = flow_n2c + 2048;           // 196608
    float* so_t     = value_t + 196608;          // 1769472
    unsigned short* uws = (unsigned short*)(so_t + 1769472);
    unsigned short* x_pad     = uws;                       // 1156*192
    unsigned short* vp0h      = x_pad + 1156 * 192;
    unsigned short* extra_pad = vp0h + 1156 * 192;         // 1156*480
    unsigned short* s1 = extra_pad + 1156 * 480;           // 1156*64 each
    unsigned short* a1 = s1 + 1156 * 64;
    unsigned short* s2 = a1 + 1156 * 64;
    unsigned short* a2 = s2 + 1156 * 64;
    unsigned short* attn_pad = a2 + 1156 * 64;             // 1156*192
    unsigned short* op0h     = attn_pad + 1156 * 192;      // 1156*192
    unsigned short* aw_t     = op0h + 1156 * 192;          // 3072*2592
    unsigned short* wgt      = aw_t + (size_t)3072 * 2592; // 14688*512

    // ---- 1. border zeroing of all padded buffers ----
    BorderP bp;
    bp.p[0] = x_pad;     bp.C[0] = 192;
    bp.p[1] = extra_pad; bp.C[1] = 480;
    bp.p[2] = vp0h;      bp.C[2] = 192;
    bp.p[3] = s1;        bp.C[3] = 64;
    bp.p[4] = a1;        bp.C[4] = 64;
    bp.p[5] = s2;        bp.C[5] = 64;
    bp.p[6] = a2;        bp.C[6] = 64;
    bp.p[7] = attn_pad;  bp.C[7] = 192;
    bp.p[8] = op0h;      bp.C[8] = 192;
    border_k<<<dim3(132, 9), 256, 0, stream>>>(bp);

    // ---- 2. weight transform (all convs, one launch) ----
    WXP wx;
    const int big = 1 << 30;
    wx.d[0] = {vp0_w, vp0_w, big, 192, 0, 192, 6, 0};       // vp0
    wx.d[1] = {vp1_w, vp1_w, big, 192, 0, 192, 6, 648};     // vp1
    wx.d[2] = {so0_w, aw0_w, 64, 64, 64, 460, 15, 1296};    // so0+aw0
    wx.d[3] = {so1_w, so1_w, big, 64, 0, 64, 2, 2376};
    wx.d[4] = {aw1_w, aw1_w, big, 64, 0, 64, 2, 2448};
    wx.d[5] = {so2_w, so2_w, big, 64, 0, 64, 2, 2520};
    wx.d[6] = {aw2_w, aw2_w, big, 64, 0, 64, 2, 2592};
    wx.d[7] = {so3_w, aw3_w, 1728, 1728, 7776, 64, 2, 2664};
    wx.d[8] = {op0_w, op0_w, big, 192, 0, 192, 6, 13392};
    wx.d[9] = {op1_w, op1_w, big, 192, 0, 192, 6, 14040};
    wxform_k<<<14688, 256, 0, stream>>>(wx, wgt);

    // ---- 3. flows / inputs ----
    compose_flows_k<<<4, 256, 0, stream>>>(flow_1, flow_2, flip_1, flip_2,
                                           flow_cn2, flow_n2c);
    xpad_k<<<192, 256, 0, stream>>>(x, x_pad);
    build_extra_k<<<480 * 1024 / 256, 256, 0, stream>>>(
        x, flow_1, flow_2, flip_1, flip_2, flow_cn2, flow_n2c, extra_pad);

    // ---- 4. convs ----
    ConvDesc cd_null = {nullptr, nullptr, nullptr, nullptr, 0, 0, 0, 0};
    {   // vp0: x_pad -> vp0h (bf16 padded), lrelu
        ConvDesc a = {x_pad, vp0_b, vp0h, nullptr, 3, 192, 192, 1};
        conv_mfma_k<<<dim3(3, 4), 256, 0, stream>>>(wgt + (size_t)0 * 512, 192, big, a, cd_null);
    }
    {   // vp1: vp0h -> value_t (fp32 cmod 8)
        ConvDesc a = {vp0h, vp1_b, value_t, nullptr, 1, 8, 192, 0};
        conv_mfma_k<<<dim3(3, 4), 256, 0, stream>>>(wgt + (size_t)648 * 512, 192, big, a, cd_null);
    }
    {   // so0 + aw0: extra_pad -> s1, a1 (bf16 padded), lrelu
        ConvDesc a = {extra_pad, so0_b, s1, nullptr, 3, 64, 64, 1};
        ConvDesc b = {extra_pad, aw0_b, a1, nullptr, 3, 64, 64, 1};
        conv_mfma_k<<<dim3(2, 4), 256, 0, stream>>>(wgt + (size_t)1296 * 512, 480, 64, a, b);
    }
    {   // so1 + aw1
        ConvDesc a = {s1, so1_b, s2, nullptr, 3, 64, 64, 1};
        ConvDesc b = {a1, aw1_b, a2, nullptr, 3, 64, 64, 1};
        conv_mfma_k<<<dim3(2, 4), 256, 0, stream>>>(wgt + (size_t)2376 * 512, 64, 64, a, b);
    }
    {   // so2 + aw2 (write back into s1/a1)
        ConvDesc a = {s2, so2_b, s1, nullptr, 3, 64, 64, 1};
        ConvDesc b = {a2, aw2_b, a1, nullptr, 3, 64, 64, 1};
        conv_mfma_k<<<dim3(2, 4), 256, 0, stream>>>(wgt + (size_t)2520 * 512, 64, 64, a, b);
    }
    {   // so3 (fp32 cmod 576) + aw3 (bf16 cmod 2592)
        ConvDesc a = {s1, so3_b, so_t, nullptr, 1, 576, 1728, 0};
        ConvDesc b = {a1, aw3_b, aw_t, nullptr, 2, 2592, 7776, 0};
        conv_mfma_k<<<dim3(149, 4), 256, 0, stream>>>(wgt + (size_t)2664 * 512, 64, 1728, a, b);
    }

    // ---- 5. deformable attention -> attn_pad (bf16 padded) ----
    deform_attn_k<<<24576 / 4, 256, 0, stream>>>(value_t, so_t, aw_t,
                                                 flow_1, flow_2, flip_1, flip_2,
                                                 flow_cn2, flow_n2c, attn_pad);

    // ---- 6. output projection + residual ----
    {   // op0: attn_pad -> op0h, lrelu
        ConvDesc a = {attn_pad, op0_b, op0h, nullptr, 3, 192, 192, 1};
        conv_mfma_k<<<dim3(3, 4), 256, 0, stream>>>(wgt + (size_t)13392 * 512, 192, big, a, cd_null);
    }
    {   // op1: op0h -> out (fp32 ch-major) + residual x
        ConvDesc a = {op0h, op1_b, out, x, 0, 0, 192, 0};
        conv_mfma_k<<<dim3(3, 4), 256, 0, stream>>>(wgt + (size_t)14040 * 512, 192, big, a, cd_null);
    }
}

// Round 4
// 519.161 us; speedup vs baseline: 5.7415x; 1.5699x over previous
//
#include <hip/hip_runtime.h>
#include <math.h>

#define HW 1024

typedef __attribute__((ext_vector_type(8))) short bf16x8;
typedef __attribute__((ext_vector_type(4))) float floatx4;

__device__ __forceinline__ unsigned short f2bf(float f) {
    unsigned u = __float_as_uint(f);
    u += 0x7FFF + ((u >> 16) & 1);
    return (unsigned short)(u >> 16);
}
__device__ __forceinline__ float bf2f(unsigned short u) {
    return __uint_as_float(((unsigned)u) << 16);
}

// ---------------------------------------------------------------------------
// Bilinear sample, zero padding, absolute pixel coords (matches reference).
// ---------------------------------------------------------------------------
__device__ __forceinline__ float bilin32(const float* __restrict__ img, float px, float py) {
    float x0f = floorf(px), y0f = floorf(py);
    float wx = px - x0f, wy = py - y0f;
    bool vx0 = (x0f >= 0.f) && (x0f <= 31.f);
    bool vx1 = (x0f >= -1.f) && (x0f <= 30.f);
    bool vy0 = (y0f >= 0.f) && (y0f <= 31.f);
    bool vy1 = (y0f >= -1.f) && (y0f <= 30.f);
    int ix0 = (int)fminf(fmaxf(x0f, 0.f), 31.f);
    int iy0 = (int)fminf(fmaxf(y0f, 0.f), 31.f);
    int ix1 = (int)fminf(fmaxf(x0f + 1.f, 0.f), 31.f);
    int iy1 = (int)fminf(fmaxf(y0f + 1.f, 0.f), 31.f);
    float w00 = (1.f - wx) * (1.f - wy) * ((vx0 && vy0) ? 1.f : 0.f);
    float w01 = wx * (1.f - wy) * ((vx1 && vy0) ? 1.f : 0.f);
    float w10 = (1.f - wx) * wy * ((vx0 && vy1) ? 1.f : 0.f);
    float w11 = wx * wy * ((vx1 && vy1) ? 1.f : 0.f);
    return w00 * img[iy0 * 32 + ix0] + w01 * img[iy0 * 32 + ix1] +
           w10 * img[iy1 * 32 + ix0] + w11 * img[iy1 * 32 + ix1];
}

// fa + warp(fb, fa) at pix
__device__ __forceinline__ float2 comp_flow(const float* __restrict__ fa,
                                            const float* __restrict__ fb, int pix) {
    int y = pix >> 5, x = pix & 31;
    float fx = fa[pix], fy = fa[HW + pix];
    float px = (float)x + fx, py = (float)y + fy;
    float2 r;
    r.x = fx + bilin32(fb, px, py);
    r.y = fy + bilin32(fb + HW, px, py);
    return r;
}

// ---------------------------------------------------------------------------
// Prep kernel: sections by blockIdx.x.
//  [0,192)      xpad: x -> x_pad bf16 [34*34][192]
//  [192,2112)   build_extra (flow composition inlined) -> extra_pad [34*34][480]
//  [2112,2128)  flow_cn2 / flow_n2c fp32 arrays (for deform_attn)
//  [2128,3760)  wxform: weights -> bf16 MFMA fragment order, coalesced
// ---------------------------------------------------------------------------
struct WD { const float* src; int cout, Cin, nCb, wbase, beg; };
struct PrepP {
    const float *x, *f1, *f2, *ff1, *ff2;
    float *fcn2, *fn2c;
    unsigned short *x_pad, *extra_pad, *wgt;
    WD wd[12];
};

__global__ __launch_bounds__(256) void prep_k(PrepP P) {
    __shared__ float wlds[16 * 288];
    const int b = blockIdx.x, tid = threadIdx.x;
    if (b < 192) {
        int idx = b * 256 + tid;                 // < 1024*48
        int pix = idx / 48, c4 = idx - pix * 48;
        int y = pix >> 5, xx = pix & 31;
        int c0 = c4 * 4;
        ushort4 s;
        s.x = f2bf(P.x[(size_t)(c0 + 0) * HW + pix]);
        s.y = f2bf(P.x[(size_t)(c0 + 1) * HW + pix]);
        s.z = f2bf(P.x[(size_t)(c0 + 2) * HW + pix]);
        s.w = f2bf(P.x[(size_t)(c0 + 3) * HW + pix]);
        *(ushort4*)(&P.x_pad[(size_t)((y + 1) * 34 + xx + 1) * 192 + c0]) = s;
    } else if (b < 2112) {
        int idx = (b - 192) * 256 + tid;         // < 480*1024
        int ch = idx >> 10, pix = idx & 1023;
        int y = pix >> 5, xx = pix & 31;
        float v = 0.f;
        if (ch < 64) {
            v = P.x[(size_t)ch * HW + pix];
        } else if (ch < 448) {
            int grp = (ch - 64) >> 6;
            int c = (ch - 64) & 63;
            const float* src;
            float fx, fy;
            if (grp == 0)      { src = P.x + 64 * HW;  fx = P.f1[pix];  fy = P.f1[HW + pix]; }
            else if (grp == 1) { src = P.x + 128 * HW; float2 r = comp_flow(P.f1, P.f2, pix);  fx = r.x; fy = r.y; }
            else if (grp == 2) { src = P.x;            fx = P.ff1[pix]; fy = P.ff1[HW + pix]; }
            else if (grp == 3) { src = P.x + 128 * HW; fx = P.f2[pix];  fy = P.f2[HW + pix]; }
            else if (grp == 4) { src = P.x + 64 * HW;  fx = P.ff2[pix]; fy = P.ff2[HW + pix]; }
            else               { src = P.x;            float2 r = comp_flow(P.ff2, P.ff1, pix); fx = r.x; fy = r.y; }
            v = bilin32(src + c * HW, (float)xx + fx, (float)y + fy);
        } else if (ch < 460) {
            int fc = ch - 448;
            int which = fc >> 1, comp = fc & 1;
            if (which == 0)      v = P.f1[comp * HW + pix];
            else if (which == 1) { float2 r = comp_flow(P.f1, P.f2, pix);  v = comp ? r.y : r.x; }
            else if (which == 2) v = P.ff1[comp * HW + pix];
            else if (which == 3) v = P.f2[comp * HW + pix];
            else if (which == 4) v = P.ff2[comp * HW + pix];
            else                 { float2 r = comp_flow(P.ff2, P.ff1, pix); v = comp ? r.y : r.x; }
        }
        P.extra_pad[(size_t)((y + 1) * 34 + xx + 1) * 480 + ch] = f2bf(v);
    } else if (b < 2128) {
        int idx = (b - 2112) * 256 + tid;
        if (idx < 1024) {
            float2 r = comp_flow(P.f1, P.f2, idx);
            P.fcn2[idx] = r.x; P.fcn2[HW + idx] = r.y;
        } else if (idx < 2048) {
            int pix = idx - 1024;
            float2 r = comp_flow(P.ff2, P.ff1, pix);
            P.fn2c[pix] = r.x; P.fn2c[HW + pix] = r.y;
        }
    } else {
        int blk = b - 2128;                      // < 1632
        int di = 0;
        while (di < 11 && blk >= P.wd[di + 1].beg) ++di;
        WD w = P.wd[di];
        int local = blk - w.beg;
        int co16 = local / w.nCb, cb = local - co16 * w.nCb;
        int cr0 = co16 * 16, ci0 = cb * 32;
        // coalesced load: 16 rows x 288 consecutive floats each
        for (int i = tid; i < 16 * 288; i += 256) {
            int cr = i / 288, o = i - cr * 288;
            int crg = cr0 + cr, ci = ci0 + o / 9;
            float v = (crg < w.cout && ci < w.Cin)
                ? w.src[((size_t)crg * w.Cin + ci0) * 9 + o] : 0.f;
            wlds[i] = v;
        }
        __syncthreads();
        // emit 9 fragment blocks of 512 bf16, coalesced
        for (int e = tid; e < 9 * 512; e += 256) {
            int t = e >> 9, idx = e & 511;
            int j = idx & 7, lane = idx >> 3, q = lane >> 4, mm = lane & 15;
            P.wgt[((size_t)w.wbase + ((size_t)co16 * 9 + t) * w.nCb + cb) * 512 + idx] =
                f2bf(wlds[mm * 288 + (q * 8 + j) * 9 + t]);
        }
    }
}

// ---------------------------------------------------------------------------
// MFMA 3x3 conv, multi-descriptor. Block = 64co x 256pix (4 waves, each
// 64co x 64pix = 4x4 acc of 16x16x32 bf16 MFMA). Grid (sum Mblocks, 4).
// Weights staged into LDS per K-chunk (36 KiB) alongside input tile (27 KiB).
// Output modes: 0 fp32 ch-major (+residual), 1 fp32 cmod, 2 bf16 cmod,
// 3 bf16 padded query-major (cmod = CpadOut).
// ---------------------------------------------------------------------------
struct CDesc {
    const unsigned short* in;
    const unsigned short* wgt;
    const float* bias;
    void* out;
    const float* residual;
    int Cpad, nCb, Cout, mode, cmod, relu, Mblocks;
};
struct CParam { CDesc d[4]; };

__global__ __launch_bounds__(256) void conv_mfma_k(CParam P) {
    __shared__ unsigned short blds[340 * 40];   // 10 rows x 34 cols x stride 40
    __shared__ unsigned short wlds[36 * 512];   // 4 co16 x 9 taps x 512
    int bx = blockIdx.x;
    int di = 0;
    while (bx >= P.d[di].Mblocks) { bx -= P.d[di].Mblocks; ++di; }
    const CDesc d = P.d[di];

    const int tid = threadIdx.x;
    const int w = tid >> 6, lane = tid & 63;
    const int lq = lane >> 4, ln = lane & 15;
    const int co0 = bx * 64;
    const int by = blockIdx.y, y0 = by * 8;
    const unsigned short* __restrict__ in = d.in;
    const unsigned short* __restrict__ wg = d.wgt;
    const int Cpad = d.Cpad, nCb = d.nCb;

    floatx4 acc[4][4];
#pragma unroll
    for (int mt = 0; mt < 4; ++mt)
#pragma unroll
        for (int nt = 0; nt < 4; ++nt)
            acc[mt][nt] = (floatx4){0.f, 0.f, 0.f, 0.f};

    for (int cb = 0; cb < nCb; ++cb) {
        __syncthreads();
        const int ci0 = cb << 5;
        // stage input tile: 10*34*4 chunks of 16 B
        for (int i = tid; i < 1360; i += 256) {
            int r = i / 136, rem = i - r * 136, c = rem >> 2, g = rem & 3;
            *(bf16x8*)(&blds[(r * 34 + c) * 40 + g * 8]) =
                *(const bf16x8*)(in + (size_t)((y0 + r) * 34 + c) * Cpad + ci0 + g * 8);
        }
        // stage weights: 36 fragment blocks x 64 lanes x 16 B
        for (int i = tid; i < 2304; i += 256) {
            int chunk = i >> 6, l16 = i & 63;
            int mt = chunk / 9, t = chunk - mt * 9;
            *(bf16x8*)(&wlds[chunk * 512 + l16 * 8]) =
                *(const bf16x8*)(wg + ((size_t)(((co0 >> 4) + mt) * 9 + t) * nCb + cb) * 512 + l16 * 8);
        }
        __syncthreads();
        for (int t = 0; t < 9; ++t) {
            const int dy = t / 3, dx = t - dy * 3;
            bf16x8 bfr[4];
#pragma unroll
            for (int nt = 0; nt < 4; ++nt) {
                int yy = w * 2 + (nt >> 1) + dy;
                int xx = (nt & 1) * 16 + ln + dx;
                bfr[nt] = *(const bf16x8*)(&blds[(yy * 34 + xx) * 40 + lq * 8]);
            }
#pragma unroll
            for (int mt = 0; mt < 4; ++mt) {
                bf16x8 afr = *(const bf16x8*)(&wlds[(mt * 9 + t) * 512 + lane * 8]);
#pragma unroll
                for (int nt = 0; nt < 4; ++nt)
                    acc[mt][nt] = __builtin_amdgcn_mfma_f32_16x16x32_bf16(afr, bfr[nt], acc[mt][nt], 0, 0, 0);
            }
        }
    }

#pragma unroll
    for (int mt = 0; mt < 4; ++mt) {
        const int co = co0 + mt * 16 + lq * 4;
        if (co >= d.Cout) continue;
        float bv[4];
#pragma unroll
        for (int r = 0; r < 4; ++r) bv[r] = d.bias[co + r];
#pragma unroll
        for (int nt = 0; nt < 4; ++nt) {
            const int pix = by * 256 + w * 64 + nt * 16 + ln;
            float v[4];
#pragma unroll
            for (int r = 0; r < 4; ++r) {
                float vv = acc[mt][nt][r] + bv[r];
                if (d.relu) vv = (vv >= 0.f) ? vv : 0.1f * vv;
                v[r] = vv;
            }
            if (d.mode == 0) {
                float* o = (float*)d.out;
#pragma unroll
                for (int r = 0; r < 4; ++r) {
                    float vv = v[r];
                    if (d.residual) vv += d.residual[(size_t)(co + r) * HW + pix];
                    o[(size_t)(co + r) * HW + pix] = vv;
                }
            } else if (d.mode == 1) {
                int fq = co / d.cmod, cc = co - fq * d.cmod;
                *(float4*)((float*)d.out + ((size_t)fq * HW + pix) * d.cmod + cc) =
                    make_float4(v[0], v[1], v[2], v[3]);
            } else if (d.mode == 2) {
                int fq = co / d.cmod, cc = co - fq * d.cmod;
                ushort4 s4;
                s4.x = f2bf(v[0]); s4.y = f2bf(v[1]); s4.z = f2bf(v[2]); s4.w = f2bf(v[3]);
                *(ushort4*)((unsigned short*)d.out + ((size_t)fq * HW + pix) * d.cmod + cc) = s4;
            } else {
                int yy = (pix >> 5) + 1, xx = (pix & 31) + 1;
                ushort4 s4;
                s4.x = f2bf(v[0]); s4.y = f2bf(v[1]); s4.z = f2bf(v[2]); s4.w = f2bf(v[3]);
                *(ushort4*)((unsigned short*)d.out + (size_t)(yy * 34 + xx) * d.cmod + co) = s4;
            }
        }
    }
}

// ---------------------------------------------------------------------------
// Deformable attention. One wave per (q, m). aw_t bf16 [q][2592],
// so_t fp32 [q][576], value_t fp32 [(l*8+m)*1024+pix][8].
// Writes attn_pad bf16 [34*34][192] interior.
// ---------------------------------------------------------------------------
__global__ __launch_bounds__(256) void deform_attn_k(
    const float* __restrict__ value_t, const float* __restrict__ so_t,
    const unsigned short* __restrict__ aw_t,
    const float* __restrict__ flow_1, const float* __restrict__ flow_2,
    const float* __restrict__ flip_flow_1, const float* __restrict__ flip_flow_2,
    const float* __restrict__ flow_cn2, const float* __restrict__ flow_n2c,
    unsigned short* __restrict__ attn_pad)
{
    const int wav = threadIdx.x >> 6;
    const int lane = threadIdx.x & 63;
    const int wid = blockIdx.x * 4 + wav;      // 0..24575
    const int q = wid >> 3, m = wid & 7;
    const int f = q >> 10, pix = q & 1023;
    const int y = pix >> 5, x = pix & 31;

    float flx0 = 0.f, fly0 = 0.f, flx1 = 0.f, fly1 = 0.f, flx2 = 0.f, fly2 = 0.f;
    if (f == 0) {
        flx1 = flow_1[pix];      fly1 = flow_1[HW + pix];
        flx2 = flow_cn2[pix];    fly2 = flow_cn2[HW + pix];
    } else if (f == 1) {
        flx0 = flip_flow_1[pix]; fly0 = flip_flow_1[HW + pix];
        flx2 = flow_2[pix];      fly2 = flow_2[HW + pix];
    } else {
        flx0 = flow_n2c[pix];    fly0 = flow_n2c[HW + pix];
        flx1 = flip_flow_2[pix]; fly1 = flip_flow_2[HW + pix];
    }

    const unsigned short* awp = aw_t + (size_t)q * 2592 + m * 324;
    float av[6];
    float vmax = -1e30f;
#pragma unroll
    for (int it = 0; it < 6; ++it) {
        int j = lane + it * 64;
        float a = (j < 324) ? bf2f(awp[j]) : -1e30f;
        av[it] = a;
        vmax = fmaxf(vmax, a);
    }
#pragma unroll
    for (int off = 32; off; off >>= 1) vmax = fmaxf(vmax, __shfl_xor(vmax, off));
    float ssum = 0.f;
#pragma unroll
    for (int it = 0; it < 6; ++it) {
        int j = lane + it * 64;
        float e = (j < 324) ? __expf(av[it] - vmax) : 0.f;
        av[it] = e;
        ssum += e;
    }
#pragma unroll
    for (int off = 32; off; off >>= 1) ssum += __shfl_xor(ssum, off);
    const float inv = 1.f / ssum;

    float acc[8];
#pragma unroll
    for (int dd = 0; dd < 8; ++dd) acc[dd] = 0.f;
    const float* sop = so_t + (size_t)q * 576 + m * 72;

#pragma unroll
    for (int it = 0; it < 6; ++it) {
        int j = lane + it * 64;
        if (j < 324) {
            float wj = av[it] * inv;
            int l = j / 108;
            int r = j - l * 108;
            int p = r / 9;
            int k = r - p * 9;
            float2 so2 = *(const float2*)(sop + (l * 12 + p) * 2);
            float fx = (l == 0) ? flx0 : (l == 1) ? flx1 : flx2;
            float fy = (l == 0) ? fly0 : (l == 1) ? fly1 : fly2;
            float pxf = (float)x + so2.x + fx + (float)(k / 3 - 1);
            float pyf = (float)y + so2.y + fy + (float)(k % 3 - 1);
            float x0f = floorf(pxf), y0f = floorf(pyf);
            float wx = pxf - x0f, wy = pyf - y0f;
            bool vx0 = (x0f >= 0.f) && (x0f <= 31.f);
            bool vx1 = (x0f >= -1.f) && (x0f <= 30.f);
            bool vy0 = (y0f >= 0.f) && (y0f <= 31.f);
            bool vy1 = (y0f >= -1.f) && (y0f <= 30.f);
            int ix0 = (int)fminf(fmaxf(x0f, 0.f), 31.f);
            int iy0 = (int)fminf(fmaxf(y0f, 0.f), 31.f);
            int ix1 = (int)fminf(fmaxf(x0f + 1.f, 0.f), 31.f);
            int iy1 = (int)fminf(fmaxf(y0f + 1.f, 0.f), 31.f);
            float w00 = (1.f - wx) * (1.f - wy) * ((vx0 && vy0) ? 1.f : 0.f);
            float w01 = wx * (1.f - wy) * ((vx1 && vy0) ? 1.f : 0.f);
            float w10 = (1.f - wx) * wy * ((vx0 && vy1) ? 1.f : 0.f);
            float w11 = wx * wy * ((vx1 && vy1) ? 1.f : 0.f);
            int t00 = iy0 * 32 + ix0, t01 = iy0 * 32 + ix1;
            int t10 = iy1 * 32 + ix0, t11 = iy1 * 32 + ix1;
            const float4* vb = (const float4*)(value_t) + (size_t)(l * 8 + m) * 2048;
            float4 a00 = vb[t00 * 2], b00 = vb[t00 * 2 + 1];
            float4 a01 = vb[t01 * 2], b01 = vb[t01 * 2 + 1];
            float4 a10 = vb[t10 * 2], b10 = vb[t10 * 2 + 1];
            float4 a11 = vb[t11 * 2], b11 = vb[t11 * 2 + 1];
            acc[0] = fmaf(wj, w00 * a00.x + w01 * a01.x + w10 * a10.x + w11 * a11.x, acc[0]);
            acc[1] = fmaf(wj, w00 * a00.y + w01 * a01.y + w10 * a10.y + w11 * a11.y, acc[1]);
            acc[2] = fmaf(wj, w00 * a00.z + w01 * a01.z + w10 * a10.z + w11 * a11.z, acc[2]);
            acc[3] = fmaf(wj, w00 * a00.w + w01 * a01.w + w10 * a10.w + w11 * a11.w, acc[3]);
            acc[4] = fmaf(wj, w00 * b00.x + w01 * b01.x + w10 * b10.x + w11 * b11.x, acc[4]);
            acc[5] = fmaf(wj, w00 * b00.y + w01 * b01.y + w10 * b10.y + w11 * b11.y, acc[5]);
            acc[6] = fmaf(wj, w00 * b00.z + w01 * b01.z + w10 * b10.z + w11 * b11.z, acc[6]);
            acc[7] = fmaf(wj, w00 * b00.w + w01 * b01.w + w10 * b10.w + w11 * b11.w, acc[7]);
        }
    }
#pragma unroll
    for (int dd = 0; dd < 8; ++dd) {
#pragma unroll
        for (int off = 32; off; off >>= 1) acc[dd] += __shfl_xor(acc[dd], off);
    }
    if (lane == 0) {
        unsigned short* op = attn_pad + (size_t)((y + 1) * 34 + x + 1) * 192 + f * 64 + m * 8;
        ushort4 s0, s1;
        s0.x = f2bf(acc[0]); s0.y = f2bf(acc[1]); s0.z = f2bf(acc[2]); s0.w = f2bf(acc[3]);
        s1.x = f2bf(acc[4]); s1.y = f2bf(acc[5]); s1.z = f2bf(acc[6]); s1.w = f2bf(acc[7]);
        *(ushort4*)(op) = s0;
        *(ushort4*)(op + 4) = s1;
    }
}

// ---------------------------------------------------------------------------
extern "C" void kernel_launch(void* const* d_in, const int* in_sizes, int n_in,
                              void* d_out, int out_size, void* d_ws, size_t ws_size,
                              hipStream_t stream) {
    const float* x      = (const float*)d_in[0];
    const float* flow_1 = (const float*)d_in[1];
    const float* flow_2 = (const float*)d_in[2];
    const float* flip_1 = (const float*)d_in[3];
    const float* flip_2 = (const float*)d_in[4];
    const float* vp0_w = (const float*)d_in[5];  const float* vp0_b = (const float*)d_in[6];
    const float* vp1_w = (const float*)d_in[7];  const float* vp1_b = (const float*)d_in[8];
    const float* so0_w = (const float*)d_in[9];  const float* so0_b = (const float*)d_in[10];
    const float* so1_w = (const float*)d_in[11]; const float* so1_b = (const float*)d_in[12];
    const float* so2_w = (const float*)d_in[13]; const float* so2_b = (const float*)d_in[14];
    const float* so3_w = (const float*)d_in[15]; const float* so3_b = (const float*)d_in[16];
    const float* aw0_w = (const float*)d_in[17]; const float* aw0_b = (const float*)d_in[18];
    const float* aw1_w = (const float*)d_in[19]; const float* aw1_b = (const float*)d_in[20];
    const float* aw2_w = (const float*)d_in[21]; const float* aw2_b = (const float*)d_in[22];
    const float* aw3_w = (const float*)d_in[23]; const float* aw3_b = (const float*)d_in[24];
    const float* op0_w = (const float*)d_in[25]; const float* op0_b = (const float*)d_in[26];
    const float* op1_w = (const float*)d_in[27]; const float* op1_b = (const float*)d_in[28];
    float* out = (float*)d_out;
    (void)ws_size; (void)in_sizes; (void)n_in; (void)out_size;

    // ---- workspace layout ----
    float* fws = (float*)d_ws;
    float* flow_cn2 = fws;                       // 2048
    float* flow_n2c = flow_cn2 + 2048;           // 2048
    float* value_t  = flow_n2c + 2048;           // 196608
    float* so_t     = value_t + 196608;          // 1769472
    unsigned short* uws = (unsigned short*)(so_t + 1769472);
    // bf16 padded buffers (contiguous: one memset zeroes borders of all)
    unsigned short* x_pad     = uws;                       // 1156*192
    unsigned short* vp0h      = x_pad + 1156 * 192;        // 1156*192
    unsigned short* extra_pad = vp0h + 1156 * 192;         // 1156*480
    unsigned short* s1 = extra_pad + 1156 * 480;           // 1156*64 x4
    unsigned short* a1 = s1 + 1156 * 64;
    unsigned short* s2 = a1 + 1156 * 64;
    unsigned short* a2 = s2 + 1156 * 64;
    unsigned short* attn_pad = a2 + 1156 * 64;             // 1156*192
    unsigned short* op0h     = attn_pad + 1156 * 192;      // 1156*192
    const size_t pad_shorts = (size_t)1156 * (192 * 4 + 480 + 64 * 4);
    unsigned short* aw_t = op0h + 1156 * 192;              // 3072*2592
    unsigned short* wgt  = aw_t + (size_t)3072 * 2592;     // 14688*512

    // ---- 1. zero all padded bf16 buffers (borders) in one memset ----
    hipMemsetAsync(x_pad, 0, pad_shorts * sizeof(unsigned short), stream);

    // ---- 2. prep: xpad + extra + flows + weight transform ----
    PrepP pp;
    pp.x = x; pp.f1 = flow_1; pp.f2 = flow_2; pp.ff1 = flip_1; pp.ff2 = flip_2;
    pp.fcn2 = flow_cn2; pp.fn2c = flow_n2c;
    pp.x_pad = x_pad; pp.extra_pad = extra_pad; pp.wgt = wgt;
    pp.wd[0]  = {vp0_w, 192, 192, 6,     0,    0};
    pp.wd[1]  = {vp1_w, 192, 192, 6,   648,   72};
    pp.wd[2]  = {so0_w,  64, 460, 15, 1296,  144};
    pp.wd[3]  = {aw0_w,  64, 460, 15, 1836,  204};
    pp.wd[4]  = {so1_w,  64,  64, 2,  2376,  264};
    pp.wd[5]  = {aw1_w,  64,  64, 2,  2448,  272};
    pp.wd[6]  = {so2_w,  64,  64, 2,  2520,  280};
    pp.wd[7]  = {aw2_w,  64,  64, 2,  2592,  288};
    pp.wd[8]  = {so3_w, 1728, 64, 2,  2664,  296};
    pp.wd[9]  = {aw3_w, 7776, 64, 2,  4608,  512};
    pp.wd[10] = {op0_w, 192, 192, 6, 13392, 1488};
    pp.wd[11] = {op1_w, 192, 192, 6, 14040, 1560};
    prep_k<<<3760, 256, 0, stream>>>(pp);

    const int BIG = 1 << 30;
    CDesc nul = {nullptr, nullptr, nullptr, nullptr, nullptr, 0, 0, 0, 0, 0, 0, BIG};

    // ---- 3. conv launches ----
    {   // L1: vp0 (x_pad->vp0h) + so0/aw0 (extra->s1/a1), all lrelu, mode 3
        CParam cp;
        cp.d[0] = {x_pad,     wgt + (size_t)0 * 512,    vp0_b, vp0h, nullptr, 192, 6,  192, 3, 192, 1, 3};
        cp.d[1] = {extra_pad, wgt + (size_t)1296 * 512, so0_b, s1,   nullptr, 480, 15, 64,  3, 64,  1, 1};
        cp.d[2] = {extra_pad, wgt + (size_t)1836 * 512, aw0_b, a1,   nullptr, 480, 15, 64,  3, 64,  1, 1};
        cp.d[3] = nul;
        conv_mfma_k<<<dim3(5, 4), 256, 0, stream>>>(cp);
    }
    {   // L2: vp1 (->value_t fp32 cmod8) + so1/aw1
        CParam cp;
        cp.d[0] = {vp0h, wgt + (size_t)648 * 512,  vp1_b, value_t, nullptr, 192, 6, 192, 1, 8,  0, 3};
        cp.d[1] = {s1,   wgt + (size_t)2376 * 512, so1_b, s2,      nullptr, 64,  2, 64,  3, 64, 1, 1};
        cp.d[2] = {a1,   wgt + (size_t)2448 * 512, aw1_b, a2,      nullptr, 64,  2, 64,  3, 64, 1, 1};
        cp.d[3] = nul;
        conv_mfma_k<<<dim3(5, 4), 256, 0, stream>>>(cp);
    }
    {   // L3: so2/aw2 (s2/a2 -> s1/a1)
        CParam cp;
        cp.d[0] = {s2, wgt + (size_t)2520 * 512, so2_b, s1, nullptr, 64, 2, 64, 3, 64, 1, 1};
        cp.d[1] = {a2, wgt + (size_t)2592 * 512, aw2_b, a1, nullptr, 64, 2, 64, 3, 64, 1, 1};
        cp.d[2] = nul; cp.d[3] = nul;
        conv_mfma_k<<<dim3(2, 4), 256, 0, stream>>>(cp);
    }
    {   // L4: so3 (fp32 cmod 576) + aw3 (bf16 cmod 2592)
        CParam cp;
        cp.d[0] = {s1, wgt + (size_t)2664 * 512, so3_b, so_t, nullptr, 64, 2, 1728, 1, 576,  0, 27};
        cp.d[1] = {a1, wgt + (size_t)4608 * 512, aw3_b, aw_t, nullptr, 64, 2, 7776, 2, 2592, 0, 122};
        cp.d[2] = nul; cp.d[3] = nul;
        conv_mfma_k<<<dim3(149, 4), 256, 0, stream>>>(cp);
    }

    // ---- 4. deformable attention -> attn_pad ----
    deform_attn_k<<<6144, 256, 0, stream>>>(value_t, so_t, aw_t,
                                            flow_1, flow_2, flip_1, flip_2,
                                            flow_cn2, flow_n2c, attn_pad);

    // ---- 5. output projection ----
    {   // op0: attn_pad -> op0h (lrelu)
        CParam cp;
        cp.d[0] = {attn_pad, wgt + (size_t)13392 * 512, op0_b, op0h, nullptr, 192, 6, 192, 3, 192, 1, 3};
        cp.d[1] = nul; cp.d[2] = nul; cp.d[3] = nul;
        conv_mfma_k<<<dim3(3, 4), 256, 0, stream>>>(cp);
    }
    {   // op1: op0h -> out (fp32 ch-major) + residual x
        CParam cp;
        cp.d[0] = {op0h, wgt + (size_t)14040 * 512, op1_b, out, x, 192, 6, 192, 0, 0, 0, 3};
        cp.d[1] = nul; cp.d[2] = nul; cp.d[3] = nul;
        conv_mfma_k<<<dim3(3, 4), 256, 0, stream>>>(cp);
    }
}

// Round 5
// 341.338 us; speedup vs baseline: 8.7327x; 1.5210x over previous
//
#include <hip/hip_runtime.h>
#include <math.h>

#define HW 1024

typedef __attribute__((ext_vector_type(8))) short bf16x8;
typedef __attribute__((ext_vector_type(4))) float floatx4;

__device__ __forceinline__ unsigned short f2bf(float f) {
    unsigned u = __float_as_uint(f);
    u += 0x7FFF + ((u >> 16) & 1);
    return (unsigned short)(u >> 16);
}
__device__ __forceinline__ float bf2f(unsigned short u) {
    return __uint_as_float(((unsigned)u) << 16);
}

// ---------------------------------------------------------------------------
// Bilinear sample, zero padding, absolute pixel coords (matches reference).
// ---------------------------------------------------------------------------
__device__ __forceinline__ float bilin32(const float* __restrict__ img, float px, float py) {
    float x0f = floorf(px), y0f = floorf(py);
    float wx = px - x0f, wy = py - y0f;
    bool vx0 = (x0f >= 0.f) && (x0f <= 31.f);
    bool vx1 = (x0f >= -1.f) && (x0f <= 30.f);
    bool vy0 = (y0f >= 0.f) && (y0f <= 31.f);
    bool vy1 = (y0f >= -1.f) && (y0f <= 30.f);
    int ix0 = (int)fminf(fmaxf(x0f, 0.f), 31.f);
    int iy0 = (int)fminf(fmaxf(y0f, 0.f), 31.f);
    int ix1 = (int)fminf(fmaxf(x0f + 1.f, 0.f), 31.f);
    int iy1 = (int)fminf(fmaxf(y0f + 1.f, 0.f), 31.f);
    float w00 = (1.f - wx) * (1.f - wy) * ((vx0 && vy0) ? 1.f : 0.f);
    float w01 = wx * (1.f - wy) * ((vx1 && vy0) ? 1.f : 0.f);
    float w10 = (1.f - wx) * wy * ((vx0 && vy1) ? 1.f : 0.f);
    float w11 = wx * wy * ((vx1 && vy1) ? 1.f : 0.f);
    return w00 * img[iy0 * 32 + ix0] + w01 * img[iy0 * 32 + ix1] +
           w10 * img[iy1 * 32 + ix0] + w11 * img[iy1 * 32 + ix1];
}

// fa + warp(fb, fa) at pix
__device__ __forceinline__ float2 comp_flow(const float* __restrict__ fa,
                                            const float* __restrict__ fb, int pix) {
    int y = pix >> 5, x = pix & 31;
    float fx = fa[pix], fy = fa[HW + pix];
    float px = (float)x + fx, py = (float)y + fy;
    float2 r;
    r.x = fx + bilin32(fb, px, py);
    r.y = fy + bilin32(fb + HW, px, py);
    return r;
}

// ---------------------------------------------------------------------------
// Prep kernel: sections by blockIdx.x.
//  [0,192)      xpad: x -> x_pad bf16 [34*34][192]
//  [192,2112)   build_extra (flow composition inlined) -> extra_pad [34*34][480]
//  [2112,2128)  flow_cn2 / flow_n2c fp32 arrays (for deform_attn)
//  [2128,3760)  wxform: weights -> bf16 MFMA fragment order, coalesced
// ---------------------------------------------------------------------------
struct WD { const float* src; int cout, Cin, nCb, wbase, beg; };
struct PrepP {
    const float *x, *f1, *f2, *ff1, *ff2;
    float *fcn2, *fn2c;
    unsigned short *x_pad, *extra_pad, *wgt;
    WD wd[12];
};

__global__ __launch_bounds__(256) void prep_k(PrepP P) {
    __shared__ float wlds[16 * 288];
    const int b = blockIdx.x, tid = threadIdx.x;
    if (b < 192) {
        int idx = b * 256 + tid;                 // < 1024*48
        int pix = idx / 48, c4 = idx - pix * 48;
        int y = pix >> 5, xx = pix & 31;
        int c0 = c4 * 4;
        ushort4 s;
        s.x = f2bf(P.x[(size_t)(c0 + 0) * HW + pix]);
        s.y = f2bf(P.x[(size_t)(c0 + 1) * HW + pix]);
        s.z = f2bf(P.x[(size_t)(c0 + 2) * HW + pix]);
        s.w = f2bf(P.x[(size_t)(c0 + 3) * HW + pix]);
        *(ushort4*)(&P.x_pad[(size_t)((y + 1) * 34 + xx + 1) * 192 + c0]) = s;
    } else if (b < 2112) {
        int idx = (b - 192) * 256 + tid;         // < 480*1024
        int ch = idx >> 10, pix = idx & 1023;
        int y = pix >> 5, xx = pix & 31;
        float v = 0.f;
        if (ch < 64) {
            v = P.x[(size_t)ch * HW + pix];
        } else if (ch < 448) {
            int grp = (ch - 64) >> 6;
            int c = (ch - 64) & 63;
            const float* src;
            float fx, fy;
            if (grp == 0)      { src = P.x + 64 * HW;  fx = P.f1[pix];  fy = P.f1[HW + pix]; }
            else if (grp == 1) { src = P.x + 128 * HW; float2 r = comp_flow(P.f1, P.f2, pix);  fx = r.x; fy = r.y; }
            else if (grp == 2) { src = P.x;            fx = P.ff1[pix]; fy = P.ff1[HW + pix]; }
            else if (grp == 3) { src = P.x + 128 * HW; fx = P.f2[pix];  fy = P.f2[HW + pix]; }
            else if (grp == 4) { src = P.x + 64 * HW;  fx = P.ff2[pix]; fy = P.ff2[HW + pix]; }
            else               { src = P.x;            float2 r = comp_flow(P.ff2, P.ff1, pix); fx = r.x; fy = r.y; }
            v = bilin32(src + c * HW, (float)xx + fx, (float)y + fy);
        } else if (ch < 460) {
            int fc = ch - 448;
            int which = fc >> 1, comp = fc & 1;
            if (which == 0)      v = P.f1[comp * HW + pix];
            else if (which == 1) { float2 r = comp_flow(P.f1, P.f2, pix);  v = comp ? r.y : r.x; }
            else if (which == 2) v = P.ff1[comp * HW + pix];
            else if (which == 3) v = P.f2[comp * HW + pix];
            else if (which == 4) v = P.ff2[comp * HW + pix];
            else                 { float2 r = comp_flow(P.ff2, P.ff1, pix); v = comp ? r.y : r.x; }
        }
        P.extra_pad[(size_t)((y + 1) * 34 + xx + 1) * 480 + ch] = f2bf(v);
    } else if (b < 2128) {
        int idx = (b - 2112) * 256 + tid;
        if (idx < 1024) {
            float2 r = comp_flow(P.f1, P.f2, idx);
            P.fcn2[idx] = r.x; P.fcn2[HW + idx] = r.y;
        } else if (idx < 2048) {
            int pix = idx - 1024;
            float2 r = comp_flow(P.ff2, P.ff1, pix);
            P.fn2c[pix] = r.x; P.fn2c[HW + pix] = r.y;
        }
    } else {
        int blk = b - 2128;                      // < 1632
        int di = 0;
        while (di < 11 && blk >= P.wd[di + 1].beg) ++di;
        WD w = P.wd[di];
        int local = blk - w.beg;
        int co16 = local / w.nCb, cb = local - co16 * w.nCb;
        int cr0 = co16 * 16, ci0 = cb * 32;
        // coalesced load: 16 rows x 288 consecutive floats each
        for (int i = tid; i < 16 * 288; i += 256) {
            int cr = i / 288, o = i - cr * 288;
            int crg = cr0 + cr, ci = ci0 + o / 9;
            float v = (crg < w.cout && ci < w.Cin)
                ? w.src[((size_t)crg * w.Cin + ci0) * 9 + o] : 0.f;
            wlds[i] = v;
        }
        __syncthreads();
        // emit 9 fragment blocks of 512 bf16, coalesced
        for (int e = tid; e < 9 * 512; e += 256) {
            int t = e >> 9, idx = e & 511;
            int j = idx & 7, lane = idx >> 3, q = lane >> 4, mm = lane & 15;
            P.wgt[((size_t)w.wbase + ((size_t)co16 * 9 + t) * w.nCb + cb) * 512 + idx] =
                f2bf(wlds[mm * 288 + (q * 8 + j) * 9 + t]);
        }
    }
}

// ---------------------------------------------------------------------------
// MFMA 3x3 conv, multi-descriptor, register-prefetch double-buffered.
// Template PIXROWS = pixel rows per block (8 -> 256 pix, grid y=4;
//                                          4 -> 128 pix, grid y=8).
// Block = 64co x (PIXROWS*32)pix, 4 waves. Wave tile 64co x (PIXROWS*8)pix.
// Weights + input tile staged in LDS per 32-ci chunk; next chunk's global
// loads are issued into registers before computing the current chunk.
// Output modes: 0 fp32 ch-major (+residual), 1 fp32 cmod, 2 bf16 cmod,
// 3 bf16 padded query-major (cmod = CpadOut).
// ---------------------------------------------------------------------------
struct CDesc {
    const unsigned short* in;
    const unsigned short* wgt;
    const float* bias;
    void* out;
    const float* residual;
    int Cpad, nCb, Cout, mode, cmod, relu, Mblocks;
};
struct CParam { CDesc d[4]; };

template<int PIXROWS>
__global__ __launch_bounds__(256) void conv_mfma_k(CParam P) {
    constexpr int TROWS = PIXROWS + 2;
    constexpr int TC = TROWS * 34 * 4;           // input 16B chunks per stage
    constexpr int ITRIPS = (TC + 255) / 256;
    constexpr int NTY = PIXROWS / 4;             // 2 or 1
    constexpr int NACC = NTY * 2;
    __shared__ unsigned short blds[TROWS * 34 * 40];
    __shared__ unsigned short wlds[36 * 512];

    int bx = blockIdx.x;
    int di = 0;
    while (bx >= P.d[di].Mblocks) { bx -= P.d[di].Mblocks; ++di; }
    const CDesc d = P.d[di];

    const int tid = threadIdx.x;
    const int w = tid >> 6, lane = tid & 63;
    const int lq = lane >> 4, ln = lane & 15;
    const int co0 = bx * 64;
    const int by = blockIdx.y, y0 = by * PIXROWS;
    const unsigned short* __restrict__ in = d.in;
    const unsigned short* __restrict__ wg = d.wgt;
    const int Cpad = d.Cpad, nCb = d.nCb;

    floatx4 acc[4][NACC];
#pragma unroll
    for (int mt = 0; mt < 4; ++mt)
#pragma unroll
        for (int nt = 0; nt < NACC; ++nt)
            acc[mt][nt] = (floatx4){0.f, 0.f, 0.f, 0.f};

    bf16x8 ireg[ITRIPS];
    bf16x8 wreg[9];

    // issue global loads for chunk cb into registers (batched, no LDS dep)
    auto load_regs = [&](int cb) {
        const int ci0 = cb << 5;
#pragma unroll
        for (int k = 0; k < ITRIPS; ++k) {
            int i = tid + k * 256;
            if (i < TC) {
                int r = i / 136, rem = i - r * 136, c = rem >> 2, g = rem & 3;
                ireg[k] = *(const bf16x8*)(in + (size_t)((y0 + r) * 34 + c) * Cpad + ci0 + g * 8);
            }
        }
#pragma unroll
        for (int k = 0; k < 9; ++k) {
            int i = tid + k * 256;
            int chunk = i >> 6, l16 = i & 63;
            int mt = chunk / 9, t = chunk - mt * 9;
            wreg[k] = *(const bf16x8*)(wg + ((size_t)(((co0 >> 4) + mt) * 9 + t) * nCb + cb) * 512 + l16 * 8);
        }
    };

    load_regs(0);

    for (int cb = 0; cb < nCb; ++cb) {
        __syncthreads();
        // registers -> LDS
#pragma unroll
        for (int k = 0; k < ITRIPS; ++k) {
            int i = tid + k * 256;
            if (i < TC) {
                int r = i / 136, rem = i - r * 136, c = rem >> 2, g = rem & 3;
                *(bf16x8*)(&blds[(r * 34 + c) * 40 + g * 8]) = ireg[k];
            }
        }
#pragma unroll
        for (int k = 0; k < 9; ++k) {
            int i = tid + k * 256;
            int chunk = i >> 6, l16 = i & 63;
            *(bf16x8*)(&wlds[chunk * 512 + l16 * 8]) = wreg[k];
        }
        __syncthreads();
        if (cb + 1 < nCb) load_regs(cb + 1);   // prefetch next chunk
        for (int t = 0; t < 9; ++t) {
            const int dy = t / 3, dx = t - dy * 3;
            bf16x8 bfr[NACC];
#pragma unroll
            for (int ty = 0; ty < NTY; ++ty)
#pragma unroll
                for (int tx = 0; tx < 2; ++tx) {
                    int yy = w * NTY + ty + dy;
                    int xx = tx * 16 + ln + dx;
                    bfr[ty * 2 + tx] = *(const bf16x8*)(&blds[(yy * 34 + xx) * 40 + lq * 8]);
                }
#pragma unroll
            for (int mt = 0; mt < 4; ++mt) {
                bf16x8 afr = *(const bf16x8*)(&wlds[(mt * 9 + t) * 512 + lane * 8]);
#pragma unroll
                for (int nt = 0; nt < NACC; ++nt)
                    acc[mt][nt] = __builtin_amdgcn_mfma_f32_16x16x32_bf16(afr, bfr[nt], acc[mt][nt], 0, 0, 0);
            }
        }
    }

#pragma unroll
    for (int mt = 0; mt < 4; ++mt) {
        const int co = co0 + mt * 16 + lq * 4;
        if (co >= d.Cout) continue;
        float bv[4];
#pragma unroll
        for (int r = 0; r < 4; ++r) bv[r] = d.bias[co + r];
#pragma unroll
        for (int nt = 0; nt < NACC; ++nt) {
            const int ty = nt >> 1, tx = nt & 1;
            const int pix = by * (PIXROWS * 32) + (w * NTY + ty) * 32 + tx * 16 + ln;
            float v[4];
#pragma unroll
            for (int r = 0; r < 4; ++r) {
                float vv = acc[mt][nt][r] + bv[r];
                if (d.relu) vv = (vv >= 0.f) ? vv : 0.1f * vv;
                v[r] = vv;
            }
            if (d.mode == 0) {
                float* o = (float*)d.out;
#pragma unroll
                for (int r = 0; r < 4; ++r) {
                    float vv = v[r];
                    if (d.residual) vv += d.residual[(size_t)(co + r) * HW + pix];
                    o[(size_t)(co + r) * HW + pix] = vv;
                }
            } else if (d.mode == 1) {
                int fq = co / d.cmod, cc = co - fq * d.cmod;
                *(float4*)((float*)d.out + ((size_t)fq * HW + pix) * d.cmod + cc) =
                    make_float4(v[0], v[1], v[2], v[3]);
            } else if (d.mode == 2) {
                int fq = co / d.cmod, cc = co - fq * d.cmod;
                ushort4 s4;
                s4.x = f2bf(v[0]); s4.y = f2bf(v[1]); s4.z = f2bf(v[2]); s4.w = f2bf(v[3]);
                *(ushort4*)((unsigned short*)d.out + ((size_t)fq * HW + pix) * d.cmod + cc) = s4;
            } else {
                int yy = (pix >> 5) + 1, xx = (pix & 31) + 1;
                ushort4 s4;
                s4.x = f2bf(v[0]); s4.y = f2bf(v[1]); s4.z = f2bf(v[2]); s4.w = f2bf(v[3]);
                *(ushort4*)((unsigned short*)d.out + (size_t)(yy * 34 + xx) * d.cmod + co) = s4;
            }
        }
    }
}

// ---------------------------------------------------------------------------
// Deformable attention. One wave per (q, m). aw_t bf16 [q][2592],
// so_t fp32 [q][576], value_t fp32 [(l*8+m)*1024+pix][8].
// Writes attn_pad bf16 [34*34][192] interior.
// ---------------------------------------------------------------------------
__global__ __launch_bounds__(256) void deform_attn_k(
    const float* __restrict__ value_t, const float* __restrict__ so_t,
    const unsigned short* __restrict__ aw_t,
    const float* __restrict__ flow_1, const float* __restrict__ flow_2,
    const float* __restrict__ flip_flow_1, const float* __restrict__ flip_flow_2,
    const float* __restrict__ flow_cn2, const float* __restrict__ flow_n2c,
    unsigned short* __restrict__ attn_pad)
{
    const int wav = threadIdx.x >> 6;
    const int lane = threadIdx.x & 63;
    const int wid = blockIdx.x * 4 + wav;      // 0..24575
    const int q = wid >> 3, m = wid & 7;
    const int f = q >> 10, pix = q & 1023;
    const int y = pix >> 5, x = pix & 31;

    float flx0 = 0.f, fly0 = 0.f, flx1 = 0.f, fly1 = 0.f, flx2 = 0.f, fly2 = 0.f;
    if (f == 0) {
        flx1 = flow_1[pix];      fly1 = flow_1[HW + pix];
        flx2 = flow_cn2[pix];    fly2 = flow_cn2[HW + pix];
    } else if (f == 1) {
        flx0 = flip_flow_1[pix]; fly0 = flip_flow_1[HW + pix];
        flx2 = flow_2[pix];      fly2 = flow_2[HW + pix];
    } else {
        flx0 = flow_n2c[pix];    fly0 = flow_n2c[HW + pix];
        flx1 = flip_flow_2[pix]; fly1 = flip_flow_2[HW + pix];
    }

    const unsigned short* awp = aw_t + (size_t)q * 2592 + m * 324;
    float av[6];
    float vmax = -1e30f;
#pragma unroll
    for (int it = 0; it < 6; ++it) {
        int j = lane + it * 64;
        float a = (j < 324) ? bf2f(awp[j]) : -1e30f;
        av[it] = a;
        vmax = fmaxf(vmax, a);
    }
#pragma unroll
    for (int off = 32; off; off >>= 1) vmax = fmaxf(vmax, __shfl_xor(vmax, off));
    float ssum = 0.f;
#pragma unroll
    for (int it = 0; it < 6; ++it) {
        int j = lane + it * 64;
        float e = (j < 324) ? __expf(av[it] - vmax) : 0.f;
        av[it] = e;
        ssum += e;
    }
#pragma unroll
    for (int off = 32; off; off >>= 1) ssum += __shfl_xor(ssum, off);
    const float inv = 1.f / ssum;

    float acc[8];
#pragma unroll
    for (int dd = 0; dd < 8; ++dd) acc[dd] = 0.f;
    const float* sop = so_t + (size_t)q * 576 + m * 72;

#pragma unroll
    for (int it = 0; it < 6; ++it) {
        int j = lane + it * 64;
        if (j < 324) {
            float wj = av[it] * inv;
            int l = j / 108;
            int r = j - l * 108;
            int p = r / 9;
            int k = r - p * 9;
            float2 so2 = *(const float2*)(sop + (l * 12 + p) * 2);
            float fx = (l == 0) ? flx0 : (l == 1) ? flx1 : flx2;
            float fy = (l == 0) ? fly0 : (l == 1) ? fly1 : fly2;
            float pxf = (float)x + so2.x + fx + (float)(k / 3 - 1);
            float pyf = (float)y + so2.y + fy + (float)(k % 3 - 1);
            float x0f = floorf(pxf), y0f = floorf(pyf);
            float wx = pxf - x0f, wy = pyf - y0f;
            bool vx0 = (x0f >= 0.f) && (x0f <= 31.f);
            bool vx1 = (x0f >= -1.f) && (x0f <= 30.f);
            bool vy0 = (y0f >= 0.f) && (y0f <= 31.f);
            bool vy1 = (y0f >= -1.f) && (y0f <= 30.f);
            int ix0 = (int)fminf(fmaxf(x0f, 0.f), 31.f);
            int iy0 = (int)fminf(fmaxf(y0f, 0.f), 31.f);
            int ix1 = (int)fminf(fmaxf(x0f + 1.f, 0.f), 31.f);
            int iy1 = (int)fminf(fmaxf(y0f + 1.f, 0.f), 31.f);
            float w00 = (1.f - wx) * (1.f - wy) * ((vx0 && vy0) ? 1.f : 0.f);
            float w01 = wx * (1.f - wy) * ((vx1 && vy0) ? 1.f : 0.f);
            float w10 = (1.f - wx) * wy * ((vx0 && vy1) ? 1.f : 0.f);
            float w11 = wx * wy * ((vx1 && vy1) ? 1.f : 0.f);
            int t00 = iy0 * 32 + ix0, t01 = iy0 * 32 + ix1;
            int t10 = iy1 * 32 + ix0, t11 = iy1 * 32 + ix1;
            const float4* vb = (const float4*)(value_t) + (size_t)(l * 8 + m) * 2048;
            float4 a00 = vb[t00 * 2], b00 = vb[t00 * 2 + 1];
            float4 a01 = vb[t01 * 2], b01 = vb[t01 * 2 + 1];
            float4 a10 = vb[t10 * 2], b10 = vb[t10 * 2 + 1];
            float4 a11 = vb[t11 * 2], b11 = vb[t11 * 2 + 1];
            acc[0] = fmaf(wj, w00 * a00.x + w01 * a01.x + w10 * a10.x + w11 * a11.x, acc[0]);
            acc[1] = fmaf(wj, w00 * a00.y + w01 * a01.y + w10 * a10.y + w11 * a11.y, acc[1]);
            acc[2] = fmaf(wj, w00 * a00.z + w01 * a01.z + w10 * a10.z + w11 * a11.z, acc[2]);
            acc[3] = fmaf(wj, w00 * a00.w + w01 * a01.w + w10 * a10.w + w11 * a11.w, acc[3]);
            acc[4] = fmaf(wj, w00 * b00.x + w01 * b01.x + w10 * b10.x + w11 * b11.x, acc[4]);
            acc[5] = fmaf(wj, w00 * b00.y + w01 * b01.y + w10 * b10.y + w11 * b11.y, acc[5]);
            acc[6] = fmaf(wj, w00 * b00.z + w01 * b01.z + w10 * b10.z + w11 * b11.z, acc[6]);
            acc[7] = fmaf(wj, w00 * b00.w + w01 * b01.w + w10 * b10.w + w11 * b11.w, acc[7]);
        }
    }
#pragma unroll
    for (int dd = 0; dd < 8; ++dd) {
#pragma unroll
        for (int off = 32; off; off >>= 1) acc[dd] += __shfl_xor(acc[dd], off);
    }
    if (lane == 0) {
        unsigned short* op = attn_pad + (size_t)((y + 1) * 34 + x + 1) * 192 + f * 64 + m * 8;
        ushort4 s0, s1;
        s0.x = f2bf(acc[0]); s0.y = f2bf(acc[1]); s0.z = f2bf(acc[2]); s0.w = f2bf(acc[3]);
        s1.x = f2bf(acc[4]); s1.y = f2bf(acc[5]); s1.z = f2bf(acc[6]); s1.w = f2bf(acc[7]);
        *(ushort4*)(op) = s0;
        *(ushort4*)(op + 4) = s1;
    }
}

// ---------------------------------------------------------------------------
extern "C" void kernel_launch(void* const* d_in, const int* in_sizes, int n_in,
                              void* d_out, int out_size, void* d_ws, size_t ws_size,
                              hipStream_t stream) {
    const float* x      = (const float*)d_in[0];
    const float* flow_1 = (const float*)d_in[1];
    const float* flow_2 = (const float*)d_in[2];
    const float* flip_1 = (const float*)d_in[3];
    const float* flip_2 = (const float*)d_in[4];
    const float* vp0_w = (const float*)d_in[5];  const float* vp0_b = (const float*)d_in[6];
    const float* vp1_w = (const float*)d_in[7];  const float* vp1_b = (const float*)d_in[8];
    const float* so0_w = (const float*)d_in[9];  const float* so0_b = (const float*)d_in[10];
    const float* so1_w = (const float*)d_in[11]; const float* so1_b = (const float*)d_in[12];
    const float* so2_w = (const float*)d_in[13]; const float* so2_b = (const float*)d_in[14];
    const float* so3_w = (const float*)d_in[15]; const float* so3_b = (const float*)d_in[16];
    const float* aw0_w = (const float*)d_in[17]; const float* aw0_b = (const float*)d_in[18];
    const float* aw1_w = (const float*)d_in[19]; const float* aw1_b = (const float*)d_in[20];
    const float* aw2_w = (const float*)d_in[21]; const float* aw2_b = (const float*)d_in[22];
    const float* aw3_w = (const float*)d_in[23]; const float* aw3_b = (const float*)d_in[24];
    const float* op0_w = (const float*)d_in[25]; const float* op0_b = (const float*)d_in[26];
    const float* op1_w = (const float*)d_in[27]; const float* op1_b = (const float*)d_in[28];
    float* out = (float*)d_out;
    (void)ws_size; (void)in_sizes; (void)n_in; (void)out_size;

    // ---- workspace layout ----
    float* fws = (float*)d_ws;
    float* flow_cn2 = fws;                       // 2048
    float* flow_n2c = flow_cn2 + 2048;           // 2048
    float* value_t  = flow_n2c + 2048;           // 196608
    float* so_t     = value_t + 196608;          // 1769472
    unsigned short* uws = (unsigned short*)(so_t + 1769472);
    // bf16 padded buffers (contiguous: one memset zeroes borders of all)
    unsigned short* x_pad     = uws;                       // 1156*192
    unsigned short* vp0h      = x_pad + 1156 * 192;        // 1156*192
    unsigned short* extra_pad = vp0h + 1156 * 192;         // 1156*480
    unsigned short* s1 = extra_pad + 1156 * 480;           // 1156*64 x4
    unsigned short* a1 = s1 + 1156 * 64;
    unsigned short* s2 = a1 + 1156 * 64;
    unsigned short* a2 = s2 + 1156 * 64;
    unsigned short* attn_pad = a2 + 1156 * 64;             // 1156*192
    unsigned short* op0h     = attn_pad + 1156 * 192;      // 1156*192
    const size_t pad_shorts = (size_t)1156 * (192 * 4 + 480 + 64 * 4);
    unsigned short* aw_t = op0h + 1156 * 192;              // 3072*2592
    unsigned short* wgt  = aw_t + (size_t)3072 * 2592;     // 14688*512

    // ---- 1. zero all padded bf16 buffers (borders) in one memset ----
    hipMemsetAsync(x_pad, 0, pad_shorts * sizeof(unsigned short), stream);

    // ---- 2. prep: xpad + extra + flows + weight transform ----
    PrepP pp;
    pp.x = x; pp.f1 = flow_1; pp.f2 = flow_2; pp.ff1 = flip_1; pp.ff2 = flip_2;
    pp.fcn2 = flow_cn2; pp.fn2c = flow_n2c;
    pp.x_pad = x_pad; pp.extra_pad = extra_pad; pp.wgt = wgt;
    pp.wd[0]  = {vp0_w, 192, 192, 6,     0,    0};
    pp.wd[1]  = {vp1_w, 192, 192, 6,   648,   72};
    pp.wd[2]  = {so0_w,  64, 460, 15, 1296,  144};
    pp.wd[3]  = {aw0_w,  64, 460, 15, 1836,  204};
    pp.wd[4]  = {so1_w,  64,  64, 2,  2376,  264};
    pp.wd[5]  = {aw1_w,  64,  64, 2,  2448,  272};
    pp.wd[6]  = {so2_w,  64,  64, 2,  2520,  280};
    pp.wd[7]  = {aw2_w,  64,  64, 2,  2592,  288};
    pp.wd[8]  = {so3_w, 1728, 64, 2,  2664,  296};
    pp.wd[9]  = {aw3_w, 7776, 64, 2,  4608,  512};
    pp.wd[10] = {op0_w, 192, 192, 6, 13392, 1488};
    pp.wd[11] = {op1_w, 192, 192, 6, 14040, 1560};
    prep_k<<<3760, 256, 0, stream>>>(pp);

    const int BIG = 1 << 30;
    CDesc nul = {nullptr, nullptr, nullptr, nullptr, nullptr, 0, 0, 0, 0, 0, 0, BIG};

    // ---- 3. conv launches ----
    {   // L1: vp0 (x_pad->vp0h) + so0/aw0 (extra->s1/a1), all lrelu, mode 3
        CParam cp;
        cp.d[0] = {x_pad,     wgt + (size_t)0 * 512,    vp0_b, vp0h, nullptr, 192, 6,  192, 3, 192, 1, 3};
        cp.d[1] = {extra_pad, wgt + (size_t)1296 * 512, so0_b, s1,   nullptr, 480, 15, 64,  3, 64,  1, 1};
        cp.d[2] = {extra_pad, wgt + (size_t)1836 * 512, aw0_b, a1,   nullptr, 480, 15, 64,  3, 64,  1, 1};
        cp.d[3] = nul;
        conv_mfma_k<4><<<dim3(5, 8), 256, 0, stream>>>(cp);
    }
    {   // L2: vp1 (->value_t fp32 cmod8) + so1/aw1
        CParam cp;
        cp.d[0] = {vp0h, wgt + (size_t)648 * 512,  vp1_b, value_t, nullptr, 192, 6, 192, 1, 8,  0, 3};
        cp.d[1] = {s1,   wgt + (size_t)2376 * 512, so1_b, s2,      nullptr, 64,  2, 64,  3, 64, 1, 1};
        cp.d[2] = {a1,   wgt + (size_t)2448 * 512, aw1_b, a2,      nullptr, 64,  2, 64,  3, 64, 1, 1};
        cp.d[3] = nul;
        conv_mfma_k<4><<<dim3(5, 8), 256, 0, stream>>>(cp);
    }
    {   // L3: so2/aw2 (s2/a2 -> s1/a1)
        CParam cp;
        cp.d[0] = {s2, wgt + (size_t)2520 * 512, so2_b, s1, nullptr, 64, 2, 64, 3, 64, 1, 1};
        cp.d[1] = {a2, wgt + (size_t)2592 * 512, aw2_b, a1, nullptr, 64, 2, 64, 3, 64, 1, 1};
        cp.d[2] = nul; cp.d[3] = nul;
        conv_mfma_k<4><<<dim3(2, 8), 256, 0, stream>>>(cp);
    }
    {   // L4: so3 (fp32 cmod 576) + aw3 (bf16 cmod 2592) — big, keep 256-pix blocks
        CParam cp;
        cp.d[0] = {s1, wgt + (size_t)2664 * 512, so3_b, so_t, nullptr, 64, 2, 1728, 1, 576,  0, 27};
        cp.d[1] = {a1, wgt + (size_t)4608 * 512, aw3_b, aw_t, nullptr, 64, 2, 7776, 2, 2592, 0, 122};
        cp.d[2] = nul; cp.d[3] = nul;
        conv_mfma_k<8><<<dim3(149, 4), 256, 0, stream>>>(cp);
    }

    // ---- 4. deformable attention -> attn_pad ----
    deform_attn_k<<<6144, 256, 0, stream>>>(value_t, so_t, aw_t,
                                            flow_1, flow_2, flip_1, flip_2,
                                            flow_cn2, flow_n2c, attn_pad);

    // ---- 5. output projection ----
    {   // op0: attn_pad -> op0h (lrelu)
        CParam cp;
        cp.d[0] = {attn_pad, wgt + (size_t)13392 * 512, op0_b, op0h, nullptr, 192, 6, 192, 3, 192, 1, 3};
        cp.d[1] = nul; cp.d[2] = nul; cp.d[3] = nul;
        conv_mfma_k<4><<<dim3(3, 8), 256, 0, stream>>>(cp);
    }
    {   // op1: op0h -> out (fp32 ch-major) + residual x
        CParam cp;
        cp.d[0] = {op0h, wgt + (size_t)14040 * 512, op1_b, out, x, 192, 6, 192, 0, 0, 0, 3};
        cp.d[1] = nul; cp.d[2] = nul; cp.d[3] = nul;
        conv_mfma_k<4><<<dim3(3, 8), 256, 0, stream>>>(cp);
    }
}

// Round 6
// 325.321 us; speedup vs baseline: 9.1626x; 1.0492x over previous
//
#include <hip/hip_runtime.h>
#include <math.h>

#define HW 1024

typedef __attribute__((ext_vector_type(8))) short bf16x8;
typedef __attribute__((ext_vector_type(4))) float floatx4;

__device__ __forceinline__ unsigned short f2bf(float f) {
    unsigned u = __float_as_uint(f);
    u += 0x7FFF + ((u >> 16) & 1);
    return (unsigned short)(u >> 16);
}
__device__ __forceinline__ float bf2f(unsigned short u) {
    return __uint_as_float(((unsigned)u) << 16);
}

// ---------------------------------------------------------------------------
// Bilinear sample, zero padding, absolute pixel coords (matches reference).
// ---------------------------------------------------------------------------
__device__ __forceinline__ float bilin32(const float* __restrict__ img, float px, float py) {
    float x0f = floorf(px), y0f = floorf(py);
    float wx = px - x0f, wy = py - y0f;
    bool vx0 = (x0f >= 0.f) && (x0f <= 31.f);
    bool vx1 = (x0f >= -1.f) && (x0f <= 30.f);
    bool vy0 = (y0f >= 0.f) && (y0f <= 31.f);
    bool vy1 = (y0f >= -1.f) && (y0f <= 30.f);
    int ix0 = (int)fminf(fmaxf(x0f, 0.f), 31.f);
    int iy0 = (int)fminf(fmaxf(y0f, 0.f), 31.f);
    int ix1 = (int)fminf(fmaxf(x0f + 1.f, 0.f), 31.f);
    int iy1 = (int)fminf(fmaxf(y0f + 1.f, 0.f), 31.f);
    float w00 = (1.f - wx) * (1.f - wy) * ((vx0 && vy0) ? 1.f : 0.f);
    float w01 = wx * (1.f - wy) * ((vx1 && vy0) ? 1.f : 0.f);
    float w10 = (1.f - wx) * wy * ((vx0 && vy1) ? 1.f : 0.f);
    float w11 = wx * wy * ((vx1 && vy1) ? 1.f : 0.f);
    return w00 * img[iy0 * 32 + ix0] + w01 * img[iy0 * 32 + ix1] +
           w10 * img[iy1 * 32 + ix0] + w11 * img[iy1 * 32 + ix1];
}

// fa + warp(fb, fa) at pix
__device__ __forceinline__ float2 comp_flow(const float* __restrict__ fa,
                                            const float* __restrict__ fb, int pix) {
    int y = pix >> 5, x = pix & 31;
    float fx = fa[pix], fy = fa[HW + pix];
    float px = (float)x + fx, py = (float)y + fy;
    float2 r;
    r.x = fx + bilin32(fb, px, py);
    r.y = fy + bilin32(fb + HW, px, py);
    return r;
}

// ---------------------------------------------------------------------------
// Prep kernel: sections by blockIdx.x.
//  [0,192)      xpad: x -> x_pad bf16 [34*34][192]
//  [192,2112)   build_extra (flow composition inlined) -> extra_pad [34*34][480]
//  [2112,2128)  flow_cn2 / flow_n2c fp32 arrays (for deform_attn)
//  [2128,3760)  wxform: weights -> bf16 MFMA fragment order, coalesced
// ---------------------------------------------------------------------------
struct WD { const float* src; int cout, Cin, nCb, wbase, beg; };
struct PrepP {
    const float *x, *f1, *f2, *ff1, *ff2;
    float *fcn2, *fn2c;
    unsigned short *x_pad, *extra_pad, *wgt;
    WD wd[12];
};

__global__ __launch_bounds__(256) void prep_k(PrepP P) {
    __shared__ float wlds[16 * 288];
    const int b = blockIdx.x, tid = threadIdx.x;
    if (b < 192) {
        int idx = b * 256 + tid;                 // < 1024*48
        int pix = idx / 48, c4 = idx - pix * 48;
        int y = pix >> 5, xx = pix & 31;
        int c0 = c4 * 4;
        ushort4 s;
        s.x = f2bf(P.x[(size_t)(c0 + 0) * HW + pix]);
        s.y = f2bf(P.x[(size_t)(c0 + 1) * HW + pix]);
        s.z = f2bf(P.x[(size_t)(c0 + 2) * HW + pix]);
        s.w = f2bf(P.x[(size_t)(c0 + 3) * HW + pix]);
        *(ushort4*)(&P.x_pad[(size_t)((y + 1) * 34 + xx + 1) * 192 + c0]) = s;
    } else if (b < 2112) {
        int idx = (b - 192) * 256 + tid;         // < 480*1024
        int ch = idx >> 10, pix = idx & 1023;
        int y = pix >> 5, xx = pix & 31;
        float v = 0.f;
        if (ch < 64) {
            v = P.x[(size_t)ch * HW + pix];
        } else if (ch < 448) {
            int grp = (ch - 64) >> 6;
            int c = (ch - 64) & 63;
            const float* src;
            float fx, fy;
            if (grp == 0)      { src = P.x + 64 * HW;  fx = P.f1[pix];  fy = P.f1[HW + pix]; }
            else if (grp == 1) { src = P.x + 128 * HW; float2 r = comp_flow(P.f1, P.f2, pix);  fx = r.x; fy = r.y; }
            else if (grp == 2) { src = P.x;            fx = P.ff1[pix]; fy = P.ff1[HW + pix]; }
            else if (grp == 3) { src = P.x + 128 * HW; fx = P.f2[pix];  fy = P.f2[HW + pix]; }
            else if (grp == 4) { src = P.x + 64 * HW;  fx = P.ff2[pix]; fy = P.ff2[HW + pix]; }
            else               { src = P.x;            float2 r = comp_flow(P.ff2, P.ff1, pix); fx = r.x; fy = r.y; }
            v = bilin32(src + c * HW, (float)xx + fx, (float)y + fy);
        } else if (ch < 460) {
            int fc = ch - 448;
            int which = fc >> 1, comp = fc & 1;
            if (which == 0)      v = P.f1[comp * HW + pix];
            else if (which == 1) { float2 r = comp_flow(P.f1, P.f2, pix);  v = comp ? r.y : r.x; }
            else if (which == 2) v = P.ff1[comp * HW + pix];
            else if (which == 3) v = P.f2[comp * HW + pix];
            else if (which == 4) v = P.ff2[comp * HW + pix];
            else                 { float2 r = comp_flow(P.ff2, P.ff1, pix); v = comp ? r.y : r.x; }
        }
        P.extra_pad[(size_t)((y + 1) * 34 + xx + 1) * 480 + ch] = f2bf(v);
    } else if (b < 2128) {
        int idx = (b - 2112) * 256 + tid;
        if (idx < 1024) {
            float2 r = comp_flow(P.f1, P.f2, idx);
            P.fcn2[idx] = r.x; P.fcn2[HW + idx] = r.y;
        } else if (idx < 2048) {
            int pix = idx - 1024;
            float2 r = comp_flow(P.ff2, P.ff1, pix);
            P.fn2c[pix] = r.x; P.fn2c[HW + pix] = r.y;
        }
    } else {
        int blk = b - 2128;                      // < 1632
        int di = 0;
        while (di < 11 && blk >= P.wd[di + 1].beg) ++di;
        WD w = P.wd[di];
        int local = blk - w.beg;
        int co16 = local / w.nCb, cb = local - co16 * w.nCb;
        int cr0 = co16 * 16, ci0 = cb * 32;
        // coalesced load: 16 rows x 288 consecutive floats each
        for (int i = tid; i < 16 * 288; i += 256) {
            int cr = i / 288, o = i - cr * 288;
            int crg = cr0 + cr, ci = ci0 + o / 9;
            float v = (crg < w.cout && ci < w.Cin)
                ? w.src[((size_t)crg * w.Cin + ci0) * 9 + o] : 0.f;
            wlds[i] = v;
        }
        __syncthreads();
        // emit 9 fragment blocks of 512 bf16, coalesced
        for (int e = tid; e < 9 * 512; e += 256) {
            int t = e >> 9, idx = e & 511;
            int j = idx & 7, lane = idx >> 3, q = lane >> 4, mm = lane & 15;
            P.wgt[((size_t)w.wbase + ((size_t)co16 * 9 + t) * w.nCb + cb) * 512 + idx] =
                f2bf(wlds[mm * 288 + (q * 8 + j) * 9 + t]);
        }
    }
}

// ---------------------------------------------------------------------------
// MFMA 3x3 conv, multi-descriptor, register-prefetch double-buffered.
// Output modes: 0 fp32 ch-major (+residual), 1 fp32 cmod, 2 bf16 cmod,
// 3 bf16 padded query-major (cmod = CpadOut).
// ---------------------------------------------------------------------------
struct CDesc {
    const unsigned short* in;
    const unsigned short* wgt;
    const float* bias;
    void* out;
    const float* residual;
    int Cpad, nCb, Cout, mode, cmod, relu, Mblocks;
};
struct CParam { CDesc d[4]; };

template<int PIXROWS>
__global__ __launch_bounds__(256) void conv_mfma_k(CParam P) {
    constexpr int TROWS = PIXROWS + 2;
    constexpr int TC = TROWS * 34 * 4;           // input 16B chunks per stage
    constexpr int ITRIPS = (TC + 255) / 256;
    constexpr int NTY = PIXROWS / 4;             // 2 or 1
    constexpr int NACC = NTY * 2;
    __shared__ unsigned short blds[TROWS * 34 * 40];
    __shared__ unsigned short wlds[36 * 512];

    int bx = blockIdx.x;
    int di = 0;
    while (bx >= P.d[di].Mblocks) { bx -= P.d[di].Mblocks; ++di; }
    const CDesc d = P.d[di];

    const int tid = threadIdx.x;
    const int w = tid >> 6, lane = tid & 63;
    const int lq = lane >> 4, ln = lane & 15;
    const int co0 = bx * 64;
    const int by = blockIdx.y, y0 = by * PIXROWS;
    const unsigned short* __restrict__ in = d.in;
    const unsigned short* __restrict__ wg = d.wgt;
    const int Cpad = d.Cpad, nCb = d.nCb;

    floatx4 acc[4][NACC];
#pragma unroll
    for (int mt = 0; mt < 4; ++mt)
#pragma unroll
        for (int nt = 0; nt < NACC; ++nt)
            acc[mt][nt] = (floatx4){0.f, 0.f, 0.f, 0.f};

    bf16x8 ireg[ITRIPS];
    bf16x8 wreg[9];

    auto load_regs = [&](int cb) {
        const int ci0 = cb << 5;
#pragma unroll
        for (int k = 0; k < ITRIPS; ++k) {
            int i = tid + k * 256;
            if (i < TC) {
                int r = i / 136, rem = i - r * 136, c = rem >> 2, g = rem & 3;
                ireg[k] = *(const bf16x8*)(in + (size_t)((y0 + r) * 34 + c) * Cpad + ci0 + g * 8);
            }
        }
#pragma unroll
        for (int k = 0; k < 9; ++k) {
            int i = tid + k * 256;
            int chunk = i >> 6, l16 = i & 63;
            int mt = chunk / 9, t = chunk - mt * 9;
            wreg[k] = *(const bf16x8*)(wg + ((size_t)(((co0 >> 4) + mt) * 9 + t) * nCb + cb) * 512 + l16 * 8);
        }
    };

    load_regs(0);

    for (int cb = 0; cb < nCb; ++cb) {
        __syncthreads();
#pragma unroll
        for (int k = 0; k < ITRIPS; ++k) {
            int i = tid + k * 256;
            if (i < TC) {
                int r = i / 136, rem = i - r * 136, c = rem >> 2, g = rem & 3;
                *(bf16x8*)(&blds[(r * 34 + c) * 40 + g * 8]) = ireg[k];
            }
        }
#pragma unroll
        for (int k = 0; k < 9; ++k) {
            int i = tid + k * 256;
            int chunk = i >> 6, l16 = i & 63;
            *(bf16x8*)(&wlds[chunk * 512 + l16 * 8]) = wreg[k];
        }
        __syncthreads();
        if (cb + 1 < nCb) load_regs(cb + 1);   // prefetch next chunk
        for (int t = 0; t < 9; ++t) {
            const int dy = t / 3, dx = t - dy * 3;
            bf16x8 bfr[NACC];
#pragma unroll
            for (int ty = 0; ty < NTY; ++ty)
#pragma unroll
                for (int tx = 0; tx < 2; ++tx) {
                    int yy = w * NTY + ty + dy;
                    int xx = tx * 16 + ln + dx;
                    bfr[ty * 2 + tx] = *(const bf16x8*)(&blds[(yy * 34 + xx) * 40 + lq * 8]);
                }
#pragma unroll
            for (int mt = 0; mt < 4; ++mt) {
                bf16x8 afr = *(const bf16x8*)(&wlds[(mt * 9 + t) * 512 + lane * 8]);
#pragma unroll
                for (int nt = 0; nt < NACC; ++nt)
                    acc[mt][nt] = __builtin_amdgcn_mfma_f32_16x16x32_bf16(afr, bfr[nt], acc[mt][nt], 0, 0, 0);
            }
        }
    }

#pragma unroll
    for (int mt = 0; mt < 4; ++mt) {
        const int co = co0 + mt * 16 + lq * 4;
        if (co >= d.Cout) continue;
        float bv[4];
#pragma unroll
        for (int r = 0; r < 4; ++r) bv[r] = d.bias[co + r];
#pragma unroll
        for (int nt = 0; nt < NACC; ++nt) {
            const int ty = nt >> 1, tx = nt & 1;
            const int pix = by * (PIXROWS * 32) + (w * NTY + ty) * 32 + tx * 16 + ln;
            float v[4];
#pragma unroll
            for (int r = 0; r < 4; ++r) {
                float vv = acc[mt][nt][r] + bv[r];
                if (d.relu) vv = (vv >= 0.f) ? vv : 0.1f * vv;
                v[r] = vv;
            }
            if (d.mode == 0) {
                float* o = (float*)d.out;
#pragma unroll
                for (int r = 0; r < 4; ++r) {
                    float vv = v[r];
                    if (d.residual) vv += d.residual[(size_t)(co + r) * HW + pix];
                    o[(size_t)(co + r) * HW + pix] = vv;
                }
            } else if (d.mode == 1) {
                int fq = co / d.cmod, cc = co - fq * d.cmod;
                *(float4*)((float*)d.out + ((size_t)fq * HW + pix) * d.cmod + cc) =
                    make_float4(v[0], v[1], v[2], v[3]);
            } else if (d.mode == 2) {
                int fq = co / d.cmod, cc = co - fq * d.cmod;
                ushort4 s4;
                s4.x = f2bf(v[0]); s4.y = f2bf(v[1]); s4.z = f2bf(v[2]); s4.w = f2bf(v[3]);
                *(ushort4*)((unsigned short*)d.out + ((size_t)fq * HW + pix) * d.cmod + cc) = s4;
            } else {
                int yy = (pix >> 5) + 1, xx = (pix & 31) + 1;
                ushort4 s4;
                s4.x = f2bf(v[0]); s4.y = f2bf(v[1]); s4.z = f2bf(v[2]); s4.w = f2bf(v[3]);
                *(ushort4*)((unsigned short*)d.out + (size_t)(yy * 34 + xx) * d.cmod + co) = s4;
            }
        }
    }
}

// ---------------------------------------------------------------------------
// Deformable attention, LDS-resident value. Grid: 384 blocks = 8 m x 48
// query-chunks (64 q each). Each block stages value for head m across all 3
// levels into LDS (bf16, 48 KiB), then its 4 waves process 64 (q,m) pairs.
// value_b bf16 [(l*8+m)*1024+pix][8]; aw_t bf16 [q][2592]; so_t fp32 [q][576].
// Writes attn_pad bf16 [34*34][192] interior.
// ---------------------------------------------------------------------------
__global__ __launch_bounds__(256) void deform_attn_k(
    const unsigned short* __restrict__ value_b, const float* __restrict__ so_t,
    const unsigned short* __restrict__ aw_t,
    const float* __restrict__ flow_1, const float* __restrict__ flow_2,
    const float* __restrict__ flip_flow_1, const float* __restrict__ flip_flow_2,
    const float* __restrict__ flow_cn2, const float* __restrict__ flow_n2c,
    unsigned short* __restrict__ attn_pad)
{
    __shared__ unsigned short vlds[3 * 1024 * 8];   // [l][pix][8] bf16, 48 KiB
    const int tid = threadIdx.x;
    const int wav = tid >> 6, lane = tid & 63;
    const int m = blockIdx.x & 7, qc = blockIdx.x >> 3;

    // stage value: 3 levels x 1024 pix x 16 B, fully coalesced
    for (int i = tid; i < 3072; i += 256) {
        int l = i >> 10, p = i & 1023;
        *(bf16x8*)(&vlds[(size_t)i * 8]) =
            *(const bf16x8*)(value_b + ((size_t)((l * 8 + m) * 1024) + p) * 8);
    }
    __syncthreads();

    for (int r = 0; r < 16; ++r) {
        const int q = qc * 64 + r * 4 + wav;
        const int f = q >> 10, pix = q & 1023;
        const int y = pix >> 5, x = pix & 31;

        float flx0 = 0.f, fly0 = 0.f, flx1 = 0.f, fly1 = 0.f, flx2 = 0.f, fly2 = 0.f;
        if (f == 0) {
            flx1 = flow_1[pix];      fly1 = flow_1[HW + pix];
            flx2 = flow_cn2[pix];    fly2 = flow_cn2[HW + pix];
        } else if (f == 1) {
            flx0 = flip_flow_1[pix]; fly0 = flip_flow_1[HW + pix];
            flx2 = flow_2[pix];      fly2 = flow_2[HW + pix];
        } else {
            flx0 = flow_n2c[pix];    fly0 = flow_n2c[HW + pix];
            flx1 = flip_flow_2[pix]; fly1 = flip_flow_2[HW + pix];
        }

        // softmax over 324 logits (coalesced bf16 reads)
        const unsigned short* awp = aw_t + (size_t)q * 2592 + m * 324;
        float av[6];
        float vmax = -1e30f;
#pragma unroll
        for (int it = 0; it < 6; ++it) {
            int j = lane + it * 64;
            float a = (j < 324) ? bf2f(awp[j]) : -1e30f;
            av[it] = a;
            vmax = fmaxf(vmax, a);
        }
#pragma unroll
        for (int off = 32; off; off >>= 1) vmax = fmaxf(vmax, __shfl_xor(vmax, off));
        float ssum = 0.f;
#pragma unroll
        for (int it = 0; it < 6; ++it) {
            int j = lane + it * 64;
            float e = (j < 324) ? __expf(av[it] - vmax) : 0.f;
            av[it] = e;
            ssum += e;
        }
#pragma unroll
        for (int off = 32; off; off >>= 1) ssum += __shfl_xor(ssum, off);
        const float inv = 1.f / ssum;

        float acc[8];
#pragma unroll
        for (int dd = 0; dd < 8; ++dd) acc[dd] = 0.f;
        const float* sop = so_t + (size_t)q * 576 + m * 72;

#pragma unroll
        for (int it = 0; it < 6; ++it) {
            int j = lane + it * 64;
            if (j < 324) {
                float wj = av[it] * inv;
                int l = j / 108;
                int rr = j - l * 108;
                int p = rr / 9;
                int k = rr - p * 9;
                float2 so2 = *(const float2*)(sop + (l * 12 + p) * 2);
                float fx = (l == 0) ? flx0 : (l == 1) ? flx1 : flx2;
                float fy = (l == 0) ? fly0 : (l == 1) ? fly1 : fly2;
                float pxf = (float)x + so2.x + fx + (float)(k / 3 - 1);
                float pyf = (float)y + so2.y + fy + (float)(k % 3 - 1);
                float x0f = floorf(pxf), y0f = floorf(pyf);
                float wx = pxf - x0f, wy = pyf - y0f;
                bool vx0 = (x0f >= 0.f) && (x0f <= 31.f);
                bool vx1 = (x0f >= -1.f) && (x0f <= 30.f);
                bool vy0 = (y0f >= 0.f) && (y0f <= 31.f);
                bool vy1 = (y0f >= -1.f) && (y0f <= 30.f);
                int ix0 = (int)fminf(fmaxf(x0f, 0.f), 31.f);
                int iy0 = (int)fminf(fmaxf(y0f, 0.f), 31.f);
                int ix1 = (int)fminf(fmaxf(x0f + 1.f, 0.f), 31.f);
                int iy1 = (int)fminf(fmaxf(y0f + 1.f, 0.f), 31.f);
                float w00 = (1.f - wx) * (1.f - wy) * ((vx0 && vy0) ? 1.f : 0.f);
                float w01 = wx * (1.f - wy) * ((vx1 && vy0) ? 1.f : 0.f);
                float w10 = (1.f - wx) * wy * ((vx0 && vy1) ? 1.f : 0.f);
                float w11 = wx * wy * ((vx1 && vy1) ? 1.f : 0.f);
                int base = l * 1024;
                bf16x8 v00 = *(const bf16x8*)(&vlds[(size_t)(base + iy0 * 32 + ix0) * 8]);
                bf16x8 v01 = *(const bf16x8*)(&vlds[(size_t)(base + iy0 * 32 + ix1) * 8]);
                bf16x8 v10 = *(const bf16x8*)(&vlds[(size_t)(base + iy1 * 32 + ix0) * 8]);
                bf16x8 v11 = *(const bf16x8*)(&vlds[(size_t)(base + iy1 * 32 + ix1) * 8]);
#pragma unroll
                for (int dd = 0; dd < 8; ++dd) {
                    float s = w00 * bf2f((unsigned short)v00[dd])
                            + w01 * bf2f((unsigned short)v01[dd])
                            + w10 * bf2f((unsigned short)v10[dd])
                            + w11 * bf2f((unsigned short)v11[dd]);
                    acc[dd] = fmaf(wj, s, acc[dd]);
                }
            }
        }
#pragma unroll
        for (int dd = 0; dd < 8; ++dd) {
#pragma unroll
            for (int off = 32; off; off >>= 1) acc[dd] += __shfl_xor(acc[dd], off);
        }
        if (lane == 0) {
            unsigned short* op = attn_pad + (size_t)((y + 1) * 34 + x + 1) * 192 + f * 64 + m * 8;
            ushort4 s0, s1;
            s0.x = f2bf(acc[0]); s0.y = f2bf(acc[1]); s0.z = f2bf(acc[2]); s0.w = f2bf(acc[3]);
            s1.x = f2bf(acc[4]); s1.y = f2bf(acc[5]); s1.z = f2bf(acc[6]); s1.w = f2bf(acc[7]);
            *(ushort4*)(op) = s0;
            *(ushort4*)(op + 4) = s1;
        }
    }
}

// ---------------------------------------------------------------------------
extern "C" void kernel_launch(void* const* d_in, const int* in_sizes, int n_in,
                              void* d_out, int out_size, void* d_ws, size_t ws_size,
                              hipStream_t stream) {
    const float* x      = (const float*)d_in[0];
    const float* flow_1 = (const float*)d_in[1];
    const float* flow_2 = (const float*)d_in[2];
    const float* flip_1 = (const float*)d_in[3];
    const float* flip_2 = (const float*)d_in[4];
    const float* vp0_w = (const float*)d_in[5];  const float* vp0_b = (const float*)d_in[6];
    const float* vp1_w = (const float*)d_in[7];  const float* vp1_b = (const float*)d_in[8];
    const float* so0_w = (const float*)d_in[9];  const float* so0_b = (const float*)d_in[10];
    const float* so1_w = (const float*)d_in[11]; const float* so1_b = (const float*)d_in[12];
    const float* so2_w = (const float*)d_in[13]; const float* so2_b = (const float*)d_in[14];
    const float* so3_w = (const float*)d_in[15]; const float* so3_b = (const float*)d_in[16];
    const float* aw0_w = (const float*)d_in[17]; const float* aw0_b = (const float*)d_in[18];
    const float* aw1_w = (const float*)d_in[19]; const float* aw1_b = (const float*)d_in[20];
    const float* aw2_w = (const float*)d_in[21]; const float* aw2_b = (const float*)d_in[22];
    const float* aw3_w = (const float*)d_in[23]; const float* aw3_b = (const float*)d_in[24];
    const float* op0_w = (const float*)d_in[25]; const float* op0_b = (const float*)d_in[26];
    const float* op1_w = (const float*)d_in[27]; const float* op1_b = (const float*)d_in[28];
    float* out = (float*)d_out;
    (void)ws_size; (void)in_sizes; (void)n_in; (void)out_size;

    // ---- workspace layout ----
    float* fws = (float*)d_ws;
    float* flow_cn2 = fws;                       // 2048
    float* flow_n2c = flow_cn2 + 2048;           // 2048
    unsigned short* value_b = (unsigned short*)(flow_n2c + 2048); // 192*1024 bf16
    float* so_t     = (float*)(value_b + 196608);                 // 1769472 fp32
    unsigned short* uws = (unsigned short*)(so_t + 1769472);
    // bf16 padded buffers (contiguous: one memset zeroes borders of all)
    unsigned short* x_pad     = uws;                       // 1156*192
    unsigned short* vp0h      = x_pad + 1156 * 192;        // 1156*192
    unsigned short* extra_pad = vp0h + 1156 * 192;         // 1156*480
    unsigned short* s1 = extra_pad + 1156 * 480;           // 1156*64 x4
    unsigned short* a1 = s1 + 1156 * 64;
    unsigned short* s2 = a1 + 1156 * 64;
    unsigned short* a2 = s2 + 1156 * 64;
    unsigned short* attn_pad = a2 + 1156 * 64;             // 1156*192
    unsigned short* op0h     = attn_pad + 1156 * 192;      // 1156*192
    const size_t pad_shorts = (size_t)1156 * (192 * 4 + 480 + 64 * 4);
    unsigned short* aw_t = op0h + 1156 * 192;              // 3072*2592
    unsigned short* wgt  = aw_t + (size_t)3072 * 2592;     // 14688*512

    // ---- 1. zero all padded bf16 buffers (borders) in one memset ----
    hipMemsetAsync(x_pad, 0, pad_shorts * sizeof(unsigned short), stream);

    // ---- 2. prep: xpad + extra + flows + weight transform ----
    PrepP pp;
    pp.x = x; pp.f1 = flow_1; pp.f2 = flow_2; pp.ff1 = flip_1; pp.ff2 = flip_2;
    pp.fcn2 = flow_cn2; pp.fn2c = flow_n2c;
    pp.x_pad = x_pad; pp.extra_pad = extra_pad; pp.wgt = wgt;
    pp.wd[0]  = {vp0_w, 192, 192, 6,     0,    0};
    pp.wd[1]  = {vp1_w, 192, 192, 6,   648,   72};
    pp.wd[2]  = {so0_w,  64, 460, 15, 1296,  144};
    pp.wd[3]  = {aw0_w,  64, 460, 15, 1836,  204};
    pp.wd[4]  = {so1_w,  64,  64, 2,  2376,  264};
    pp.wd[5]  = {aw1_w,  64,  64, 2,  2448,  272};
    pp.wd[6]  = {so2_w,  64,  64, 2,  2520,  280};
    pp.wd[7]  = {aw2_w,  64,  64, 2,  2592,  288};
    pp.wd[8]  = {so3_w, 1728, 64, 2,  2664,  296};
    pp.wd[9]  = {aw3_w, 7776, 64, 2,  4608,  512};
    pp.wd[10] = {op0_w, 192, 192, 6, 13392, 1488};
    pp.wd[11] = {op1_w, 192, 192, 6, 14040, 1560};
    prep_k<<<3760, 256, 0, stream>>>(pp);

    const int BIG = 1 << 30;
    CDesc nul = {nullptr, nullptr, nullptr, nullptr, nullptr, 0, 0, 0, 0, 0, 0, BIG};

    // ---- 3. conv launches ----
    {   // L1: vp0 (x_pad->vp0h) + so0/aw0 (extra->s1/a1), all lrelu, mode 3
        CParam cp;
        cp.d[0] = {x_pad,     wgt + (size_t)0 * 512,    vp0_b, vp0h, nullptr, 192, 6,  192, 3, 192, 1, 3};
        cp.d[1] = {extra_pad, wgt + (size_t)1296 * 512, so0_b, s1,   nullptr, 480, 15, 64,  3, 64,  1, 1};
        cp.d[2] = {extra_pad, wgt + (size_t)1836 * 512, aw0_b, a1,   nullptr, 480, 15, 64,  3, 64,  1, 1};
        cp.d[3] = nul;
        conv_mfma_k<4><<<dim3(5, 8), 256, 0, stream>>>(cp);
    }
    {   // L2: vp1 (->value_b bf16 cmod8) + so1/aw1
        CParam cp;
        cp.d[0] = {vp0h, wgt + (size_t)648 * 512,  vp1_b, value_b, nullptr, 192, 6, 192, 2, 8,  0, 3};
        cp.d[1] = {s1,   wgt + (size_t)2376 * 512, so1_b, s2,      nullptr, 64,  2, 64,  3, 64, 1, 1};
        cp.d[2] = {a1,   wgt + (size_t)2448 * 512, aw1_b, a2,      nullptr, 64,  2, 64,  3, 64, 1, 1};
        cp.d[3] = nul;
        conv_mfma_k<4><<<dim3(5, 8), 256, 0, stream>>>(cp);
    }
    {   // L3: so2/aw2 (s2/a2 -> s1/a1)
        CParam cp;
        cp.d[0] = {s2, wgt + (size_t)2520 * 512, so2_b, s1, nullptr, 64, 2, 64, 3, 64, 1, 1};
        cp.d[1] = {a2, wgt + (size_t)2592 * 512, aw2_b, a1, nullptr, 64, 2, 64, 3, 64, 1, 1};
        cp.d[2] = nul; cp.d[3] = nul;
        conv_mfma_k<4><<<dim3(2, 8), 256, 0, stream>>>(cp);
    }
    {   // L4: so3 (fp32 cmod 576) + aw3 (bf16 cmod 2592) — big, 256-pix blocks
        CParam cp;
        cp.d[0] = {s1, wgt + (size_t)2664 * 512, so3_b, so_t, nullptr, 64, 2, 1728, 1, 576,  0, 27};
        cp.d[1] = {a1, wgt + (size_t)4608 * 512, aw3_b, aw_t, nullptr, 64, 2, 7776, 2, 2592, 0, 122};
        cp.d[2] = nul; cp.d[3] = nul;
        conv_mfma_k<8><<<dim3(149, 4), 256, 0, stream>>>(cp);
    }

    // ---- 4. deformable attention (LDS value) -> attn_pad ----
    deform_attn_k<<<384, 256, 0, stream>>>(value_b, so_t, aw_t,
                                           flow_1, flow_2, flip_1, flip_2,
                                           flow_cn2, flow_n2c, attn_pad);

    // ---- 5. output projection ----
    {   // op0: attn_pad -> op0h (lrelu)
        CParam cp;
        cp.d[0] = {attn_pad, wgt + (size_t)13392 * 512, op0_b, op0h, nullptr, 192, 6, 192, 3, 192, 1, 3};
        cp.d[1] = nul; cp.d[2] = nul; cp.d[3] = nul;
        conv_mfma_k<4><<<dim3(3, 8), 256, 0, stream>>>(cp);
    }
    {   // op1: op0h -> out (fp32 ch-major) + residual x
        CParam cp;
        cp.d[0] = {op0h, wgt + (size_t)14040 * 512, op1_b, out, x, 192, 6, 192, 0, 0, 0, 3};
        cp.d[1] = nul; cp.d[2] = nul; cp.d[3] = nul;
        conv_mfma_k<4><<<dim3(3, 8), 256, 0, stream>>>(cp);
    }
}

// Round 7
// 291.938 us; speedup vs baseline: 10.2103x; 1.1143x over previous
//
#include <hip/hip_runtime.h>
#include <math.h>

#define HW 1024

typedef __attribute__((ext_vector_type(8))) short bf16x8;
typedef __attribute__((ext_vector_type(4))) float floatx4;

__device__ __forceinline__ unsigned short f2bf(float f) {
    unsigned u = __float_as_uint(f);
    u += 0x7FFF + ((u >> 16) & 1);
    return (unsigned short)(u >> 16);
}
__device__ __forceinline__ float bf2f(unsigned short u) {
    return __uint_as_float(((unsigned)u) << 16);
}
__device__ __forceinline__ float bflo(unsigned u) { return __uint_as_float(u << 16); }
__device__ __forceinline__ float bfhi(unsigned u) { return __uint_as_float(u & 0xffff0000u); }

// ---------------------------------------------------------------------------
// Bilinear sample, zero padding, absolute pixel coords (matches reference).
// ---------------------------------------------------------------------------
__device__ __forceinline__ float bilin32(const float* __restrict__ img, float px, float py) {
    float x0f = floorf(px), y0f = floorf(py);
    float wx = px - x0f, wy = py - y0f;
    bool vx0 = (x0f >= 0.f) && (x0f <= 31.f);
    bool vx1 = (x0f >= -1.f) && (x0f <= 30.f);
    bool vy0 = (y0f >= 0.f) && (y0f <= 31.f);
    bool vy1 = (y0f >= -1.f) && (y0f <= 30.f);
    int ix0 = (int)fminf(fmaxf(x0f, 0.f), 31.f);
    int iy0 = (int)fminf(fmaxf(y0f, 0.f), 31.f);
    int ix1 = (int)fminf(fmaxf(x0f + 1.f, 0.f), 31.f);
    int iy1 = (int)fminf(fmaxf(y0f + 1.f, 0.f), 31.f);
    float w00 = (1.f - wx) * (1.f - wy) * ((vx0 && vy0) ? 1.f : 0.f);
    float w01 = wx * (1.f - wy) * ((vx1 && vy0) ? 1.f : 0.f);
    float w10 = (1.f - wx) * wy * ((vx0 && vy1) ? 1.f : 0.f);
    float w11 = wx * wy * ((vx1 && vy1) ? 1.f : 0.f);
    return w00 * img[iy0 * 32 + ix0] + w01 * img[iy0 * 32 + ix1] +
           w10 * img[iy1 * 32 + ix0] + w11 * img[iy1 * 32 + ix1];
}

// fa + warp(fb, fa) at pix
__device__ __forceinline__ float2 comp_flow(const float* __restrict__ fa,
                                            const float* __restrict__ fb, int pix) {
    int y = pix >> 5, x = pix & 31;
    float fx = fa[pix], fy = fa[HW + pix];
    float px = (float)x + fx, py = (float)y + fy;
    float2 r;
    r.x = fx + bilin32(fb, px, py);
    r.y = fy + bilin32(fb + HW, px, py);
    return r;
}

// ---------------------------------------------------------------------------
// Prep kernel: sections by blockIdx.x.
// ---------------------------------------------------------------------------
struct WD { const float* src; int cout, Cin, nCb, wbase, beg; };
struct PrepP {
    const float *x, *f1, *f2, *ff1, *ff2;
    float *fcn2, *fn2c;
    unsigned short *x_pad, *extra_pad, *wgt;
    WD wd[12];
};

__global__ __launch_bounds__(256) void prep_k(PrepP P) {
    __shared__ float wlds[16 * 288];
    const int b = blockIdx.x, tid = threadIdx.x;
    if (b < 192) {
        int idx = b * 256 + tid;                 // < 1024*48
        int pix = idx / 48, c4 = idx - pix * 48;
        int y = pix >> 5, xx = pix & 31;
        int c0 = c4 * 4;
        ushort4 s;
        s.x = f2bf(P.x[(size_t)(c0 + 0) * HW + pix]);
        s.y = f2bf(P.x[(size_t)(c0 + 1) * HW + pix]);
        s.z = f2bf(P.x[(size_t)(c0 + 2) * HW + pix]);
        s.w = f2bf(P.x[(size_t)(c0 + 3) * HW + pix]);
        *(ushort4*)(&P.x_pad[(size_t)((y + 1) * 34 + xx + 1) * 192 + c0]) = s;
    } else if (b < 2112) {
        int idx = (b - 192) * 256 + tid;         // < 480*1024
        int ch = idx >> 10, pix = idx & 1023;
        int y = pix >> 5, xx = pix & 31;
        float v = 0.f;
        if (ch < 64) {
            v = P.x[(size_t)ch * HW + pix];
        } else if (ch < 448) {
            int grp = (ch - 64) >> 6;
            int c = (ch - 64) & 63;
            const float* src;
            float fx, fy;
            if (grp == 0)      { src = P.x + 64 * HW;  fx = P.f1[pix];  fy = P.f1[HW + pix]; }
            else if (grp == 1) { src = P.x + 128 * HW; float2 r = comp_flow(P.f1, P.f2, pix);  fx = r.x; fy = r.y; }
            else if (grp == 2) { src = P.x;            fx = P.ff1[pix]; fy = P.ff1[HW + pix]; }
            else if (grp == 3) { src = P.x + 128 * HW; fx = P.f2[pix];  fy = P.f2[HW + pix]; }
            else if (grp == 4) { src = P.x + 64 * HW;  fx = P.ff2[pix]; fy = P.ff2[HW + pix]; }
            else               { src = P.x;            float2 r = comp_flow(P.ff2, P.ff1, pix); fx = r.x; fy = r.y; }
            v = bilin32(src + c * HW, (float)xx + fx, (float)y + fy);
        } else if (ch < 460) {
            int fc = ch - 448;
            int which = fc >> 1, comp = fc & 1;
            if (which == 0)      v = P.f1[comp * HW + pix];
            else if (which == 1) { float2 r = comp_flow(P.f1, P.f2, pix);  v = comp ? r.y : r.x; }
            else if (which == 2) v = P.ff1[comp * HW + pix];
            else if (which == 3) v = P.f2[comp * HW + pix];
            else if (which == 4) v = P.ff2[comp * HW + pix];
            else                 { float2 r = comp_flow(P.ff2, P.ff1, pix); v = comp ? r.y : r.x; }
        }
        P.extra_pad[(size_t)((y + 1) * 34 + xx + 1) * 480 + ch] = f2bf(v);
    } else if (b < 2128) {
        int idx = (b - 2112) * 256 + tid;
        if (idx < 1024) {
            float2 r = comp_flow(P.f1, P.f2, idx);
            P.fcn2[idx] = r.x; P.fcn2[HW + idx] = r.y;
        } else if (idx < 2048) {
            int pix = idx - 1024;
            float2 r = comp_flow(P.ff2, P.ff1, pix);
            P.fn2c[pix] = r.x; P.fn2c[HW + pix] = r.y;
        }
    } else {
        int blk = b - 2128;                      // < 1632
        int di = 0;
        while (di < 11 && blk >= P.wd[di + 1].beg) ++di;
        WD w = P.wd[di];
        int local = blk - w.beg;
        int co16 = local / w.nCb, cb = local - co16 * w.nCb;
        int cr0 = co16 * 16, ci0 = cb * 32;
        for (int i = tid; i < 16 * 288; i += 256) {
            int cr = i / 288, o = i - cr * 288;
            int crg = cr0 + cr, ci = ci0 + o / 9;
            float v = (crg < w.cout && ci < w.Cin)
                ? w.src[((size_t)crg * w.Cin + ci0) * 9 + o] : 0.f;
            wlds[i] = v;
        }
        __syncthreads();
        for (int e = tid; e < 9 * 512; e += 256) {
            int t = e >> 9, idx = e & 511;
            int j = idx & 7, lane = idx >> 3, q = lane >> 4, mm = lane & 15;
            P.wgt[((size_t)w.wbase + ((size_t)co16 * 9 + t) * w.nCb + cb) * 512 + idx] =
                f2bf(wlds[mm * 288 + (q * 8 + j) * 9 + t]);
        }
    }
}

// ---------------------------------------------------------------------------
// MFMA 3x3 conv, multi-descriptor, register-prefetch double-buffered.
// ---------------------------------------------------------------------------
struct CDesc {
    const unsigned short* in;
    const unsigned short* wgt;
    const float* bias;
    void* out;
    const float* residual;
    int Cpad, nCb, Cout, mode, cmod, relu, Mblocks;
};
struct CParam { CDesc d[4]; };

template<int PIXROWS>
__global__ __launch_bounds__(256) void conv_mfma_k(CParam P) {
    constexpr int TROWS = PIXROWS + 2;
    constexpr int TC = TROWS * 34 * 4;
    constexpr int ITRIPS = (TC + 255) / 256;
    constexpr int NTY = PIXROWS / 4;
    constexpr int NACC = NTY * 2;
    __shared__ unsigned short blds[TROWS * 34 * 40];
    __shared__ unsigned short wlds[36 * 512];

    int bx = blockIdx.x;
    int di = 0;
    while (bx >= P.d[di].Mblocks) { bx -= P.d[di].Mblocks; ++di; }
    const CDesc d = P.d[di];

    const int tid = threadIdx.x;
    const int w = tid >> 6, lane = tid & 63;
    const int lq = lane >> 4, ln = lane & 15;
    const int co0 = bx * 64;
    const int by = blockIdx.y, y0 = by * PIXROWS;
    const unsigned short* __restrict__ in = d.in;
    const unsigned short* __restrict__ wg = d.wgt;
    const int Cpad = d.Cpad, nCb = d.nCb;

    floatx4 acc[4][NACC];
#pragma unroll
    for (int mt = 0; mt < 4; ++mt)
#pragma unroll
        for (int nt = 0; nt < NACC; ++nt)
            acc[mt][nt] = (floatx4){0.f, 0.f, 0.f, 0.f};

    bf16x8 ireg[ITRIPS];
    bf16x8 wreg[9];

    auto load_regs = [&](int cb) {
        const int ci0 = cb << 5;
#pragma unroll
        for (int k = 0; k < ITRIPS; ++k) {
            int i = tid + k * 256;
            if (i < TC) {
                int r = i / 136, rem = i - r * 136, c = rem >> 2, g = rem & 3;
                ireg[k] = *(const bf16x8*)(in + (size_t)((y0 + r) * 34 + c) * Cpad + ci0 + g * 8);
            }
        }
#pragma unroll
        for (int k = 0; k < 9; ++k) {
            int i = tid + k * 256;
            int chunk = i >> 6, l16 = i & 63;
            int mt = chunk / 9, t = chunk - mt * 9;
            wreg[k] = *(const bf16x8*)(wg + ((size_t)(((co0 >> 4) + mt) * 9 + t) * nCb + cb) * 512 + l16 * 8);
        }
    };

    load_regs(0);

    for (int cb = 0; cb < nCb; ++cb) {
        __syncthreads();
#pragma unroll
        for (int k = 0; k < ITRIPS; ++k) {
            int i = tid + k * 256;
            if (i < TC) {
                int r = i / 136, rem = i - r * 136, c = rem >> 2, g = rem & 3;
                *(bf16x8*)(&blds[(r * 34 + c) * 40 + g * 8]) = ireg[k];
            }
        }
#pragma unroll
        for (int k = 0; k < 9; ++k) {
            int i = tid + k * 256;
            int chunk = i >> 6, l16 = i & 63;
            *(bf16x8*)(&wlds[chunk * 512 + l16 * 8]) = wreg[k];
        }
        __syncthreads();
        if (cb + 1 < nCb) load_regs(cb + 1);
        for (int t = 0; t < 9; ++t) {
            const int dy = t / 3, dx = t - dy * 3;
            bf16x8 bfr[NACC];
#pragma unroll
            for (int ty = 0; ty < NTY; ++ty)
#pragma unroll
                for (int tx = 0; tx < 2; ++tx) {
                    int yy = w * NTY + ty + dy;
                    int xx = tx * 16 + ln + dx;
                    bfr[ty * 2 + tx] = *(const bf16x8*)(&blds[(yy * 34 + xx) * 40 + lq * 8]);
                }
#pragma unroll
            for (int mt = 0; mt < 4; ++mt) {
                bf16x8 afr = *(const bf16x8*)(&wlds[(mt * 9 + t) * 512 + lane * 8]);
#pragma unroll
                for (int nt = 0; nt < NACC; ++nt)
                    acc[mt][nt] = __builtin_amdgcn_mfma_f32_16x16x32_bf16(afr, bfr[nt], acc[mt][nt], 0, 0, 0);
            }
        }
    }

#pragma unroll
    for (int mt = 0; mt < 4; ++mt) {
        const int co = co0 + mt * 16 + lq * 4;
        if (co >= d.Cout) continue;
        float bv[4];
#pragma unroll
        for (int r = 0; r < 4; ++r) bv[r] = d.bias[co + r];
#pragma unroll
        for (int nt = 0; nt < NACC; ++nt) {
            const int ty = nt >> 1, tx = nt & 1;
            const int pix = by * (PIXROWS * 32) + (w * NTY + ty) * 32 + tx * 16 + ln;
            float v[4];
#pragma unroll
            for (int r = 0; r < 4; ++r) {
                float vv = acc[mt][nt][r] + bv[r];
                if (d.relu) vv = (vv >= 0.f) ? vv : 0.1f * vv;
                v[r] = vv;
            }
            if (d.mode == 0) {
                float* o = (float*)d.out;
#pragma unroll
                for (int r = 0; r < 4; ++r) {
                    float vv = v[r];
                    if (d.residual) vv += d.residual[(size_t)(co + r) * HW + pix];
                    o[(size_t)(co + r) * HW + pix] = vv;
                }
            } else if (d.mode == 1) {
                int fq = co / d.cmod, cc = co - fq * d.cmod;
                *(float4*)((float*)d.out + ((size_t)fq * HW + pix) * d.cmod + cc) =
                    make_float4(v[0], v[1], v[2], v[3]);
            } else if (d.mode == 2) {
                int fq = co / d.cmod, cc = co - fq * d.cmod;
                ushort4 s4;
                s4.x = f2bf(v[0]); s4.y = f2bf(v[1]); s4.z = f2bf(v[2]); s4.w = f2bf(v[3]);
                *(ushort4*)((unsigned short*)d.out + ((size_t)fq * HW + pix) * d.cmod + cc) = s4;
            } else {
                int yy = (pix >> 5) + 1, xx = (pix & 31) + 1;
                ushort4 s4;
                s4.x = f2bf(v[0]); s4.y = f2bf(v[1]); s4.z = f2bf(v[2]); s4.w = f2bf(v[3]);
                *(ushort4*)((unsigned short*)d.out + (size_t)(yy * 34 + xx) * d.cmod + co) = s4;
            }
        }
    }
}

// ---------------------------------------------------------------------------
// Deformable attention v3: LDS value + patch-convolution gathers.
// Key identity: the 9 integer patch taps of one (l,p) point share a single
// fractional bilinear weight pair (wx,wy), so
//   sum_k a_k * bilinear(base+k) == sum over a 4x4 grid of c_g * V0[g]
// where c = conv2d(3x3 prob patch, 2x2 bilinear kernel) and V0 is the
// zero-padded value. Per patch: 16 gathers instead of 36.
// Grid: 768 blocks = 8 m x 96 chunks of 32 queries. 4 waves/block.
// Lanes = (patch pp=lane&15, quadrant gq=lane>>4); 3 patch iterations cover
// the 36 (l,p) patches; each lane gathers its 2x2 quadrant of the 4x4 grid.
// LDS: 48 KiB value + 3.4 KiB prob scratch -> 3 blocks/CU.
// ---------------------------------------------------------------------------
__global__ __launch_bounds__(256) void deform_attn_k(
    const unsigned short* __restrict__ value_b, const float* __restrict__ so_t,
    const unsigned short* __restrict__ aw_t,
    const float* __restrict__ flow_1, const float* __restrict__ flow_2,
    const float* __restrict__ flip_flow_1, const float* __restrict__ flip_flow_2,
    const float* __restrict__ flow_cn2, const float* __restrict__ flow_n2c,
    unsigned short* __restrict__ attn_pad)
{
    __shared__ unsigned short vlds[24576];        // [l][pix][8] bf16, 48 KiB
    __shared__ unsigned short pwlds[4][432];      // per-wave probs, rows of 12
    const int tid = threadIdx.x;
    const int wav = tid >> 6, lane = tid & 63;
    const int m = blockIdx.x & 7, qc = blockIdx.x >> 3;

    for (int i = tid; i < 3072; i += 256) {
        int l = i >> 10, p = i & 1023;
        *(bf16x8*)(&vlds[(size_t)i * 8]) =
            *(const bf16x8*)(value_b + ((size_t)((l * 8 + m) * 1024) + p) * 8);
    }
    __syncthreads();

    const int pp = lane & 15, gq = lane >> 4;
    const int gdy = (gq >> 1) * 2 - 1;            // -1 or +1
    const int gdx = (gq & 1) * 2 - 1;
    const bool selx = (gq & 1);                   // cols (2,3) vs (0,1)
    const bool sely = (gq >> 1);                  // rows (2,3) vs (0,1)

    for (int r = 0; r < 8; ++r) {
        const int q = qc * 32 + r * 4 + wav;
        const int f = q >> 10, pix = q & 1023;
        const int y = pix >> 5, x = pix & 31;

        float flx0 = 0.f, fly0 = 0.f, flx1 = 0.f, fly1 = 0.f, flx2 = 0.f, fly2 = 0.f;
        if (f == 0) {
            flx1 = flow_1[pix];      fly1 = flow_1[HW + pix];
            flx2 = flow_cn2[pix];    fly2 = flow_cn2[HW + pix];
        } else if (f == 1) {
            flx0 = flip_flow_1[pix]; fly0 = flip_flow_1[HW + pix];
            flx2 = flow_2[pix];      fly2 = flow_2[HW + pix];
        } else {
            flx0 = flow_n2c[pix];    fly0 = flow_n2c[HW + pix];
            flx1 = flip_flow_2[pix]; fly1 = flip_flow_2[HW + pix];
        }

        // ---- softmax over 324 logits ----
        const unsigned short* awp = aw_t + (size_t)q * 2592 + m * 324;
        float av[6];
        float vmax = -1e30f;
#pragma unroll
        for (int it = 0; it < 6; ++it) {
            int j = lane + it * 64;
            float a = (j < 324) ? bf2f(awp[j]) : -1e30f;
            av[it] = a;
            vmax = fmaxf(vmax, a);
        }
#pragma unroll
        for (int off = 32; off; off >>= 1) vmax = fmaxf(vmax, __shfl_xor(vmax, off));
        float ssum = 0.f;
#pragma unroll
        for (int it = 0; it < 6; ++it) {
            int j = lane + it * 64;
            float e = (j < 324) ? __expf(av[it] - vmax) : 0.f;
            av[it] = e;
            ssum += e;
        }
#pragma unroll
        for (int off = 32; off; off >>= 1) ssum += __shfl_xor(ssum, off);
        const float inv = 1.f / ssum;

        // scatter normalized probs to per-wave scratch (rows of 12 shorts)
#pragma unroll
        for (int it = 0; it < 6; ++it) {
            int j = lane + it * 64;
            if (j < 324) {
                int pi = j / 9, k = j - pi * 9;
                pwlds[wav][pi * 12 + k] = f2bf(av[it] * inv);
            }
        }

        // ---- patch-convolution gather ----
        float acc[8];
#pragma unroll
        for (int dd = 0; dd < 8; ++dd) acc[dd] = 0.f;
        const float* sop = so_t + (size_t)q * 576 + m * 72;

#pragma unroll
        for (int pt = 0; pt < 3; ++pt) {
            int pi = pt * 16 + pp;
            if (pi < 36) {
                int l = pi / 12;
                float2 so2 = *(const float2*)(sop + pi * 2);
                float fx = (l == 0) ? flx0 : (l == 1) ? flx1 : flx2;
                float fy = (l == 0) ? fly0 : (l == 1) ? fly1 : fly2;
                float bxf = (float)x + so2.x + fx;
                float byf = (float)y + so2.y + fy;
                float x0f = floorf(bxf), y0f = floorf(byf);
                float wx = bxf - x0f, wy = byf - y0f;
                float ax = 1.f - wx, ay = 1.f - wy;
                // clamp base for safe int math (full-OOB masked anyway)
                int x0 = (int)fminf(fmaxf(x0f, -2.f), 34.f);
                int y0 = (int)fminf(fmaxf(y0f, -2.f), 34.f);

                // probs a[k], k = kxidx*3 + kyidx  (k/3-1 is x-offset!)
                const unsigned short* pr = &pwlds[wav][pi * 12];
                uint2 pv0 = *(const uint2*)(pr);
                uint2 pv1 = *(const uint2*)(pr + 4);
                float a0 = bflo(pv0.x), a1 = bfhi(pv0.x), a2 = bflo(pv0.y);
                float a3 = bfhi(pv0.y), a4 = bflo(pv1.x), a5 = bfhi(pv1.x);
                float a6 = bflo(pv1.y), a7 = bfhi(pv1.y), a8 = bf2f(pr[8]);

                // horizontal conv over kx (x-offset = k/3): rows indexed by ky
                // row ky: A0=a[0*3+ky], A1=a[1*3+ky], A2=a[2*3+ky]
                float bs0a, bs0b, bs1a, bs1b, bs2a, bs2b;
                {
                    float b0, b1, b2, b3;
                    b0 = a0 * ax; b1 = a0 * wx + a3 * ax; b2 = a3 * wx + a6 * ax; b3 = a6 * wx;
                    bs0a = selx ? b2 : b0; bs0b = selx ? b3 : b1;
                    b0 = a1 * ax; b1 = a1 * wx + a4 * ax; b2 = a4 * wx + a7 * ax; b3 = a7 * wx;
                    bs1a = selx ? b2 : b0; bs1b = selx ? b3 : b1;
                    b0 = a2 * ax; b1 = a2 * wx + a5 * ax; b2 = a5 * wx + a8 * ax; b3 = a8 * wx;
                    bs2a = selx ? b2 : b0; bs2b = selx ? b3 : b1;
                }
                // vertical conv over ky for the 2 selected columns
                float c00, c01, c10, c11;   // c[sy][sx]
                {
                    float c0 = bs0a * ay, c1 = bs0a * wy + bs1a * ay;
                    float c2 = bs1a * wy + bs2a * ay, c3 = bs2a * wy;
                    c00 = sely ? c2 : c0; c10 = sely ? c3 : c1;
                    c0 = bs0b * ay; c1 = bs0b * wy + bs1b * ay;
                    c2 = bs1b * wy + bs2b * ay; c3 = bs2b * wy;
                    c01 = sely ? c2 : c0; c11 = sely ? c3 : c1;
                }
                float cg[2][2] = {{c00, c01}, {c10, c11}};
                const int vbase = l * 1024;
#pragma unroll
                for (int sy = 0; sy < 2; ++sy) {
#pragma unroll
                    for (int sx = 0; sx < 2; ++sx) {
                        int dy = gdy + sy, dx = gdx + sx;
                        float pyf = y0f + (float)dy, pxf = x0f + (float)dx;
                        bool v = (pxf >= 0.f) && (pxf <= 31.f) && (pyf >= 0.f) && (pyf <= 31.f);
                        int px = min(max(x0 + dx, 0), 31);
                        int py = min(max(y0 + dy, 0), 31);
                        float c = cg[sy][sx] * (v ? 1.f : 0.f);
                        uint4 vv = *(const uint4*)(&vlds[(size_t)(vbase + py * 32 + px) * 8]);
                        acc[0] = fmaf(c, bflo(vv.x), acc[0]);
                        acc[1] = fmaf(c, bfhi(vv.x), acc[1]);
                        acc[2] = fmaf(c, bflo(vv.y), acc[2]);
                        acc[3] = fmaf(c, bfhi(vv.y), acc[3]);
                        acc[4] = fmaf(c, bflo(vv.z), acc[4]);
                        acc[5] = fmaf(c, bfhi(vv.z), acc[5]);
                        acc[6] = fmaf(c, bflo(vv.w), acc[6]);
                        acc[7] = fmaf(c, bfhi(vv.w), acc[7]);
                    }
                }
            }
        }

#pragma unroll
        for (int dd = 0; dd < 8; ++dd) {
#pragma unroll
            for (int off = 32; off; off >>= 1) acc[dd] += __shfl_xor(acc[dd], off);
        }
        if (lane == 0) {
            unsigned short* op = attn_pad + (size_t)((y + 1) * 34 + x + 1) * 192 + f * 64 + m * 8;
            ushort4 s0, s1;
            s0.x = f2bf(acc[0]); s0.y = f2bf(acc[1]); s0.z = f2bf(acc[2]); s0.w = f2bf(acc[3]);
            s1.x = f2bf(acc[4]); s1.y = f2bf(acc[5]); s1.z = f2bf(acc[6]); s1.w = f2bf(acc[7]);
            *(ushort4*)(op) = s0;
            *(ushort4*)(op + 4) = s1;
        }
    }
}

// ---------------------------------------------------------------------------
extern "C" void kernel_launch(void* const* d_in, const int* in_sizes, int n_in,
                              void* d_out, int out_size, void* d_ws, size_t ws_size,
                              hipStream_t stream) {
    const float* x      = (const float*)d_in[0];
    const float* flow_1 = (const float*)d_in[1];
    const float* flow_2 = (const float*)d_in[2];
    const float* flip_1 = (const float*)d_in[3];
    const float* flip_2 = (const float*)d_in[4];
    const float* vp0_w = (const float*)d_in[5];  const float* vp0_b = (const float*)d_in[6];
    const float* vp1_w = (const float*)d_in[7];  const float* vp1_b = (const float*)d_in[8];
    const float* so0_w = (const float*)d_in[9];  const float* so0_b = (const float*)d_in[10];
    const float* so1_w = (const float*)d_in[11]; const float* so1_b = (const float*)d_in[12];
    const float* so2_w = (const float*)d_in[13]; const float* so2_b = (const float*)d_in[14];
    const float* so3_w = (const float*)d_in[15]; const float* so3_b = (const float*)d_in[16];
    const float* aw0_w = (const float*)d_in[17]; const float* aw0_b = (const float*)d_in[18];
    const float* aw1_w = (const float*)d_in[19]; const float* aw1_b = (const float*)d_in[20];
    const float* aw2_w = (const float*)d_in[21]; const float* aw2_b = (const float*)d_in[22];
    const float* aw3_w = (const float*)d_in[23]; const float* aw3_b = (const float*)d_in[24];
    const float* op0_w = (const float*)d_in[25]; const float* op0_b = (const float*)d_in[26];
    const float* op1_w = (const float*)d_in[27]; const float* op1_b = (const float*)d_in[28];
    float* out = (float*)d_out;
    (void)ws_size; (void)in_sizes; (void)n_in; (void)out_size;

    // ---- workspace layout ----
    float* fws = (float*)d_ws;
    float* flow_cn2 = fws;                       // 2048
    float* flow_n2c = flow_cn2 + 2048;           // 2048
    unsigned short* value_b = (unsigned short*)(flow_n2c + 2048); // 192*1024 bf16
    float* so_t     = (float*)(value_b + 196608);                 // 1769472 fp32
    unsigned short* uws = (unsigned short*)(so_t + 1769472);
    unsigned short* x_pad     = uws;                       // 1156*192
    unsigned short* vp0h      = x_pad + 1156 * 192;        // 1156*192
    unsigned short* extra_pad = vp0h + 1156 * 192;         // 1156*480
    unsigned short* s1 = extra_pad + 1156 * 480;           // 1156*64 x4
    unsigned short* a1 = s1 + 1156 * 64;
    unsigned short* s2 = a1 + 1156 * 64;
    unsigned short* a2 = s2 + 1156 * 64;
    unsigned short* attn_pad = a2 + 1156 * 64;             // 1156*192
    unsigned short* op0h     = attn_pad + 1156 * 192;      // 1156*192
    const size_t pad_shorts = (size_t)1156 * (192 * 4 + 480 + 64 * 4);
    unsigned short* aw_t = op0h + 1156 * 192;              // 3072*2592
    unsigned short* wgt  = aw_t + (size_t)3072 * 2592;     // 14688*512

    hipMemsetAsync(x_pad, 0, pad_shorts * sizeof(unsigned short), stream);

    PrepP pp;
    pp.x = x; pp.f1 = flow_1; pp.f2 = flow_2; pp.ff1 = flip_1; pp.ff2 = flip_2;
    pp.fcn2 = flow_cn2; pp.fn2c = flow_n2c;
    pp.x_pad = x_pad; pp.extra_pad = extra_pad; pp.wgt = wgt;
    pp.wd[0]  = {vp0_w, 192, 192, 6,     0,    0};
    pp.wd[1]  = {vp1_w, 192, 192, 6,   648,   72};
    pp.wd[2]  = {so0_w,  64, 460, 15, 1296,  144};
    pp.wd[3]  = {aw0_w,  64, 460, 15, 1836,  204};
    pp.wd[4]  = {so1_w,  64,  64, 2,  2376,  264};
    pp.wd[5]  = {aw1_w,  64,  64, 2,  2448,  272};
    pp.wd[6]  = {so2_w,  64,  64, 2,  2520,  280};
    pp.wd[7]  = {aw2_w,  64,  64, 2,  2592,  288};
    pp.wd[8]  = {so3_w, 1728, 64, 2,  2664,  296};
    pp.wd[9]  = {aw3_w, 7776, 64, 2,  4608,  512};
    pp.wd[10] = {op0_w, 192, 192, 6, 13392, 1488};
    pp.wd[11] = {op1_w, 192, 192, 6, 14040, 1560};
    prep_k<<<3760, 256, 0, stream>>>(pp);

    const int BIG = 1 << 30;
    CDesc nul = {nullptr, nullptr, nullptr, nullptr, nullptr, 0, 0, 0, 0, 0, 0, BIG};

    {   // L1: vp0 + so0/aw0
        CParam cp;
        cp.d[0] = {x_pad,     wgt + (size_t)0 * 512,    vp0_b, vp0h, nullptr, 192, 6,  192, 3, 192, 1, 3};
        cp.d[1] = {extra_pad, wgt + (size_t)1296 * 512, so0_b, s1,   nullptr, 480, 15, 64,  3, 64,  1, 1};
        cp.d[2] = {extra_pad, wgt + (size_t)1836 * 512, aw0_b, a1,   nullptr, 480, 15, 64,  3, 64,  1, 1};
        cp.d[3] = nul;
        conv_mfma_k<4><<<dim3(5, 8), 256, 0, stream>>>(cp);
    }
    {   // L2: vp1 (->value_b bf16 cmod8) + so1/aw1
        CParam cp;
        cp.d[0] = {vp0h, wgt + (size_t)648 * 512,  vp1_b, value_b, nullptr, 192, 6, 192, 2, 8,  0, 3};
        cp.d[1] = {s1,   wgt + (size_t)2376 * 512, so1_b, s2,      nullptr, 64,  2, 64,  3, 64, 1, 1};
        cp.d[2] = {a1,   wgt + (size_t)2448 * 512, aw1_b, a2,      nullptr, 64,  2, 64,  3, 64, 1, 1};
        cp.d[3] = nul;
        conv_mfma_k<4><<<dim3(5, 8), 256, 0, stream>>>(cp);
    }
    {   // L3: so2/aw2
        CParam cp;
        cp.d[0] = {s2, wgt + (size_t)2520 * 512, so2_b, s1, nullptr, 64, 2, 64, 3, 64, 1, 1};
        cp.d[1] = {a2, wgt + (size_t)2592 * 512, aw2_b, a1, nullptr, 64, 2, 64, 3, 64, 1, 1};
        cp.d[2] = nul; cp.d[3] = nul;
        conv_mfma_k<4><<<dim3(2, 8), 256, 0, stream>>>(cp);
    }
    {   // L4: so3 (fp32 cmod 576) + aw3 (bf16 cmod 2592)
        CParam cp;
        cp.d[0] = {s1, wgt + (size_t)2664 * 512, so3_b, so_t, nullptr, 64, 2, 1728, 1, 576,  0, 27};
        cp.d[1] = {a1, wgt + (size_t)4608 * 512, aw3_b, aw_t, nullptr, 64, 2, 7776, 2, 2592, 0, 122};
        cp.d[2] = nul; cp.d[3] = nul;
        conv_mfma_k<8><<<dim3(149, 4), 256, 0, stream>>>(cp);
    }

    // deformable attention (patch-conv, 768 blocks)
    deform_attn_k<<<768, 256, 0, stream>>>(value_b, so_t, aw_t,
                                           flow_1, flow_2, flip_1, flip_2,
                                           flow_cn2, flow_n2c, attn_pad);

    {   // op0
        CParam cp;
        cp.d[0] = {attn_pad, wgt + (size_t)13392 * 512, op0_b, op0h, nullptr, 192, 6, 192, 3, 192, 1, 3};
        cp.d[1] = nul; cp.d[2] = nul; cp.d[3] = nul;
        conv_mfma_k<4><<<dim3(3, 8), 256, 0, stream>>>(cp);
    }
    {   // op1 + residual
        CParam cp;
        cp.d[0] = {op0h, wgt + (size_t)14040 * 512, op1_b, out, x, 192, 6, 192, 0, 0, 0, 3};
        cp.d[1] = nul; cp.d[2] = nul; cp.d[3] = nul;
        conv_mfma_k<4><<<dim3(3, 8), 256, 0, stream>>>(cp);
    }
}

// Round 8
// 269.924 us; speedup vs baseline: 11.0431x; 1.0816x over previous
//
#include <hip/hip_runtime.h>
#include <math.h>

#define HW 1024

typedef __attribute__((ext_vector_type(8))) short bf16x8;
typedef __attribute__((ext_vector_type(4))) float floatx4;

__device__ __forceinline__ unsigned short f2bf(float f) {
    unsigned u = __float_as_uint(f);
    u += 0x7FFF + ((u >> 16) & 1);
    return (unsigned short)(u >> 16);
}
__device__ __forceinline__ float bf2f(unsigned short u) {
    return __uint_as_float(((unsigned)u) << 16);
}
__device__ __forceinline__ float bflo(unsigned u) { return __uint_as_float(u << 16); }
__device__ __forceinline__ float bfhi(unsigned u) { return __uint_as_float(u & 0xffff0000u); }

// ---------------------------------------------------------------------------
// Bilinear sample, zero padding, absolute pixel coords (matches reference).
// ---------------------------------------------------------------------------
__device__ __forceinline__ float bilin32(const float* __restrict__ img, float px, float py) {
    float x0f = floorf(px), y0f = floorf(py);
    float wx = px - x0f, wy = py - y0f;
    bool vx0 = (x0f >= 0.f) && (x0f <= 31.f);
    bool vx1 = (x0f >= -1.f) && (x0f <= 30.f);
    bool vy0 = (y0f >= 0.f) && (y0f <= 31.f);
    bool vy1 = (y0f >= -1.f) && (y0f <= 30.f);
    int ix0 = (int)fminf(fmaxf(x0f, 0.f), 31.f);
    int iy0 = (int)fminf(fmaxf(y0f, 0.f), 31.f);
    int ix1 = (int)fminf(fmaxf(x0f + 1.f, 0.f), 31.f);
    int iy1 = (int)fminf(fmaxf(y0f + 1.f, 0.f), 31.f);
    float w00 = (1.f - wx) * (1.f - wy) * ((vx0 && vy0) ? 1.f : 0.f);
    float w01 = wx * (1.f - wy) * ((vx1 && vy0) ? 1.f : 0.f);
    float w10 = (1.f - wx) * wy * ((vx0 && vy1) ? 1.f : 0.f);
    float w11 = wx * wy * ((vx1 && vy1) ? 1.f : 0.f);
    return w00 * img[iy0 * 32 + ix0] + w01 * img[iy0 * 32 + ix1] +
           w10 * img[iy1 * 32 + ix0] + w11 * img[iy1 * 32 + ix1];
}

// fa + warp(fb, fa) at pix
__device__ __forceinline__ float2 comp_flow(const float* __restrict__ fa,
                                            const float* __restrict__ fb, int pix) {
    int y = pix >> 5, x = pix & 31;
    float fx = fa[pix], fy = fa[HW + pix];
    float px = (float)x + fx, py = (float)y + fy;
    float2 r;
    r.x = fx + bilin32(fb, px, py);
    r.y = fy + bilin32(fb + HW, px, py);
    return r;
}

// ---------------------------------------------------------------------------
// Prep kernel: sections by blockIdx.x.
//  [0,192)      xpad
//  [192,2112)   build_extra
//  [2112,2128)  flow_cn2 / flow_n2c
//  [2128,2144)  border zeroing of all padded bf16 buffers (replaces memset)
//  [2144,3776)  wxform
// ---------------------------------------------------------------------------
struct WD { const float* src; int cout, Cin, nCb, wbase, beg; };
struct PrepP {
    const float *x, *f1, *f2, *ff1, *ff2;
    float *fcn2, *fn2c;
    unsigned short *x_pad, *extra_pad, *wgt;
    WD wd[12];
};

__global__ __launch_bounds__(256) void prep_k(PrepP P) {
    __shared__ float wlds[16 * 288];
    const int b = blockIdx.x, tid = threadIdx.x;
    if (b < 192) {
        int idx = b * 256 + tid;                 // < 1024*48
        int pix = idx / 48, c4 = idx - pix * 48;
        int y = pix >> 5, xx = pix & 31;
        int c0 = c4 * 4;
        ushort4 s;
        s.x = f2bf(P.x[(size_t)(c0 + 0) * HW + pix]);
        s.y = f2bf(P.x[(size_t)(c0 + 1) * HW + pix]);
        s.z = f2bf(P.x[(size_t)(c0 + 2) * HW + pix]);
        s.w = f2bf(P.x[(size_t)(c0 + 3) * HW + pix]);
        *(ushort4*)(&P.x_pad[(size_t)((y + 1) * 34 + xx + 1) * 192 + c0]) = s;
    } else if (b < 2112) {
        int idx = (b - 192) * 256 + tid;         // < 480*1024
        int ch = idx >> 10, pix = idx & 1023;
        int y = pix >> 5, xx = pix & 31;
        float v = 0.f;
        if (ch < 64) {
            v = P.x[(size_t)ch * HW + pix];
        } else if (ch < 448) {
            int grp = (ch - 64) >> 6;
            int c = (ch - 64) & 63;
            const float* src;
            float fx, fy;
            if (grp == 0)      { src = P.x + 64 * HW;  fx = P.f1[pix];  fy = P.f1[HW + pix]; }
            else if (grp == 1) { src = P.x + 128 * HW; float2 r = comp_flow(P.f1, P.f2, pix);  fx = r.x; fy = r.y; }
            else if (grp == 2) { src = P.x;            fx = P.ff1[pix]; fy = P.ff1[HW + pix]; }
            else if (grp == 3) { src = P.x + 128 * HW; fx = P.f2[pix];  fy = P.f2[HW + pix]; }
            else if (grp == 4) { src = P.x + 64 * HW;  fx = P.ff2[pix]; fy = P.ff2[HW + pix]; }
            else               { src = P.x;            float2 r = comp_flow(P.ff2, P.ff1, pix); fx = r.x; fy = r.y; }
            v = bilin32(src + c * HW, (float)xx + fx, (float)y + fy);
        } else if (ch < 460) {
            int fc = ch - 448;
            int which = fc >> 1, comp = fc & 1;
            if (which == 0)      v = P.f1[comp * HW + pix];
            else if (which == 1) { float2 r = comp_flow(P.f1, P.f2, pix);  v = comp ? r.y : r.x; }
            else if (which == 2) v = P.ff1[comp * HW + pix];
            else if (which == 3) v = P.f2[comp * HW + pix];
            else if (which == 4) v = P.ff2[comp * HW + pix];
            else                 { float2 r = comp_flow(P.ff2, P.ff1, pix); v = comp ? r.y : r.x; }
        }
        P.extra_pad[(size_t)((y + 1) * 34 + xx + 1) * 480 + ch] = f2bf(v);
    } else if (b < 2128) {
        int idx = (b - 2112) * 256 + tid;
        if (idx < 1024) {
            float2 r = comp_flow(P.f1, P.f2, idx);
            P.fcn2[idx] = r.x; P.fcn2[HW + idx] = r.y;
        } else if (idx < 2048) {
            int pix = idx - 1024;
            float2 r = comp_flow(P.ff2, P.ff1, pix);
            P.fn2c[pix] = r.x; P.fn2c[HW + pix] = r.y;
        }
    } else if (b < 2144) {
        // border zeroing: 9 contiguous padded buffers starting at x_pad.
        // order must match ws layout: x_pad, vp0h, extra_pad, s1,a1,s2,a2,
        // attn_pad, op0h.
        const int chans[9] = {192, 192, 480, 64, 64, 64, 64, 192, 192};
        size_t offs[9]; size_t a = 0;
        for (int i = 0; i < 9; ++i) { offs[i] = a; a += (size_t)1156 * chans[i]; }
        int bb = b - 2128;                       // 0..15
        for (int item = bb; item < 9 * 132; item += 16) {
            int buf = item / 132, i = item - buf * 132;
            int py, px;
            if (i < 34) { py = 0; px = i; }
            else if (i < 68) { py = 33; px = i - 34; }
            else { int j = i - 68; py = 1 + (j >> 1); px = (j & 1) ? 33 : 0; }
            int C = chans[buf];
            unsigned short* p = P.x_pad + offs[buf] + (size_t)(py * 34 + px) * C;
            for (int c = tid; c < C; c += 256) p[c] = 0;
        }
    } else {
        int blk = b - 2144;                      // < 1632
        int di = 0;
        while (di < 11 && blk >= P.wd[di + 1].beg) ++di;
        WD w = P.wd[di];
        int local = blk - w.beg;
        int co16 = local / w.nCb, cb = local - co16 * w.nCb;
        int cr0 = co16 * 16, ci0 = cb * 32;
        for (int i = tid; i < 16 * 288; i += 256) {
            int cr = i / 288, o = i - cr * 288;
            int crg = cr0 + cr, ci = ci0 + o / 9;
            float v = (crg < w.cout && ci < w.Cin)
                ? w.src[((size_t)crg * w.Cin + ci0) * 9 + o] : 0.f;
            wlds[i] = v;
        }
        __syncthreads();
        for (int e = tid; e < 9 * 512; e += 256) {
            int t = e >> 9, idx = e & 511;
            int j = idx & 7, lane = idx >> 3, q = lane >> 4, mm = lane & 15;
            P.wgt[((size_t)w.wbase + ((size_t)co16 * 9 + t) * w.nCb + cb) * 512 + idx] =
                f2bf(wlds[mm * 288 + (q * 8 + j) * 9 + t]);
        }
    }
}

// ---------------------------------------------------------------------------
// MFMA 3x3 conv, multi-descriptor, register-prefetch double-buffered.
// Template: PIXROWS = pixel rows per block; COBLK = output channels per
// block (64 -> 4 co16 tiles, 16 -> 1 co16 tile; small COBLK gives 4x more
// blocks for the small convs -> machine actually fills).
// ---------------------------------------------------------------------------
struct CDesc {
    const unsigned short* in;
    const unsigned short* wgt;
    const float* bias;
    void* out;
    const float* residual;
    int Cpad, nCb, Cout, mode, cmod, relu, Mblocks;
};
struct CParam { CDesc d[4]; };

template<int PIXROWS, int COBLK>
__global__ __launch_bounds__(256) void conv_mfma_k(CParam P) {
    constexpr int TROWS = PIXROWS + 2;
    constexpr int TC = TROWS * 34 * 4;
    constexpr int ITRIPS = (TC + 255) / 256;
    constexpr int NTY = PIXROWS / 4;
    constexpr int NACC = NTY * 2;
    constexpr int MT = COBLK / 16;
    constexpr int WN = MT * 9 * 64;              // weight 16B chunks per stage
    constexpr int WTRIPS = (WN + 255) / 256;
    __shared__ unsigned short blds[TROWS * 34 * 40];
    __shared__ unsigned short wlds[MT * 9 * 512];

    int bx = blockIdx.x;
    int di = 0;
    while (bx >= P.d[di].Mblocks) { bx -= P.d[di].Mblocks; ++di; }
    const CDesc d = P.d[di];

    const int tid = threadIdx.x;
    const int w = tid >> 6, lane = tid & 63;
    const int lq = lane >> 4, ln = lane & 15;
    const int co0 = bx * COBLK;
    const int by = blockIdx.y, y0 = by * PIXROWS;
    const unsigned short* __restrict__ in = d.in;
    const unsigned short* __restrict__ wg = d.wgt;
    const int Cpad = d.Cpad, nCb = d.nCb;

    floatx4 acc[MT][NACC];
#pragma unroll
    for (int mt = 0; mt < MT; ++mt)
#pragma unroll
        for (int nt = 0; nt < NACC; ++nt)
            acc[mt][nt] = (floatx4){0.f, 0.f, 0.f, 0.f};

    bf16x8 ireg[ITRIPS];
    bf16x8 wreg[WTRIPS];

    auto load_regs = [&](int cb) {
        const int ci0 = cb << 5;
#pragma unroll
        for (int k = 0; k < ITRIPS; ++k) {
            int i = tid + k * 256;
            if (i < TC) {
                int r = i / 136, rem = i - r * 136, c = rem >> 2, g = rem & 3;
                ireg[k] = *(const bf16x8*)(in + (size_t)((y0 + r) * 34 + c) * Cpad + ci0 + g * 8);
            }
        }
#pragma unroll
        for (int k = 0; k < WTRIPS; ++k) {
            int i = tid + k * 256;
            if (i < WN) {
                int chunk = i >> 6, l16 = i & 63;
                int mt = chunk / 9, t = chunk - mt * 9;
                wreg[k] = *(const bf16x8*)(wg + ((size_t)(((co0 >> 4) + mt) * 9 + t) * nCb + cb) * 512 + l16 * 8);
            }
        }
    };

    load_regs(0);

    for (int cb = 0; cb < nCb; ++cb) {
        __syncthreads();
#pragma unroll
        for (int k = 0; k < ITRIPS; ++k) {
            int i = tid + k * 256;
            if (i < TC) {
                int r = i / 136, rem = i - r * 136, c = rem >> 2, g = rem & 3;
                *(bf16x8*)(&blds[(r * 34 + c) * 40 + g * 8]) = ireg[k];
            }
        }
#pragma unroll
        for (int k = 0; k < WTRIPS; ++k) {
            int i = tid + k * 256;
            if (i < WN) {
                int chunk = i >> 6, l16 = i & 63;
                *(bf16x8*)(&wlds[chunk * 512 + l16 * 8]) = wreg[k];
            }
        }
        __syncthreads();
        if (cb + 1 < nCb) load_regs(cb + 1);
        for (int t = 0; t < 9; ++t) {
            const int dy = t / 3, dx = t - dy * 3;
            bf16x8 bfr[NACC];
#pragma unroll
            for (int ty = 0; ty < NTY; ++ty)
#pragma unroll
                for (int tx = 0; tx < 2; ++tx) {
                    int yy = w * NTY + ty + dy;
                    int xx = tx * 16 + ln + dx;
                    bfr[ty * 2 + tx] = *(const bf16x8*)(&blds[(yy * 34 + xx) * 40 + lq * 8]);
                }
#pragma unroll
            for (int mt = 0; mt < MT; ++mt) {
                bf16x8 afr = *(const bf16x8*)(&wlds[(mt * 9 + t) * 512 + lane * 8]);
#pragma unroll
                for (int nt = 0; nt < NACC; ++nt)
                    acc[mt][nt] = __builtin_amdgcn_mfma_f32_16x16x32_bf16(afr, bfr[nt], acc[mt][nt], 0, 0, 0);
            }
        }
    }

#pragma unroll
    for (int mt = 0; mt < MT; ++mt) {
        const int co = co0 + mt * 16 + lq * 4;
        if (co >= d.Cout) continue;
        float bv[4];
#pragma unroll
        for (int r = 0; r < 4; ++r) bv[r] = d.bias[co + r];
#pragma unroll
        for (int nt = 0; nt < NACC; ++nt) {
            const int ty = nt >> 1, tx = nt & 1;
            const int pix = by * (PIXROWS * 32) + (w * NTY + ty) * 32 + tx * 16 + ln;
            float v[4];
#pragma unroll
            for (int r = 0; r < 4; ++r) {
                float vv = acc[mt][nt][r] + bv[r];
                if (d.relu) vv = (vv >= 0.f) ? vv : 0.1f * vv;
                v[r] = vv;
            }
            if (d.mode == 0) {
                float* o = (float*)d.out;
#pragma unroll
                for (int r = 0; r < 4; ++r) {
                    float vv = v[r];
                    if (d.residual) vv += d.residual[(size_t)(co + r) * HW + pix];
                    o[(size_t)(co + r) * HW + pix] = vv;
                }
            } else if (d.mode == 1) {
                int fq = co / d.cmod, cc = co - fq * d.cmod;
                *(float4*)((float*)d.out + ((size_t)fq * HW + pix) * d.cmod + cc) =
                    make_float4(v[0], v[1], v[2], v[3]);
            } else if (d.mode == 2) {
                int fq = co / d.cmod, cc = co - fq * d.cmod;
                ushort4 s4;
                s4.x = f2bf(v[0]); s4.y = f2bf(v[1]); s4.z = f2bf(v[2]); s4.w = f2bf(v[3]);
                *(ushort4*)((unsigned short*)d.out + ((size_t)fq * HW + pix) * d.cmod + cc) = s4;
            } else {
                int yy = (pix >> 5) + 1, xx = (pix & 31) + 1;
                ushort4 s4;
                s4.x = f2bf(v[0]); s4.y = f2bf(v[1]); s4.z = f2bf(v[2]); s4.w = f2bf(v[3]);
                *(ushort4*)((unsigned short*)d.out + (size_t)(yy * 34 + xx) * d.cmod + co) = s4;
            }
        }
    }
}

// ---------------------------------------------------------------------------
// Deformable attention v3: LDS value + patch-convolution gathers.
// ---------------------------------------------------------------------------
__global__ __launch_bounds__(256) void deform_attn_k(
    const unsigned short* __restrict__ value_b, const float* __restrict__ so_t,
    const unsigned short* __restrict__ aw_t,
    const float* __restrict__ flow_1, const float* __restrict__ flow_2,
    const float* __restrict__ flip_flow_1, const float* __restrict__ flip_flow_2,
    const float* __restrict__ flow_cn2, const float* __restrict__ flow_n2c,
    unsigned short* __restrict__ attn_pad)
{
    __shared__ unsigned short vlds[24576];        // [l][pix][8] bf16, 48 KiB
    __shared__ unsigned short pwlds[4][432];      // per-wave probs, rows of 12
    const int tid = threadIdx.x;
    const int wav = tid >> 6, lane = tid & 63;
    const int m = blockIdx.x & 7, qc = blockIdx.x >> 3;

    for (int i = tid; i < 3072; i += 256) {
        int l = i >> 10, p = i & 1023;
        *(bf16x8*)(&vlds[(size_t)i * 8]) =
            *(const bf16x8*)(value_b + ((size_t)((l * 8 + m) * 1024) + p) * 8);
    }
    __syncthreads();

    const int pp = lane & 15, gq = lane >> 4;
    const int gdy = (gq >> 1) * 2 - 1;
    const int gdx = (gq & 1) * 2 - 1;
    const bool selx = (gq & 1);
    const bool sely = (gq >> 1);

    for (int r = 0; r < 8; ++r) {
        const int q = qc * 32 + r * 4 + wav;
        const int f = q >> 10, pix = q & 1023;
        const int y = pix >> 5, x = pix & 31;

        float flx0 = 0.f, fly0 = 0.f, flx1 = 0.f, fly1 = 0.f, flx2 = 0.f, fly2 = 0.f;
        if (f == 0) {
            flx1 = flow_1[pix];      fly1 = flow_1[HW + pix];
            flx2 = flow_cn2[pix];    fly2 = flow_cn2[HW + pix];
        } else if (f == 1) {
            flx0 = flip_flow_1[pix]; fly0 = flip_flow_1[HW + pix];
            flx2 = flow_2[pix];      fly2 = flow_2[HW + pix];
        } else {
            flx0 = flow_n2c[pix];    fly0 = flow_n2c[HW + pix];
            flx1 = flip_flow_2[pix]; fly1 = flip_flow_2[HW + pix];
        }

        const unsigned short* awp = aw_t + (size_t)q * 2592 + m * 324;
        float av[6];
        float vmax = -1e30f;
#pragma unroll
        for (int it = 0; it < 6; ++it) {
            int j = lane + it * 64;
            float a = (j < 324) ? bf2f(awp[j]) : -1e30f;
            av[it] = a;
            vmax = fmaxf(vmax, a);
        }
#pragma unroll
        for (int off = 32; off; off >>= 1) vmax = fmaxf(vmax, __shfl_xor(vmax, off));
        float ssum = 0.f;
#pragma unroll
        for (int it = 0; it < 6; ++it) {
            int j = lane + it * 64;
            float e = (j < 324) ? __expf(av[it] - vmax) : 0.f;
            av[it] = e;
            ssum += e;
        }
#pragma unroll
        for (int off = 32; off; off >>= 1) ssum += __shfl_xor(ssum, off);
        const float inv = 1.f / ssum;

#pragma unroll
        for (int it = 0; it < 6; ++it) {
            int j = lane + it * 64;
            if (j < 324) {
                int pi = j / 9, k = j - pi * 9;
                pwlds[wav][pi * 12 + k] = f2bf(av[it] * inv);
            }
        }

        float acc[8];
#pragma unroll
        for (int dd = 0; dd < 8; ++dd) acc[dd] = 0.f;
        const float* sop = so_t + (size_t)q * 576 + m * 72;

#pragma unroll
        for (int pt = 0; pt < 3; ++pt) {
            int pi = pt * 16 + pp;
            if (pi < 36) {
                int l = pi / 12;
                float2 so2 = *(const float2*)(sop + pi * 2);
                float fx = (l == 0) ? flx0 : (l == 1) ? flx1 : flx2;
                float fy = (l == 0) ? fly0 : (l == 1) ? fly1 : fly2;
                float bxf = (float)x + so2.x + fx;
                float byf = (float)y + so2.y + fy;
                float x0f = floorf(bxf), y0f = floorf(byf);
                float wx = bxf - x0f, wy = byf - y0f;
                float ax = 1.f - wx, ay = 1.f - wy;
                int x0 = (int)fminf(fmaxf(x0f, -2.f), 34.f);
                int y0 = (int)fminf(fmaxf(y0f, -2.f), 34.f);

                const unsigned short* pr = &pwlds[wav][pi * 12];
                uint2 pv0 = *(const uint2*)(pr);
                uint2 pv1 = *(const uint2*)(pr + 4);
                float a0 = bflo(pv0.x), a1 = bfhi(pv0.x), a2 = bflo(pv0.y);
                float a3 = bfhi(pv0.y), a4 = bflo(pv1.x), a5 = bfhi(pv1.x);
                float a6 = bflo(pv1.y), a7 = bfhi(pv1.y), a8 = bf2f(pr[8]);

                float bs0a, bs0b, bs1a, bs1b, bs2a, bs2b;
                {
                    float b0, b1, b2, b3;
                    b0 = a0 * ax; b1 = a0 * wx + a3 * ax; b2 = a3 * wx + a6 * ax; b3 = a6 * wx;
                    bs0a = selx ? b2 : b0; bs0b = selx ? b3 : b1;
                    b0 = a1 * ax; b1 = a1 * wx + a4 * ax; b2 = a4 * wx + a7 * ax; b3 = a7 * wx;
                    bs1a = selx ? b2 : b0; bs1b = selx ? b3 : b1;
                    b0 = a2 * ax; b1 = a2 * wx + a5 * ax; b2 = a5 * wx + a8 * ax; b3 = a8 * wx;
                    bs2a = selx ? b2 : b0; bs2b = selx ? b3 : b1;
                }
                float c00, c01, c10, c11;
                {
                    float c0 = bs0a * ay, c1 = bs0a * wy + bs1a * ay;
                    float c2 = bs1a * wy + bs2a * ay, c3 = bs2a * wy;
                    c00 = sely ? c2 : c0; c10 = sely ? c3 : c1;
                    c0 = bs0b * ay; c1 = bs0b * wy + bs1b * ay;
                    c2 = bs1b * wy + bs2b * ay; c3 = bs2b * wy;
                    c01 = sely ? c2 : c0; c11 = sely ? c3 : c1;
                }
                float cg[2][2] = {{c00, c01}, {c10, c11}};
                const int vbase = l * 1024;
#pragma unroll
                for (int sy = 0; sy < 2; ++sy) {
#pragma unroll
                    for (int sx = 0; sx < 2; ++sx) {
                        int dy = gdy + sy, dx = gdx + sx;
                        float pyf = y0f + (float)dy, pxf = x0f + (float)dx;
                        bool v = (pxf >= 0.f) && (pxf <= 31.f) && (pyf >= 0.f) && (pyf <= 31.f);
                        int px = min(max(x0 + dx, 0), 31);
                        int py = min(max(y0 + dy, 0), 31);
                        float c = cg[sy][sx] * (v ? 1.f : 0.f);
                        uint4 vv = *(const uint4*)(&vlds[(size_t)(vbase + py * 32 + px) * 8]);
                        acc[0] = fmaf(c, bflo(vv.x), acc[0]);
                        acc[1] = fmaf(c, bfhi(vv.x), acc[1]);
                        acc[2] = fmaf(c, bflo(vv.y), acc[2]);
                        acc[3] = fmaf(c, bfhi(vv.y), acc[3]);
                        acc[4] = fmaf(c, bflo(vv.z), acc[4]);
                        acc[5] = fmaf(c, bfhi(vv.z), acc[5]);
                        acc[6] = fmaf(c, bflo(vv.w), acc[6]);
                        acc[7] = fmaf(c, bfhi(vv.w), acc[7]);
                    }
                }
            }
        }

#pragma unroll
        for (int dd = 0; dd < 8; ++dd) {
#pragma unroll
            for (int off = 32; off; off >>= 1) acc[dd] += __shfl_xor(acc[dd], off);
        }
        if (lane == 0) {
            unsigned short* op = attn_pad + (size_t)((y + 1) * 34 + x + 1) * 192 + f * 64 + m * 8;
            ushort4 s0, s1;
            s0.x = f2bf(acc[0]); s0.y = f2bf(acc[1]); s0.z = f2bf(acc[2]); s0.w = f2bf(acc[3]);
            s1.x = f2bf(acc[4]); s1.y = f2bf(acc[5]); s1.z = f2bf(acc[6]); s1.w = f2bf(acc[7]);
            *(ushort4*)(op) = s0;
            *(ushort4*)(op + 4) = s1;
        }
    }
}

// ---------------------------------------------------------------------------
extern "C" void kernel_launch(void* const* d_in, const int* in_sizes, int n_in,
                              void* d_out, int out_size, void* d_ws, size_t ws_size,
                              hipStream_t stream) {
    const float* x      = (const float*)d_in[0];
    const float* flow_1 = (const float*)d_in[1];
    const float* flow_2 = (const float*)d_in[2];
    const float* flip_1 = (const float*)d_in[3];
    const float* flip_2 = (const float*)d_in[4];
    const float* vp0_w = (const float*)d_in[5];  const float* vp0_b = (const float*)d_in[6];
    const float* vp1_w = (const float*)d_in[7];  const float* vp1_b = (const float*)d_in[8];
    const float* so0_w = (const float*)d_in[9];  const float* so0_b = (const float*)d_in[10];
    const float* so1_w = (const float*)d_in[11]; const float* so1_b = (const float*)d_in[12];
    const float* so2_w = (const float*)d_in[13]; const float* so2_b = (const float*)d_in[14];
    const float* so3_w = (const float*)d_in[15]; const float* so3_b = (const float*)d_in[16];
    const float* aw0_w = (const float*)d_in[17]; const float* aw0_b = (const float*)d_in[18];
    const float* aw1_w = (const float*)d_in[19]; const float* aw1_b = (const float*)d_in[20];
    const float* aw2_w = (const float*)d_in[21]; const float* aw2_b = (const float*)d_in[22];
    const float* aw3_w = (const float*)d_in[23]; const float* aw3_b = (const float*)d_in[24];
    const float* op0_w = (const float*)d_in[25]; const float* op0_b = (const float*)d_in[26];
    const float* op1_w = (const float*)d_in[27]; const float* op1_b = (const float*)d_in[28];
    float* out = (float*)d_out;
    (void)ws_size; (void)in_sizes; (void)n_in; (void)out_size;

    // ---- workspace layout ----
    float* fws = (float*)d_ws;
    float* flow_cn2 = fws;                       // 2048
    float* flow_n2c = flow_cn2 + 2048;           // 2048
    unsigned short* value_b = (unsigned short*)(flow_n2c + 2048); // 192*1024 bf16
    float* so_t     = (float*)(value_b + 196608);                 // 1769472 fp32
    unsigned short* uws = (unsigned short*)(so_t + 1769472);
    // padded bf16 buffers — order must match prep_k's border table!
    unsigned short* x_pad     = uws;                       // 1156*192
    unsigned short* vp0h      = x_pad + 1156 * 192;        // 1156*192
    unsigned short* extra_pad = vp0h + 1156 * 192;         // 1156*480
    unsigned short* s1 = extra_pad + 1156 * 480;           // 1156*64 x4
    unsigned short* a1 = s1 + 1156 * 64;
    unsigned short* s2 = a1 + 1156 * 64;
    unsigned short* a2 = s2 + 1156 * 64;
    unsigned short* attn_pad = a2 + 1156 * 64;             // 1156*192
    unsigned short* op0h     = attn_pad + 1156 * 192;      // 1156*192
    unsigned short* aw_t = op0h + 1156 * 192;              // 3072*2592
    unsigned short* wgt  = aw_t + (size_t)3072 * 2592;     // 14688*512

    // ---- prep: xpad + extra + flows + borders + weight transform ----
    PrepP pp;
    pp.x = x; pp.f1 = flow_1; pp.f2 = flow_2; pp.ff1 = flip_1; pp.ff2 = flip_2;
    pp.fcn2 = flow_cn2; pp.fn2c = flow_n2c;
    pp.x_pad = x_pad; pp.extra_pad = extra_pad; pp.wgt = wgt;
    pp.wd[0]  = {vp0_w, 192, 192, 6,     0,    0};
    pp.wd[1]  = {vp1_w, 192, 192, 6,   648,   72};
    pp.wd[2]  = {so0_w,  64, 460, 15, 1296,  144};
    pp.wd[3]  = {aw0_w,  64, 460, 15, 1836,  204};
    pp.wd[4]  = {so1_w,  64,  64, 2,  2376,  264};
    pp.wd[5]  = {aw1_w,  64,  64, 2,  2448,  272};
    pp.wd[6]  = {so2_w,  64,  64, 2,  2520,  280};
    pp.wd[7]  = {aw2_w,  64,  64, 2,  2592,  288};
    pp.wd[8]  = {so3_w, 1728, 64, 2,  2664,  296};
    pp.wd[9]  = {aw3_w, 7776, 64, 2,  4608,  512};
    pp.wd[10] = {op0_w, 192, 192, 6, 13392, 1488};
    pp.wd[11] = {op1_w, 192, 192, 6, 14040, 1560};
    prep_k<<<3776, 256, 0, stream>>>(pp);

    const int BIG = 1 << 30;
    CDesc nul = {nullptr, nullptr, nullptr, nullptr, nullptr, 0, 0, 0, 0, 0, 0, BIG};

    {   // L1: vp0 + so0/aw0 — 16-co blocks, 160 blocks
        CParam cp;
        cp.d[0] = {x_pad,     wgt + (size_t)0 * 512,    vp0_b, vp0h, nullptr, 192, 6,  192, 3, 192, 1, 12};
        cp.d[1] = {extra_pad, wgt + (size_t)1296 * 512, so0_b, s1,   nullptr, 480, 15, 64,  3, 64,  1, 4};
        cp.d[2] = {extra_pad, wgt + (size_t)1836 * 512, aw0_b, a1,   nullptr, 480, 15, 64,  3, 64,  1, 4};
        cp.d[3] = nul;
        conv_mfma_k<4, 16><<<dim3(20, 8), 256, 0, stream>>>(cp);
    }
    {   // L2: vp1 (->value_b bf16 cmod8) + so1/aw1 — 160 blocks
        CParam cp;
        cp.d[0] = {vp0h, wgt + (size_t)648 * 512,  vp1_b, value_b, nullptr, 192, 6, 192, 2, 8,  0, 12};
        cp.d[1] = {s1,   wgt + (size_t)2376 * 512, so1_b, s2,      nullptr, 64,  2, 64,  3, 64, 1, 4};
        cp.d[2] = {a1,   wgt + (size_t)2448 * 512, aw1_b, a2,      nullptr, 64,  2, 64,  3, 64, 1, 4};
        cp.d[3] = nul;
        conv_mfma_k<4, 16><<<dim3(20, 8), 256, 0, stream>>>(cp);
    }
    {   // L3: so2/aw2 — 64 blocks
        CParam cp;
        cp.d[0] = {s2, wgt + (size_t)2520 * 512, so2_b, s1, nullptr, 64, 2, 64, 3, 64, 1, 4};
        cp.d[1] = {a2, wgt + (size_t)2592 * 512, aw2_b, a1, nullptr, 64, 2, 64, 3, 64, 1, 4};
        cp.d[2] = nul; cp.d[3] = nul;
        conv_mfma_k<4, 16><<<dim3(8, 8), 256, 0, stream>>>(cp);
    }
    {   // L4: so3 (fp32 cmod 576) + aw3 (bf16 cmod 2592) — 596 blocks, 64-co
        CParam cp;
        cp.d[0] = {s1, wgt + (size_t)2664 * 512, so3_b, so_t, nullptr, 64, 2, 1728, 1, 576,  0, 27};
        cp.d[1] = {a1, wgt + (size_t)4608 * 512, aw3_b, aw_t, nullptr, 64, 2, 7776, 2, 2592, 0, 122};
        cp.d[2] = nul; cp.d[3] = nul;
        conv_mfma_k<8, 64><<<dim3(149, 4), 256, 0, stream>>>(cp);
    }

    // deformable attention (patch-conv, 768 blocks)
    deform_attn_k<<<768, 256, 0, stream>>>(value_b, so_t, aw_t,
                                           flow_1, flow_2, flip_1, flip_2,
                                           flow_cn2, flow_n2c, attn_pad);

    {   // op0 — 96 blocks
        CParam cp;
        cp.d[0] = {attn_pad, wgt + (size_t)13392 * 512, op0_b, op0h, nullptr, 192, 6, 192, 3, 192, 1, 12};
        cp.d[1] = nul; cp.d[2] = nul; cp.d[3] = nul;
        conv_mfma_k<4, 16><<<dim3(12, 8), 256, 0, stream>>>(cp);
    }
    {   // op1 + residual — 96 blocks
        CParam cp;
        cp.d[0] = {op0h, wgt + (size_t)14040 * 512, op1_b, out, x, 192, 6, 192, 0, 0, 0, 12};
        cp.d[1] = nul; cp.d[2] = nul; cp.d[3] = nul;
        conv_mfma_k<4, 16><<<dim3(12, 8), 256, 0, stream>>>(cp);
    }
}